// Round 1
// baseline (103801.782 us; speedup 1.0000x reference)
//
#include <hip/hip_runtime.h>

#define NN 100000
#define NE 1600000
#define FD 64
#define KK 3
#define NF (NN*FD)            // 6,400,000
#define KNF (KK*NF)           // 19,200,000
#define EPSBN 1e-5f

// ---------------- graph norm ----------------
__global__ void k_deg(const int* __restrict__ col, const float* __restrict__ w,
                      float* __restrict__ deg) {
  int e = blockIdx.x * 256 + threadIdx.x;
  if (e < NE) atomicAdd(&deg[col[e]], w[e]);
}

__global__ void k_dis(float* __restrict__ deg) {
  int i = blockIdx.x * 256 + threadIdx.x;
  if (i < NN) { float d = deg[i]; deg[i] = d > 0.f ? rsqrtf(d) : 0.f; }
}

__global__ void k_norm(const int* __restrict__ row, const int* __restrict__ col,
                       const float* __restrict__ w, const float* __restrict__ dis,
                       float* __restrict__ nrm) {
  int e = blockIdx.x * 256 + threadIdx.x;
  if (e < NE) nrm[e] = dis[row[e]] * w[e] * dis[col[e]];
}

// ---------------- dense GEMM: out[k][n][f] = sum_i in[k*inSK + n*64 + i] * W[k*wSK + i*64 + f]
__global__ __launch_bounds__(256) void k_gemm(const float* __restrict__ in, long inSK,
                                              const float* __restrict__ W, long wSK,
                                              float* __restrict__ out) {
  __shared__ float Wl[4096];
  int k = blockIdx.y;
  const float* Wk = W + (long)k * wSK;
  for (int i = threadIdx.x; i < 4096; i += 256) Wl[i] = Wk[i];
  __syncthreads();
  const float* xin = in + (long)k * inSK;
  int f = threadIdx.x & 63;
  int sub = threadIdx.x >> 6;
  int nb = blockIdx.x * 64;
  for (int rr = 0; rr < 16; ++rr) {
    int n = nb + rr * 4 + sub;
    if (n >= NN) return;
    const float* xr = xin + (long)n * 64;
    float acc = 0.f;
#pragma unroll
    for (int i = 0; i < 64; ++i) acc = fmaf(xr[i], Wl[i * 64 + f], acc);
    out[((long)k * NN + n) * 64 + f] = acc;
  }
}

// ---------------- scatter: dst[k][col][f] += src[k][row][f]*norm  (atomic)
__global__ void k_scatter(const int* __restrict__ row, const int* __restrict__ col,
                          const float* __restrict__ nrm, const float* __restrict__ src,
                          float* __restrict__ dst) {
  long idx = (long)blockIdx.x * 256 + threadIdx.x;
  if (idx >= (long)NE * 4) return;
  int e = (int)(idx >> 2), q = (int)(idx & 3);
  float nm = nrm[e];
  int r = row[e], c = col[e];
  long so = (long)r * 64 + q * 16;
  long dofs = (long)c * 64 + q * 16;
#pragma unroll
  for (int k = 0; k < KK; ++k) {
    const float4* s = (const float4*)(src + (long)k * NF + so);
    float* d = dst + (long)k * NF + dofs;
#pragma unroll
    for (int j = 0; j < 4; ++j) {
      float4 v = s[j];
      atomicAdd(d + 4 * j + 0, v.x * nm);
      atomicAdd(d + 4 * j + 1, v.y * nm);
      atomicAdd(d + 4 * j + 2, v.z * nm);
      atomicAdd(d + 4 * j + 3, v.w * nm);
    }
  }
}

// ---------------- a = relu(a + b + bias[k,t,:])
__global__ void k_add_relu(float* __restrict__ a, const float* __restrict__ b,
                           const float* __restrict__ bias, int t) {
  long i4 = (long)blockIdx.x * 256 + threadIdx.x;
  if (i4 >= (long)KNF / 4) return;
  long i = i4 * 4;
  int f = (int)(i & 63);
  int k = (int)(i / NF);
  const float* bp = bias + ((long)k * 2 + t) * 64 + f;
  float4 bb = *(const float4*)bp;
  float4 va = *(float4*)(a + i);
  float4 vb = *(const float4*)(b + i);
  va.x = fmaxf(va.x + vb.x + bb.x, 0.f);
  va.y = fmaxf(va.y + vb.y + bb.y, 0.f);
  va.z = fmaxf(va.z + vb.z + bb.z, 0.f);
  va.w = fmaxf(va.w + vb.w + bb.w, 0.f);
  *(float4*)(a + i) = va;
}

// ---------------- dst[n,f] = mean_k src[k,n,f]
__global__ void k_mean(const float* __restrict__ src, float* __restrict__ dst) {
  long i4 = (long)blockIdx.x * 256 + threadIdx.x;
  if (i4 >= (long)NF / 4) return;
  long i = i4 * 4;
  float4 a = *(const float4*)(src + i);
  float4 b = *(const float4*)(src + NF + i);
  float4 c = *(const float4*)(src + 2L * NF + i);
  const float s = 1.f / 3.f;
  float4 o;
  o.x = (a.x + b.x + c.x) * s;
  o.y = (a.y + b.y + c.y) * s;
  o.z = (a.z + b.z + c.z) * s;
  o.w = (a.w + b.w + c.w) * s;
  *(float4*)(dst + i) = o;
}

// ---------------- BN stats: per-feature sum & sumsq
__global__ __launch_bounds__(256) void k_bnstats(const float* __restrict__ h,
                                                 float* __restrict__ sum,
                                                 float* __restrict__ sq) {
  int f = threadIdx.x & 63, g = threadIdx.x >> 6;
  float s = 0.f, s2 = 0.f;
  for (int n = blockIdx.x * 4 + g; n < NN; n += gridDim.x * 4) {
    float v = h[(long)n * 64 + f];
    s += v; s2 += v * v;
  }
  __shared__ float ls[512];
  ls[threadIdx.x] = s;
  ls[256 + threadIdx.x] = s2;
  __syncthreads();
  if (threadIdx.x < 64) {
    float ts  = ls[f] + ls[64 + f] + ls[128 + f] + ls[192 + f];
    float ts2 = ls[256 + f] + ls[320 + f] + ls[384 + f] + ls[448 + f];
    atomicAdd(&sum[f], ts);
    atomicAdd(&sq[f], ts2);
  }
}

// ---------------- out = relu(g*(h-mu)*rsqrt(var+eps)+be)
__global__ void k_bnfin(const float* __restrict__ h, const float* __restrict__ sum,
                        const float* __restrict__ sq, const float* __restrict__ gam,
                        const float* __restrict__ bet, float* __restrict__ out) {
  long i4 = (long)blockIdx.x * 256 + threadIdx.x;
  if (i4 >= (long)NF / 4) return;
  long i = i4 * 4;
  int f = (int)(i & 63);
  float4 v = *(const float4*)(h + i);
  float o[4] = {v.x, v.y, v.z, v.w};
  float r[4];
#pragma unroll
  for (int j = 0; j < 4; ++j) {
    int fj = f + j;
    float mu = sum[fj] * (1.f / NN);
    float var = sq[fj] * (1.f / NN) - mu * mu;
    float inv = rsqrtf(var + EPSBN);
    float y = gam[fj] * (o[j] - mu) * inv + bet[fj];
    r[j] = fmaxf(y, 0.f);
  }
  float4 ov = {r[0], r[1], r[2], r[3]};
  *(float4*)(out + i) = ov;
}

extern "C" void kernel_launch(void* const* d_in, const int* in_sizes, int n_in,
                              void* d_out, int out_size, void* d_ws, size_t ws_size,
                              hipStream_t stream) {
  const float* x   = (const float*)d_in[0];
  const int*   ei  = (const int*)d_in[1];
  const float* wts = (const float*)d_in[2];
  const int* row = ei;        // edge_index[0]
  const int* col = ei + NE;   // edge_index[1]

  float* ws  = (float*)d_ws;
  float* dis = ws;            // NN (deg -> dis in place)
  float* nrm = dis + NN;      // NE
  float* h   = nrm + NE;      // NF
  float* A   = h + NF;        // KNF
  float* B   = A + KNF;       // KNF
  float* bns = B + KNF;       // 64
  // bnq = bns + 64

  hipMemsetAsync(dis, 0, NN * sizeof(float), stream);
  k_deg<<<(NE + 255) / 256, 256, 0, stream>>>(col, wts, dis);
  k_dis<<<(NN + 255) / 256, 256, 0, stream>>>(dis);
  k_norm<<<(NE + 255) / 256, 256, 0, stream>>>(row, col, wts, dis, nrm);

  dim3 gg((NN + 63) / 64, KK);
  int scatterBlocks = (int)(((long)NE * 4 + 255) / 256);
  int ewBlocks = KNF / 4 / 256;     // 18750 exact
  int nfBlocks = NF / 4 / 256;      // 6250 exact

  for (int layer = 0; layer < 3; ++layer) {
    const float* iw = (const float*)d_in[3 + 6 * layer];  // [K,F,F]
    const float* w  = (const float*)d_in[4 + 6 * layer];  // [K,1,F,F]
    const float* rw = (const float*)d_in[5 + 6 * layer];  // [K,2,F,F]
    const float* bs = (const float*)d_in[6 + 6 * layer];  // [K,2,1,F]
    const float* gm = (const float*)d_in[7 + 6 * layer];  // [F]
    const float* bt = (const float*)d_in[8 + 6 * layer];  // [F]
    const float* xin = (layer == 0) ? x : h;

    // t=0
    k_gemm<<<gg, 256, 0, stream>>>(xin, 0, iw, 4096, A);          // A = x@iw[k]
    hipMemsetAsync(B, 0, (size_t)KNF * 4, stream);
    k_scatter<<<scatterBlocks, 256, 0, stream>>>(row, col, nrm, A, B);
    k_gemm<<<gg, 256, 0, stream>>>(xin, 0, rw, 8192, A);          // A = x@rw[k,0]
    k_add_relu<<<ewBlocks, 256, 0, stream>>>(A, B, bs, 0);        // A = relu(A+B+b0)
    // t=1
    k_gemm<<<gg, 256, 0, stream>>>(A, NF, w, 4096, B);            // B = A@w[k,0]
    hipMemsetAsync(A, 0, (size_t)KNF * 4, stream);
    k_scatter<<<scatterBlocks, 256, 0, stream>>>(row, col, nrm, B, A);
    k_gemm<<<gg, 256, 0, stream>>>(xin, 0, rw + 4096, 8192, B);   // B = x@rw[k,1]
    k_add_relu<<<ewBlocks, 256, 0, stream>>>(B, A, bs, 1);        // B = relu(B+A+b1)
    // mean over k + BN + relu
    k_mean<<<nfBlocks, 256, 0, stream>>>(B, A);                   // A[0:NF) = mean_k B
    hipMemsetAsync(bns, 0, 2 * 64 * sizeof(float), stream);
    k_bnstats<<<1024, 256, 0, stream>>>(A, bns, bns + 64);
    float* dst = (layer == 2) ? (float*)d_out : h;
    k_bnfin<<<nfBlocks, 256, 0, stream>>>(A, bns, bns + 64, gm, bt, dst);
  }
}

// Round 2
// 4458.873 us; speedup vs baseline: 23.2798x; 23.2798x over previous
//
#include <hip/hip_runtime.h>

#define NN 100000
#define NE 1600000
#define FD 64
#define KK 3
#define NF (NN*FD)            // 6,400,000
#define KNF (KK*NF)           // 19,200,000
#define EPSBN 1e-5f

// ---------------- graph norm ----------------
__global__ void k_deg(const int* __restrict__ col, const float* __restrict__ w,
                      float* __restrict__ deg) {
  int e = blockIdx.x * 256 + threadIdx.x;
  if (e < NE) atomicAdd(&deg[col[e]], w[e]);
}

__global__ void k_dis(float* __restrict__ deg) {
  int i = blockIdx.x * 256 + threadIdx.x;
  if (i < NN) { float d = deg[i]; deg[i] = d > 0.f ? rsqrtf(d) : 0.f; }
}

__global__ void k_norm(const int* __restrict__ row, const int* __restrict__ col,
                       const float* __restrict__ w, const float* __restrict__ dis,
                       float* __restrict__ nrm) {
  int e = blockIdx.x * 256 + threadIdx.x;
  if (e < NE) nrm[e] = dis[row[e]] * w[e] * dis[col[e]];
}

// ---------------- CSR build (by col) ----------------
__global__ void k_hist(const int* __restrict__ col, int* __restrict__ cnt) {
  int e = blockIdx.x * 256 + threadIdx.x;
  if (e < NE) atomicAdd(&cnt[col[e]], 1);
}

// single-block hierarchical exclusive scan of cnt[NN] -> rowstart[NN+1], cursor copy
__global__ __launch_bounds__(1024) void k_scan(const int* __restrict__ cnt,
                                               int* __restrict__ rowstart,
                                               int* __restrict__ cursor) {
  __shared__ int ls[1024];
  int tid = threadIdx.x;
  const int CH = (NN + 1023) / 1024;   // 98
  int lo = tid * CH, hi = lo + CH; if (hi > NN) hi = NN; if (lo > NN) lo = NN;
  int s = 0;
  for (int i = lo; i < hi; ++i) s += cnt[i];
  ls[tid] = s;
  __syncthreads();
  for (int off = 1; off < 1024; off <<= 1) {
    int v = (tid >= off) ? ls[tid - off] : 0;
    __syncthreads();
    ls[tid] += v;
    __syncthreads();
  }
  int run = (tid == 0) ? 0 : ls[tid - 1];
  for (int i = lo; i < hi; ++i) {
    rowstart[i] = run; cursor[i] = run; run += cnt[i];
  }
  if (tid == 1023) rowstart[NN] = run;   // == NE
}

__global__ void k_place(const int* __restrict__ row, const int* __restrict__ col,
                        const float* __restrict__ nrm, int* __restrict__ cursor,
                        int* __restrict__ prow, float* __restrict__ pnrm) {
  int e = blockIdx.x * 256 + threadIdx.x;
  if (e >= NE) return;
  int p = atomicAdd(&cursor[col[e]], 1);
  prow[p] = row[e];
  pnrm[p] = nrm[e];
}

// ---------------- dense GEMM: out[k][n][f] = sum_i in[k*inSK + n*64 + i] * W[k*wSK + i*64 + f]
__global__ __launch_bounds__(256) void k_gemm(const float* __restrict__ in, long inSK,
                                              const float* __restrict__ W, long wSK,
                                              float* __restrict__ out) {
  __shared__ float Wl[4096];
  int k = blockIdx.y;
  const float* Wk = W + (long)k * wSK;
  for (int i = threadIdx.x; i < 4096; i += 256) Wl[i] = Wk[i];
  __syncthreads();
  const float* xin = in + (long)k * inSK;
  int f = threadIdx.x & 63;
  int sub = threadIdx.x >> 6;
  int nb = blockIdx.x * 64;
  for (int rr = 0; rr < 16; ++rr) {
    int n = nb + rr * 4 + sub;
    if (n >= NN) return;
    const float* xr = xin + (long)n * 64;
    float acc = 0.f;
#pragma unroll
    for (int i = 0; i < 64; ++i) acc = fmaf(xr[i], Wl[i * 64 + f], acc);
    out[((long)k * NN + n) * 64 + f] = acc;
  }
}

// ---------------- fused gather + root + bias + relu ----------------
// B[k][n][f] = relu( B[k][n][f] + bias[k][t][f] + sum_{j in CSR[n]} A[k][prow[j]][f]*pnrm[j] )
__global__ __launch_bounds__(256) void k_gather(const int* __restrict__ rowstart,
                                                const int* __restrict__ prow,
                                                const float* __restrict__ pnrm,
                                                const float* __restrict__ A,
                                                float* __restrict__ B,
                                                const float* __restrict__ bias, int t) {
  int wave = threadIdx.x >> 6;
  int f = threadIdx.x & 63;
  int n = blockIdx.x * 4 + wave;
  if (n >= NN) return;
  int s = rowstart[n], e = rowstart[n + 1];
  float a0 = 0.f, a1 = 0.f, a2 = 0.f;
  for (int j = s; j < e; ++j) {
    int r = prow[j];
    float nm = pnrm[j];
    long o = (long)r * 64 + f;
    a0 = fmaf(A[o], nm, a0);
    a1 = fmaf(A[NF + o], nm, a1);
    a2 = fmaf(A[2L * NF + o], nm, a2);
  }
  long o = (long)n * 64 + f;
  float v0 = B[o]           + a0 + bias[(0 * 2 + t) * 64 + f];
  float v1 = B[NF + o]      + a1 + bias[(1 * 2 + t) * 64 + f];
  float v2 = B[2L * NF + o] + a2 + bias[(2 * 2 + t) * 64 + f];
  B[o]           = fmaxf(v0, 0.f);
  B[NF + o]      = fmaxf(v1, 0.f);
  B[2L * NF + o] = fmaxf(v2, 0.f);
}

// ---------------- dst[n,f] = mean_k src[k,n,f]
__global__ void k_mean(const float* __restrict__ src, float* __restrict__ dst) {
  long i4 = (long)blockIdx.x * 256 + threadIdx.x;
  if (i4 >= (long)NF / 4) return;
  long i = i4 * 4;
  float4 a = *(const float4*)(src + i);
  float4 b = *(const float4*)(src + NF + i);
  float4 c = *(const float4*)(src + 2L * NF + i);
  const float s = 1.f / 3.f;
  float4 o;
  o.x = (a.x + b.x + c.x) * s;
  o.y = (a.y + b.y + c.y) * s;
  o.z = (a.z + b.z + c.z) * s;
  o.w = (a.w + b.w + c.w) * s;
  *(float4*)(dst + i) = o;
}

// ---------------- BN stats: per-feature sum & sumsq
__global__ __launch_bounds__(256) void k_bnstats(const float* __restrict__ h,
                                                 float* __restrict__ sum,
                                                 float* __restrict__ sq) {
  int f = threadIdx.x & 63, g = threadIdx.x >> 6;
  float s = 0.f, s2 = 0.f;
  for (int n = blockIdx.x * 4 + g; n < NN; n += gridDim.x * 4) {
    float v = h[(long)n * 64 + f];
    s += v; s2 += v * v;
  }
  __shared__ float ls[512];
  ls[threadIdx.x] = s;
  ls[256 + threadIdx.x] = s2;
  __syncthreads();
  if (threadIdx.x < 64) {
    float ts  = ls[f] + ls[64 + f] + ls[128 + f] + ls[192 + f];
    float ts2 = ls[256 + f] + ls[320 + f] + ls[384 + f] + ls[448 + f];
    atomicAdd(&sum[f], ts);
    atomicAdd(&sq[f], ts2);
  }
}

// ---------------- out = relu(g*(h-mu)*rsqrt(var+eps)+be)
__global__ void k_bnfin(const float* __restrict__ h, const float* __restrict__ sum,
                        const float* __restrict__ sq, const float* __restrict__ gam,
                        const float* __restrict__ bet, float* __restrict__ out) {
  long i4 = (long)blockIdx.x * 256 + threadIdx.x;
  if (i4 >= (long)NF / 4) return;
  long i = i4 * 4;
  int f = (int)(i & 63);
  float4 v = *(const float4*)(h + i);
  float o[4] = {v.x, v.y, v.z, v.w};
  float r[4];
#pragma unroll
  for (int j = 0; j < 4; ++j) {
    int fj = f + j;
    float mu = sum[fj] * (1.f / NN);
    float var = sq[fj] * (1.f / NN) - mu * mu;
    float inv = rsqrtf(var + EPSBN);
    float y = gam[fj] * (o[j] - mu) * inv + bet[fj];
    r[j] = fmaxf(y, 0.f);
  }
  float4 ov = {r[0], r[1], r[2], r[3]};
  *(float4*)(out + i) = ov;
}

extern "C" void kernel_launch(void* const* d_in, const int* in_sizes, int n_in,
                              void* d_out, int out_size, void* d_ws, size_t ws_size,
                              hipStream_t stream) {
  const float* x   = (const float*)d_in[0];
  const int*   ei  = (const int*)d_in[1];
  const float* wts = (const float*)d_in[2];
  const int* row = ei;        // edge_index[0]
  const int* col = ei + NE;   // edge_index[1]

  // workspace layout (4B units)
  char* wsb = (char*)d_ws;
  int*   cnt      = (int*)wsb;                 // NN
  int*   rowstart = cnt + NN;                  // NN+1
  int*   cursor   = rowstart + NN + 1;         // NN
  int*   prow     = cursor + NN;               // NE
  float* pnrm     = (float*)(prow + NE);       // NE
  float* dis      = pnrm + NE;                 // NN
  float* nrm      = dis + NN;                  // NE
  float* h        = nrm + NE;                  // NF
  float* A        = h + NF;                    // KNF
  float* B        = A + KNF;                   // KNF
  float* bns      = B + KNF;                   // 128

  // --- norm + CSR build (once) ---
  hipMemsetAsync(dis, 0, NN * sizeof(float), stream);
  hipMemsetAsync(cnt, 0, NN * sizeof(int), stream);
  int eb = (NE + 255) / 256;
  k_deg<<<eb, 256, 0, stream>>>(col, wts, dis);
  k_dis<<<(NN + 255) / 256, 256, 0, stream>>>(dis);
  k_norm<<<eb, 256, 0, stream>>>(row, col, wts, dis, nrm);
  k_hist<<<eb, 256, 0, stream>>>(col, cnt);
  k_scan<<<1, 1024, 0, stream>>>(cnt, rowstart, cursor);
  k_place<<<eb, 256, 0, stream>>>(row, col, nrm, cursor, prow, pnrm);

  dim3 gg((NN + 63) / 64, KK);
  int gatherBlocks = (NN + 3) / 4;
  int nfBlocks = NF / 4 / 256;      // 6250 exact

  for (int layer = 0; layer < 3; ++layer) {
    const float* iw = (const float*)d_in[3 + 6 * layer];  // [K,F,F]
    const float* w  = (const float*)d_in[4 + 6 * layer];  // [K,1,F,F]
    const float* rw = (const float*)d_in[5 + 6 * layer];  // [K,2,F,F]
    const float* bs = (const float*)d_in[6 + 6 * layer];  // [K,2,1,F]
    const float* gm = (const float*)d_in[7 + 6 * layer];  // [F]
    const float* bt = (const float*)d_in[8 + 6 * layer];  // [F]
    const float* xin = (layer == 0) ? x : h;

    // t=0: A = xin@iw[k]; B = xin@rw[k,0]; B = relu(gather(A) + B + b[:,0])
    k_gemm<<<gg, 256, 0, stream>>>(xin, 0, iw, 4096, A);
    k_gemm<<<gg, 256, 0, stream>>>(xin, 0, rw, 8192, B);
    k_gather<<<gatherBlocks, 256, 0, stream>>>(rowstart, prow, pnrm, A, B, bs, 0);
    // t=1: A = B@w[k,0]; B = xin@rw[k,1]; B = relu(gather(A) + B + b[:,1])
    k_gemm<<<gg, 256, 0, stream>>>(B, NF, w, 4096, A);
    k_gemm<<<gg, 256, 0, stream>>>(xin, 0, rw + 4096, 8192, B);
    k_gather<<<gatherBlocks, 256, 0, stream>>>(rowstart, prow, pnrm, A, B, bs, 1);
    // mean over k + BN + relu
    k_mean<<<nfBlocks, 256, 0, stream>>>(B, A);
    hipMemsetAsync(bns, 0, 2 * 64 * sizeof(float), stream);
    k_bnstats<<<1024, 256, 0, stream>>>(A, bns, bns + 64);
    float* dst = (layer == 2) ? (float*)d_out : h;
    k_bnfin<<<nfBlocks, 256, 0, stream>>>(A, bns, bns + 64, gm, bt, dst);
  }
}

// Round 3
// 3785.804 us; speedup vs baseline: 27.4187x; 1.1778x over previous
//
#include <hip/hip_runtime.h>

#define NN 100000
#define NE 1600000
#define FD 64
#define KK 3
#define NF (NN*FD)            // 6,400,000
#define KNF (KK*NF)           // 19,200,000
#define EPSBN 1e-5f

typedef unsigned short ushort;

__device__ inline float bf2f(ushort u) { return __uint_as_float((unsigned)u << 16); }
__device__ inline unsigned pk_bf16(float a, float b) {
  unsigned ua = __float_as_uint(a); ua += 0x7FFF + ((ua >> 16) & 1);
  unsigned ub = __float_as_uint(b); ub += 0x7FFF + ((ub >> 16) & 1);
  return (ua >> 16) | (ub & 0xFFFF0000u);
}

// ---------------- graph norm + CSR build ----------------
__global__ void k_degcnt(const int* __restrict__ col, const float* __restrict__ w,
                         float* __restrict__ deg, int* __restrict__ cnt) {
  int e = blockIdx.x * 256 + threadIdx.x;
  if (e < NE) { int c = col[e]; atomicAdd(&deg[c], w[e]); atomicAdd(&cnt[c], 1); }
}

__global__ void k_dis(float* __restrict__ deg) {
  int i = blockIdx.x * 256 + threadIdx.x;
  if (i < NN) { float d = deg[i]; deg[i] = d > 0.f ? rsqrtf(d) : 0.f; }
}

// single-block hierarchical exclusive scan of cnt[NN] -> rowstart[NN+1], cursor copy
__global__ __launch_bounds__(1024) void k_scan(const int* __restrict__ cnt,
                                               int* __restrict__ rowstart,
                                               int* __restrict__ cursor) {
  __shared__ int ls[1024];
  int tid = threadIdx.x;
  const int CH = (NN + 1023) / 1024;   // 98
  int lo = tid * CH, hi = lo + CH; if (hi > NN) hi = NN; if (lo > NN) lo = NN;
  int s = 0;
  for (int i = lo; i < hi; ++i) s += cnt[i];
  ls[tid] = s;
  __syncthreads();
  for (int off = 1; off < 1024; off <<= 1) {
    int v = (tid >= off) ? ls[tid - off] : 0;
    __syncthreads();
    ls[tid] += v;
    __syncthreads();
  }
  int run = (tid == 0) ? 0 : ls[tid - 1];
  for (int i = lo; i < hi; ++i) {
    rowstart[i] = run; cursor[i] = run; run += cnt[i];
  }
  if (tid == 1023) rowstart[NN] = run;   // == NE
}

// place edges into CSR-by-col, computing norm inline
__global__ void k_place(const int* __restrict__ row, const int* __restrict__ col,
                        const float* __restrict__ w, const float* __restrict__ dis,
                        int* __restrict__ cursor,
                        int* __restrict__ prow, float* __restrict__ pnrm) {
  int e = blockIdx.x * 256 + threadIdx.x;
  if (e >= NE) return;
  int r = row[e], c = col[e];
  float nm = dis[r] * w[e] * dis[c];
  int p = atomicAdd(&cursor[c], 1);
  prow[p] = r;
  pnrm[p] = nm;
}

// ---------------- fused dual GEMM ----------------
// per stack k=blockIdx.y, per row n:
//   outA[n][k][0:64] (packed bf16) = inA_row(k,n) @ WA[k]
//   outB[k][n][0:64] (f32)         = inB_row(n)   @ WB[k]
// inA planar with k-stride inASK (0 => shared input). inB always shared (x/h).
__global__ __launch_bounds__(256) void k_gemm2(
    const float* __restrict__ inA, long inASK,
    const float* __restrict__ inB,
    const float* __restrict__ WA, long wASK,
    const float* __restrict__ WB, long wBSK,
    ushort* __restrict__ outA, float* __restrict__ outB) {
  __shared__ float WlA[4096];
  __shared__ float WlB[4096];
  int k = blockIdx.y;
  {
    const float* wa = WA + (long)k * wASK;
    const float* wb = WB + (long)k * wBSK;
    for (int i = threadIdx.x; i < 1024; i += 256) {
      *(float4*)(WlA + 4 * i) = *(const float4*)(wa + 4 * i);
      *(float4*)(WlB + 4 * i) = *(const float4*)(wb + 4 * i);
    }
  }
  __syncthreads();
  int n = blockIdx.x * 256 + threadIdx.x;
  if (n >= NN) return;

  // ---- phase A: message operand, bf16 packed [n][k][f] ----
  {
    const float4* rowp = (const float4*)(inA + (long)k * inASK + (long)n * 64);
    unsigned* oa = (unsigned*)(outA + (long)n * 192 + k * 64);
    for (int h = 0; h < 2; ++h) {
      float4 acc[8];
#pragma unroll
      for (int q = 0; q < 8; ++q) acc[q] = float4{0.f, 0.f, 0.f, 0.f};
      for (int i4 = 0; i4 < 16; ++i4) {
        float4 xv = rowp[i4];
        float xs[4] = {xv.x, xv.y, xv.z, xv.w};
#pragma unroll
        for (int sub = 0; sub < 4; ++sub) {
          float xsv = xs[sub];
          const float4* wr = (const float4*)(WlA + (i4 * 4 + sub) * 64 + h * 32);
#pragma unroll
          for (int q = 0; q < 8; ++q) {
            float4 wv = wr[q];
            acc[q].x = fmaf(xsv, wv.x, acc[q].x);
            acc[q].y = fmaf(xsv, wv.y, acc[q].y);
            acc[q].z = fmaf(xsv, wv.z, acc[q].z);
            acc[q].w = fmaf(xsv, wv.w, acc[q].w);
          }
        }
      }
#pragma unroll
      for (int q = 0; q < 8; ++q) {
        oa[h * 16 + q * 2 + 0] = pk_bf16(acc[q].x, acc[q].y);
        oa[h * 16 + q * 2 + 1] = pk_bf16(acc[q].z, acc[q].w);
      }
    }
  }

  // ---- phase B: root term, f32 planar [k][n][f] ----
  {
    const float4* rowp = (const float4*)(inB + (long)n * 64);
    float4* ob = (float4*)(outB + (long)k * NF + (long)n * 64);
    for (int h = 0; h < 2; ++h) {
      float4 acc[8];
#pragma unroll
      for (int q = 0; q < 8; ++q) acc[q] = float4{0.f, 0.f, 0.f, 0.f};
      for (int i4 = 0; i4 < 16; ++i4) {
        float4 xv = rowp[i4];
        float xs[4] = {xv.x, xv.y, xv.z, xv.w};
#pragma unroll
        for (int sub = 0; sub < 4; ++sub) {
          float xsv = xs[sub];
          const float4* wr = (const float4*)(WlB + (i4 * 4 + sub) * 64 + h * 32);
#pragma unroll
          for (int q = 0; q < 8; ++q) {
            float4 wv = wr[q];
            acc[q].x = fmaf(xsv, wv.x, acc[q].x);
            acc[q].y = fmaf(xsv, wv.y, acc[q].y);
            acc[q].z = fmaf(xsv, wv.z, acc[q].z);
            acc[q].w = fmaf(xsv, wv.w, acc[q].w);
          }
        }
      }
#pragma unroll
      for (int q = 0; q < 8; ++q) ob[h * 8 + q] = acc[q];
    }
  }
}

// ---------------- fused gather + root + bias + relu ----------------
// B[k][n][f] = relu( B[k][n][f] + bias[k][t][f] + sum_{j in CSR[n]} bf2f(Abf[prow[j]][k][f])*pnrm[j] )
__global__ __launch_bounds__(256) void k_gather(const int* __restrict__ rowstart,
                                                const int* __restrict__ prow,
                                                const float* __restrict__ pnrm,
                                                const ushort* __restrict__ Abf,
                                                float* __restrict__ B,
                                                const float* __restrict__ bias, int t) {
  int wave = threadIdx.x >> 6;
  int f = threadIdx.x & 63;
  int n = blockIdx.x * 4 + wave;
  if (n >= NN) return;
  int s = rowstart[n], e = rowstart[n + 1];
  float a0 = 0.f, a1 = 0.f, a2 = 0.f;
  for (int j = s; j < e; ++j) {
    int r = prow[j];
    float nm = pnrm[j];
    const ushort* p = Abf + (long)r * 192 + f;
    a0 = fmaf(bf2f(p[0]), nm, a0);
    a1 = fmaf(bf2f(p[64]), nm, a1);
    a2 = fmaf(bf2f(p[128]), nm, a2);
  }
  long o = (long)n * 64 + f;
  float v0 = B[o]           + a0 + bias[(0 * 2 + t) * 64 + f];
  float v1 = B[NF + o]      + a1 + bias[(1 * 2 + t) * 64 + f];
  float v2 = B[2L * NF + o] + a2 + bias[(2 * 2 + t) * 64 + f];
  B[o]           = fmaxf(v0, 0.f);
  B[NF + o]      = fmaxf(v1, 0.f);
  B[2L * NF + o] = fmaxf(v2, 0.f);
}

// ---------------- fused mean-over-k + BN stats ----------------
__global__ __launch_bounds__(256) void k_meanstats(const float* __restrict__ B,
                                                   float* __restrict__ hm,
                                                   float* __restrict__ sum,
                                                   float* __restrict__ sq) {
  int f = threadIdx.x & 63, g = threadIdx.x >> 6;
  float s = 0.f, s2 = 0.f;
  for (int n = blockIdx.x * 4 + g; n < NN; n += gridDim.x * 4) {
    long o = (long)n * 64 + f;
    float v = (B[o] + B[NF + o] + B[2L * NF + o]) * (1.f / 3.f);
    hm[o] = v;
    s += v; s2 += v * v;
  }
  __shared__ float ls[512];
  ls[threadIdx.x] = s;
  ls[256 + threadIdx.x] = s2;
  __syncthreads();
  if (threadIdx.x < 64) {
    float ts  = ls[f] + ls[64 + f] + ls[128 + f] + ls[192 + f];
    float ts2 = ls[256 + f] + ls[320 + f] + ls[384 + f] + ls[448 + f];
    atomicAdd(&sum[f], ts);
    atomicAdd(&sq[f], ts2);
  }
}

// ---------------- out = relu(g*(h-mu)*rsqrt(var+eps)+be)
__global__ void k_bnfin(const float* __restrict__ h, const float* __restrict__ sum,
                        const float* __restrict__ sq, const float* __restrict__ gam,
                        const float* __restrict__ bet, float* __restrict__ out) {
  long i4 = (long)blockIdx.x * 256 + threadIdx.x;
  if (i4 >= (long)NF / 4) return;
  long i = i4 * 4;
  int f = (int)(i & 63);
  float4 v = *(const float4*)(h + i);
  float o[4] = {v.x, v.y, v.z, v.w};
  float r[4];
#pragma unroll
  for (int j = 0; j < 4; ++j) {
    int fj = f + j;
    float mu = sum[fj] * (1.f / NN);
    float var = sq[fj] * (1.f / NN) - mu * mu;
    float inv = rsqrtf(var + EPSBN);
    float y = gam[fj] * (o[j] - mu) * inv + bet[fj];
    r[j] = fmaxf(y, 0.f);
  }
  float4 ov = {r[0], r[1], r[2], r[3]};
  *(float4*)(out + i) = ov;
}

extern "C" void kernel_launch(void* const* d_in, const int* in_sizes, int n_in,
                              void* d_out, int out_size, void* d_ws, size_t ws_size,
                              hipStream_t stream) {
  const float* x   = (const float*)d_in[0];
  const int*   ei  = (const int*)d_in[1];
  const float* wts = (const float*)d_in[2];
  const int* row = ei;        // edge_index[0]
  const int* col = ei + NE;   // edge_index[1]

  // workspace layout (4B units)
  int*   cnt      = (int*)d_ws;                // NN
  int*   rowstart = cnt + NN;                  // NN+1
  int*   cursor   = rowstart + NN + 1;         // NN
  int*   prow     = cursor + NN;               // NE
  float* pnrm     = (float*)(prow + NE);       // NE
  float* dis      = pnrm + NE;                 // NN
  float* h        = dis + NN;                  // NF
  float* B        = h + NF;                    // KNF
  ushort* Abf     = (ushort*)(B + KNF);        // NN*192 ushorts (= NN*96 words)
  float* bns      = (float*)(Abf + (long)NN * 192); // 128

  // --- norm + CSR build (once) ---
  hipMemsetAsync(dis, 0, NN * sizeof(float), stream);
  hipMemsetAsync(cnt, 0, NN * sizeof(int), stream);
  int eb = (NE + 255) / 256;
  k_degcnt<<<eb, 256, 0, stream>>>(col, wts, dis, cnt);
  k_dis<<<(NN + 255) / 256, 256, 0, stream>>>(dis);
  k_scan<<<1, 1024, 0, stream>>>(cnt, rowstart, cursor);
  k_place<<<eb, 256, 0, stream>>>(row, col, wts, dis, cursor, prow, pnrm);

  dim3 gg((NN + 255) / 256, KK);
  int gatherBlocks = (NN + 3) / 4;
  int nfBlocks = NF / 4 / 256;      // 6250 exact

  for (int layer = 0; layer < 3; ++layer) {
    const float* iw = (const float*)d_in[3 + 6 * layer];  // [K,F,F]
    const float* w  = (const float*)d_in[4 + 6 * layer];  // [K,1,F,F]
    const float* rw = (const float*)d_in[5 + 6 * layer];  // [K,2,F,F]
    const float* bs = (const float*)d_in[6 + 6 * layer];  // [K,2,1,F]
    const float* gm = (const float*)d_in[7 + 6 * layer];  // [F]
    const float* bt = (const float*)d_in[8 + 6 * layer];  // [F]
    const float* xin = (layer == 0) ? x : h;

    // t=0: Abf = xin@iw (bf16), B = xin@rw0; B = relu(gather(Abf) + B + b0)
    k_gemm2<<<gg, 256, 0, stream>>>(xin, 0, xin, iw, 4096, rw, 8192, Abf, B);
    k_gather<<<gatherBlocks, 256, 0, stream>>>(rowstart, prow, pnrm, Abf, B, bs, 0);
    // t=1: Abf = B@w (bf16), B = xin@rw1 (in-place safe: row read before write)
    k_gemm2<<<gg, 256, 0, stream>>>(B, NF, xin, w, 4096, rw + 4096, 8192, Abf, B);
    k_gather<<<gatherBlocks, 256, 0, stream>>>(rowstart, prow, pnrm, Abf, B, bs, 1);
    // mean over k (into h) + BN stats + BN finalize + relu
    hipMemsetAsync(bns, 0, 2 * 64 * sizeof(float), stream);
    k_meanstats<<<1024, 256, 0, stream>>>(B, h, bns, bns + 64);
    float* dst = (layer == 2) ? (float*)d_out : h;
    k_bnfin<<<nfBlocks, 256, 0, stream>>>(h, bns, bns + 64, gm, bt, dst);
  }
}

// Round 4
// 2284.116 us; speedup vs baseline: 45.4451x; 1.6574x over previous
//
#include <hip/hip_runtime.h>

#define NN 100000
#define NE 1600000
#define FD 64
#define KK 3
#define NF (NN*FD)            // 6,400,000
#define KNF (KK*NF)           // 19,200,000
#define EPSBN 1e-5f

typedef unsigned short ushort;

__device__ inline float bf2f(ushort u) { return __uint_as_float((unsigned)u << 16); }
__device__ inline unsigned pk_bf16(float a, float b) {
  unsigned ua = __float_as_uint(a); ua += 0x7FFF + ((ua >> 16) & 1);
  unsigned ub = __float_as_uint(b); ub += 0x7FFF + ((ub >> 16) & 1);
  return (ua >> 16) | (ub & 0xFFFF0000u);
}

#define FMA4(A, s, W) do { (A).x = fmaf((s), (W).x, (A).x); (A).y = fmaf((s), (W).y, (A).y); \
                           (A).z = fmaf((s), (W).z, (A).z); (A).w = fmaf((s), (W).w, (A).w); } while (0)

// ---------------- graph norm + CSR build ----------------
__global__ void k_degcnt(const int* __restrict__ col, const float* __restrict__ w,
                         float* __restrict__ deg, int* __restrict__ cnt) {
  int e = blockIdx.x * 256 + threadIdx.x;
  if (e < NE) { int c = col[e]; atomicAdd(&deg[c], w[e]); atomicAdd(&cnt[c], 1); }
}

__global__ void k_dis(float* __restrict__ deg) {
  int i = blockIdx.x * 256 + threadIdx.x;
  if (i < NN) { float d = deg[i]; deg[i] = d > 0.f ? rsqrtf(d) : 0.f; }
}

__global__ __launch_bounds__(1024) void k_scan(const int* __restrict__ cnt,
                                               int* __restrict__ rowstart,
                                               int* __restrict__ cursor) {
  __shared__ int ls[1024];
  int tid = threadIdx.x;
  const int CH = (NN + 1023) / 1024;   // 98
  int lo = tid * CH, hi = lo + CH; if (hi > NN) hi = NN; if (lo > NN) lo = NN;
  int s = 0;
  for (int i = lo; i < hi; ++i) s += cnt[i];
  ls[tid] = s;
  __syncthreads();
  for (int off = 1; off < 1024; off <<= 1) {
    int v = (tid >= off) ? ls[tid - off] : 0;
    __syncthreads();
    ls[tid] += v;
    __syncthreads();
  }
  int run = (tid == 0) ? 0 : ls[tid - 1];
  for (int i = lo; i < hi; ++i) {
    rowstart[i] = run; cursor[i] = run; run += cnt[i];
  }
  if (tid == 1023) rowstart[NN] = run;   // == NE
}

__global__ void k_place(const int* __restrict__ row, const int* __restrict__ col,
                        const float* __restrict__ w, const float* __restrict__ dis,
                        int* __restrict__ cursor,
                        int* __restrict__ prow, float* __restrict__ pnrm) {
  int e = blockIdx.x * 256 + threadIdx.x;
  if (e >= NE) return;
  int r = row[e], c = col[e];
  float nm = dis[r] * w[e] * dis[c];
  int p = atomicAdd(&cursor[c], 1);
  prow[p] = r;
  pnrm[p] = nm;
}

// ---------------- fused dual GEMM, LDS-tiled, register-blocked ----------------
// k = blockIdx.y; per row n:
//   outA[n][k][0:64] (bf16)  = inA_row(k,n) @ WA[k]
//   outB[k][n][0:64] (f32)   = inB_row(n)   @ WB[k]
// Block: 256 rows (4 chunks x 64). Thread tile: 4 rows x 4 cols.
__global__ __launch_bounds__(256) void k_gemm2(
    const float* __restrict__ inA, long inASK,
    const float* __restrict__ inB,
    const float* __restrict__ WA, long wASK,
    const float* __restrict__ WB, long wBSK,
    ushort* __restrict__ outA, float* __restrict__ outB) {
  __shared__ float WlA[4096];
  __shared__ float WlB[4096];
  __shared__ float Xs[2][64 * 68];     // row stride 68 floats (16B-aligned, bank-spread)
  const int t = threadIdx.x;
  const int k = blockIdx.y;
  {
    const float* wa = WA + (long)k * wASK;
    const float* wb = WB + (long)k * wBSK;
    for (int i = t; i < 1024; i += 256) {
      *(float4*)(WlA + 4 * i) = *(const float4*)(wa + 4 * i);
      *(float4*)(WlB + 4 * i) = *(const float4*)(wb + 4 * i);
    }
  }
  const int c4 = t & 15;               // col quad: cols 4*c4..4*c4+3
  const int rg = t >> 4;               // row group: rows rg*4..rg*4+3
  const int blockBase = blockIdx.x * 256;
  const float4 z4 = {0.f, 0.f, 0.f, 0.f};

  for (int ch = 0; ch < 4; ++ch) {
    int base = blockBase + ch * 64;
    if (base >= NN) break;             // uniform across block
    if (ch) __syncthreads();           // previous chunk's compute done before restage
    // ---- stage 64 rows of inA (plane k) and inB, coalesced ----
    for (int p = 0; p < 4; ++p) {
      int j = p * 256 + t;             // 0..1023 float4 slots
      int r = j >> 4, cq = j & 15;
      int n = base + r;
      long go = (long)n * 64 + 4 * cq;
      float4 va = (n < NN) ? *(const float4*)(inA + (long)k * inASK + go) : z4;
      float4 vb = (n < NN) ? *(const float4*)(inB + go) : z4;
      *(float4*)(&Xs[0][r * 68 + 4 * cq]) = va;
      *(float4*)(&Xs[1][r * 68 + 4 * cq]) = vb;
    }
    __syncthreads();

    // ---- phase A: message operand -> bf16 [n][k][f] ----
    {
      float4 a0 = z4, a1 = z4, a2 = z4, a3 = z4;
      for (int i4 = 0; i4 < 16; ++i4) {
        float4 w0 = *(float4*)(WlA + (4 * i4 + 0) * 64 + 4 * c4);
        float4 w1 = *(float4*)(WlA + (4 * i4 + 1) * 64 + 4 * c4);
        float4 w2 = *(float4*)(WlA + (4 * i4 + 2) * 64 + 4 * c4);
        float4 w3 = *(float4*)(WlA + (4 * i4 + 3) * 64 + 4 * c4);
        float4 x0 = *(float4*)(&Xs[0][(rg * 4 + 0) * 68 + 4 * i4]);
        float4 x1 = *(float4*)(&Xs[0][(rg * 4 + 1) * 68 + 4 * i4]);
        float4 x2 = *(float4*)(&Xs[0][(rg * 4 + 2) * 68 + 4 * i4]);
        float4 x3 = *(float4*)(&Xs[0][(rg * 4 + 3) * 68 + 4 * i4]);
        FMA4(a0, x0.x, w0); FMA4(a0, x0.y, w1); FMA4(a0, x0.z, w2); FMA4(a0, x0.w, w3);
        FMA4(a1, x1.x, w0); FMA4(a1, x1.y, w1); FMA4(a1, x1.z, w2); FMA4(a1, x1.w, w3);
        FMA4(a2, x2.x, w0); FMA4(a2, x2.y, w1); FMA4(a2, x2.z, w2); FMA4(a2, x2.w, w3);
        FMA4(a3, x3.x, w0); FMA4(a3, x3.y, w1); FMA4(a3, x3.z, w2); FMA4(a3, x3.w, w3);
      }
      int n0 = base + rg * 4;
      float4 aa[4] = {a0, a1, a2, a3};
#pragma unroll
      for (int j = 0; j < 4; ++j) {
        int n = n0 + j;
        if (n < NN) {
          uint2 u;
          u.x = pk_bf16(aa[j].x, aa[j].y);
          u.y = pk_bf16(aa[j].z, aa[j].w);
          *(uint2*)(outA + (long)n * 192 + k * 64 + 4 * c4) = u;
        }
      }
    }

    // ---- phase B: root term -> f32 [k][n][f] ----
    {
      float4 a0 = z4, a1 = z4, a2 = z4, a3 = z4;
      for (int i4 = 0; i4 < 16; ++i4) {
        float4 w0 = *(float4*)(WlB + (4 * i4 + 0) * 64 + 4 * c4);
        float4 w1 = *(float4*)(WlB + (4 * i4 + 1) * 64 + 4 * c4);
        float4 w2 = *(float4*)(WlB + (4 * i4 + 2) * 64 + 4 * c4);
        float4 w3 = *(float4*)(WlB + (4 * i4 + 3) * 64 + 4 * c4);
        float4 x0 = *(float4*)(&Xs[1][(rg * 4 + 0) * 68 + 4 * i4]);
        float4 x1 = *(float4*)(&Xs[1][(rg * 4 + 1) * 68 + 4 * i4]);
        float4 x2 = *(float4*)(&Xs[1][(rg * 4 + 2) * 68 + 4 * i4]);
        float4 x3 = *(float4*)(&Xs[1][(rg * 4 + 3) * 68 + 4 * i4]);
        FMA4(a0, x0.x, w0); FMA4(a0, x0.y, w1); FMA4(a0, x0.z, w2); FMA4(a0, x0.w, w3);
        FMA4(a1, x1.x, w0); FMA4(a1, x1.y, w1); FMA4(a1, x1.z, w2); FMA4(a1, x1.w, w3);
        FMA4(a2, x2.x, w0); FMA4(a2, x2.y, w1); FMA4(a2, x2.z, w2); FMA4(a2, x2.w, w3);
        FMA4(a3, x3.x, w0); FMA4(a3, x3.y, w1); FMA4(a3, x3.z, w2); FMA4(a3, x3.w, w3);
      }
      int n0 = base + rg * 4;
      float4 aa[4] = {a0, a1, a2, a3};
#pragma unroll
      for (int j = 0; j < 4; ++j) {
        int n = n0 + j;
        if (n < NN)
          *(float4*)(outB + (long)k * NF + (long)n * 64 + 4 * c4) = aa[j];
      }
    }
  }
}

// ---------------- fused gather + root + bias + relu ----------------
__global__ __launch_bounds__(256) void k_gather(const int* __restrict__ rowstart,
                                                const int* __restrict__ prow,
                                                const float* __restrict__ pnrm,
                                                const ushort* __restrict__ Abf,
                                                float* __restrict__ B,
                                                const float* __restrict__ bias, int t) {
  int wave = threadIdx.x >> 6;
  int f = threadIdx.x & 63;
  int n = blockIdx.x * 4 + wave;
  if (n >= NN) return;
  int s = rowstart[n], e = rowstart[n + 1];
  float a0 = 0.f, a1 = 0.f, a2 = 0.f;
  for (int j = s; j < e; ++j) {
    int r = prow[j];
    float nm = pnrm[j];
    const ushort* p = Abf + (long)r * 192 + f;
    a0 = fmaf(bf2f(p[0]), nm, a0);
    a1 = fmaf(bf2f(p[64]), nm, a1);
    a2 = fmaf(bf2f(p[128]), nm, a2);
  }
  long o = (long)n * 64 + f;
  float v0 = B[o]           + a0 + bias[(0 * 2 + t) * 64 + f];
  float v1 = B[NF + o]      + a1 + bias[(1 * 2 + t) * 64 + f];
  float v2 = B[2L * NF + o] + a2 + bias[(2 * 2 + t) * 64 + f];
  B[o]           = fmaxf(v0, 0.f);
  B[NF + o]      = fmaxf(v1, 0.f);
  B[2L * NF + o] = fmaxf(v2, 0.f);
}

// ---------------- fused mean-over-k + BN stats ----------------
__global__ __launch_bounds__(256) void k_meanstats(const float* __restrict__ B,
                                                   float* __restrict__ hm,
                                                   float* __restrict__ sum,
                                                   float* __restrict__ sq) {
  int f = threadIdx.x & 63, g = threadIdx.x >> 6;
  float s = 0.f, s2 = 0.f;
  for (int n = blockIdx.x * 4 + g; n < NN; n += gridDim.x * 4) {
    long o = (long)n * 64 + f;
    float v = (B[o] + B[NF + o] + B[2L * NF + o]) * (1.f / 3.f);
    hm[o] = v;
    s += v; s2 += v * v;
  }
  __shared__ float ls[512];
  ls[threadIdx.x] = s;
  ls[256 + threadIdx.x] = s2;
  __syncthreads();
  if (threadIdx.x < 64) {
    float ts  = ls[f] + ls[64 + f] + ls[128 + f] + ls[192 + f];
    float ts2 = ls[256 + f] + ls[320 + f] + ls[384 + f] + ls[448 + f];
    atomicAdd(&sum[f], ts);
    atomicAdd(&sq[f], ts2);
  }
}

// ---------------- out = relu(g*(h-mu)*rsqrt(var+eps)+be)
__global__ void k_bnfin(const float* __restrict__ h, const float* __restrict__ sum,
                        const float* __restrict__ sq, const float* __restrict__ gam,
                        const float* __restrict__ bet, float* __restrict__ out) {
  long i4 = (long)blockIdx.x * 256 + threadIdx.x;
  if (i4 >= (long)NF / 4) return;
  long i = i4 * 4;
  int f = (int)(i & 63);
  float4 v = *(const float4*)(h + i);
  float o[4] = {v.x, v.y, v.z, v.w};
  float r[4];
#pragma unroll
  for (int j = 0; j < 4; ++j) {
    int fj = f + j;
    float mu = sum[fj] * (1.f / NN);
    float var = sq[fj] * (1.f / NN) - mu * mu;
    float inv = rsqrtf(var + EPSBN);
    float y = gam[fj] * (o[j] - mu) * inv + bet[fj];
    r[j] = fmaxf(y, 0.f);
  }
  float4 ov = {r[0], r[1], r[2], r[3]};
  *(float4*)(out + i) = ov;
}

extern "C" void kernel_launch(void* const* d_in, const int* in_sizes, int n_in,
                              void* d_out, int out_size, void* d_ws, size_t ws_size,
                              hipStream_t stream) {
  const float* x   = (const float*)d_in[0];
  const int*   ei  = (const int*)d_in[1];
  const float* wts = (const float*)d_in[2];
  const int* row = ei;        // edge_index[0]
  const int* col = ei + NE;   // edge_index[1]

  // workspace layout (4B units)
  int*   cnt      = (int*)d_ws;                // NN
  int*   rowstart = cnt + NN;                  // NN+1
  int*   cursor   = rowstart + NN + 1;         // NN
  int*   prow     = cursor + NN;               // NE
  float* pnrm     = (float*)(prow + NE);       // NE
  float* dis      = pnrm + NE;                 // NN
  float* h        = dis + NN;                  // NF
  float* B        = h + NF;                    // KNF
  ushort* Abf     = (ushort*)(B + KNF);        // NN*192 ushorts
  float* bns      = (float*)(Abf + (long)NN * 192); // 128

  // --- norm + CSR build (once) ---
  hipMemsetAsync(dis, 0, NN * sizeof(float), stream);
  hipMemsetAsync(cnt, 0, NN * sizeof(int), stream);
  int eb = (NE + 255) / 256;
  k_degcnt<<<eb, 256, 0, stream>>>(col, wts, dis, cnt);
  k_dis<<<(NN + 255) / 256, 256, 0, stream>>>(dis);
  k_scan<<<1, 1024, 0, stream>>>(cnt, rowstart, cursor);
  k_place<<<eb, 256, 0, stream>>>(row, col, wts, dis, cursor, prow, pnrm);

  dim3 gg((NN + 255) / 256, KK);
  int gatherBlocks = (NN + 3) / 4;
  int nfBlocks = NF / 4 / 256;      // 6250 exact

  for (int layer = 0; layer < 3; ++layer) {
    const float* iw = (const float*)d_in[3 + 6 * layer];  // [K,F,F]
    const float* w  = (const float*)d_in[4 + 6 * layer];  // [K,1,F,F]
    const float* rw = (const float*)d_in[5 + 6 * layer];  // [K,2,F,F]
    const float* bs = (const float*)d_in[6 + 6 * layer];  // [K,2,1,F]
    const float* gm = (const float*)d_in[7 + 6 * layer];  // [F]
    const float* bt = (const float*)d_in[8 + 6 * layer];  // [F]
    const float* xin = (layer == 0) ? x : h;

    // t=0: Abf = xin@iw (bf16), B = xin@rw0; B = relu(gather(Abf) + B + b0)
    k_gemm2<<<gg, 256, 0, stream>>>(xin, 0, xin, iw, 4096, rw, 8192, Abf, B);
    k_gather<<<gatherBlocks, 256, 0, stream>>>(rowstart, prow, pnrm, Abf, B, bs, 0);
    // t=1: Abf = B@w (bf16), B = xin@rw1 (in-place safe: rows staged before written)
    k_gemm2<<<gg, 256, 0, stream>>>(B, NF, xin, w, 4096, rw + 4096, 8192, Abf, B);
    k_gather<<<gatherBlocks, 256, 0, stream>>>(rowstart, prow, pnrm, Abf, B, bs, 1);
    // mean over k (into h) + BN stats + BN finalize + relu
    hipMemsetAsync(bns, 0, 2 * 64 * sizeof(float), stream);
    k_meanstats<<<1024, 256, 0, stream>>>(B, h, bns, bns + 64);
    float* dst = (layer == 2) ? (float*)d_out : h;
    k_bnfin<<<nfBlocks, 256, 0, stream>>>(h, bns, bns + 64, gm, bt, dst);
  }
}

// Round 5
// 1702.565 us; speedup vs baseline: 60.9679x; 1.3416x over previous
//
#include <hip/hip_runtime.h>

#define NN 100000
#define NE 1600000
#define FD 64
#define KK 3
#define NF (NN*FD)            // 6,400,000
#define KNF (KK*NF)           // 19,200,000
#define EPSBN 1e-5f
#define SBLK ((NN + 255) / 256)   // 391 scan blocks

typedef unsigned short ushort;

__device__ inline float bf2f(ushort u) { return __uint_as_float((unsigned)u << 16); }
__device__ inline unsigned pk_bf16(float a, float b) {
  unsigned ua = __float_as_uint(a); ua += 0x7FFF + ((ua >> 16) & 1);
  unsigned ub = __float_as_uint(b); ub += 0x7FFF + ((ub >> 16) & 1);
  return (ua >> 16) | (ub & 0xFFFF0000u);
}

#define FMA4(A, s, W) do { (A).x = fmaf((s), (W).x, (A).x); (A).y = fmaf((s), (W).y, (A).y); \
                           (A).z = fmaf((s), (W).z, (A).z); (A).w = fmaf((s), (W).w, (A).w); } while (0)

// ---------------- graph norm + CSR build ----------------
__global__ void k_degcnt(const int* __restrict__ col, const float* __restrict__ w,
                         float* __restrict__ deg, int* __restrict__ cnt) {
  int e = blockIdx.x * 256 + threadIdx.x;
  if (e < NE) { int c = col[e]; atomicAdd(&deg[c], w[e]); atomicAdd(&cnt[c], 1); }
}

__global__ void k_dis(float* __restrict__ deg) {
  int i = blockIdx.x * 256 + threadIdx.x;
  if (i < NN) { float d = deg[i]; deg[i] = d > 0.f ? rsqrtf(d) : 0.f; }
}

// ---- multi-block exclusive scan of cnt[NN] -> rowstart[NN+1] (+cursor copy) ----
__global__ __launch_bounds__(256) void k_sblk(const int* __restrict__ cnt,
                                              int* __restrict__ part) {
  int i = blockIdx.x * 256 + threadIdx.x;
  int v = (i < NN) ? cnt[i] : 0;
#pragma unroll
  for (int off = 32; off; off >>= 1) v += __shfl_down(v, off);
  __shared__ int ws[4];
  if ((threadIdx.x & 63) == 0) ws[threadIdx.x >> 6] = v;
  __syncthreads();
  if (threadIdx.x == 0) part[blockIdx.x] = ws[0] + ws[1] + ws[2] + ws[3];
}

__global__ __launch_bounds__(512) void k_sscan(const int* __restrict__ part,
                                               int* __restrict__ base) {
  __shared__ int ls[512];
  int tid = threadIdx.x;
  int v = (tid < SBLK) ? part[tid] : 0;
  ls[tid] = v;
  __syncthreads();
  for (int off = 1; off < 512; off <<= 1) {
    int u = (tid >= off) ? ls[tid - off] : 0;
    __syncthreads();
    ls[tid] += u;
    __syncthreads();
  }
  base[tid] = tid ? ls[tid - 1] : 0;     // exclusive block base
}

__global__ __launch_bounds__(256) void k_sfin(const int* __restrict__ cnt,
                                              const int* __restrict__ base,
                                              int* __restrict__ rowstart,
                                              int* __restrict__ cursor) {
  __shared__ int ls[256];
  int i = blockIdx.x * 256 + threadIdx.x;
  int v = (i < NN) ? cnt[i] : 0;
  ls[threadIdx.x] = v;
  __syncthreads();
  for (int off = 1; off < 256; off <<= 1) {
    int u = (threadIdx.x >= off) ? ls[threadIdx.x - off] : 0;
    __syncthreads();
    ls[threadIdx.x] += u;
    __syncthreads();
  }
  int excl = base[blockIdx.x] + ls[threadIdx.x] - v;
  if (i < NN) {
    rowstart[i] = excl;
    cursor[i] = excl;
    if (i == NN - 1) rowstart[NN] = excl + v;   // == NE
  }
}

// place edges into CSR-by-col, norm inline, packed (row, norm)
__global__ void k_place(const int* __restrict__ row, const int* __restrict__ col,
                        const float* __restrict__ w, const float* __restrict__ dis,
                        int* __restrict__ cursor, int2* __restrict__ edges) {
  int e = blockIdx.x * 256 + threadIdx.x;
  if (e >= NE) return;
  int r = row[e], c = col[e];
  float nm = dis[r] * w[e] * dis[c];
  int p = atomicAdd(&cursor[c], 1);
  edges[p] = make_int2(r, __float_as_int(nm));
}

// ---------------- fused dual GEMM, LDS-tiled, register-blocked ----------------
__global__ __launch_bounds__(256) void k_gemm2(
    const float* __restrict__ inA, long inASK,
    const float* __restrict__ inB,
    const float* __restrict__ WA, long wASK,
    const float* __restrict__ WB, long wBSK,
    ushort* __restrict__ outA, float* __restrict__ outB) {
  __shared__ float WlA[4096];
  __shared__ float WlB[4096];
  __shared__ float Xs[2][64 * 68];
  const int t = threadIdx.x;
  const int k = blockIdx.y;
  {
    const float* wa = WA + (long)k * wASK;
    const float* wb = WB + (long)k * wBSK;
    for (int i = t; i < 1024; i += 256) {
      *(float4*)(WlA + 4 * i) = *(const float4*)(wa + 4 * i);
      *(float4*)(WlB + 4 * i) = *(const float4*)(wb + 4 * i);
    }
  }
  const int c4 = t & 15;
  const int rg = t >> 4;
  const int blockBase = blockIdx.x * 256;
  const float4 z4 = {0.f, 0.f, 0.f, 0.f};

  for (int ch = 0; ch < 4; ++ch) {
    int base = blockBase + ch * 64;
    if (base >= NN) break;
    if (ch) __syncthreads();
    for (int p = 0; p < 4; ++p) {
      int j = p * 256 + t;
      int r = j >> 4, cq = j & 15;
      int n = base + r;
      long go = (long)n * 64 + 4 * cq;
      float4 va = (n < NN) ? *(const float4*)(inA + (long)k * inASK + go) : z4;
      float4 vb = (n < NN) ? *(const float4*)(inB + go) : z4;
      *(float4*)(&Xs[0][r * 68 + 4 * cq]) = va;
      *(float4*)(&Xs[1][r * 68 + 4 * cq]) = vb;
    }
    __syncthreads();

    // ---- phase A: message operand -> bf16 [n][k][f] ----
    {
      float4 a0 = z4, a1 = z4, a2 = z4, a3 = z4;
      for (int i4 = 0; i4 < 16; ++i4) {
        float4 w0 = *(float4*)(WlA + (4 * i4 + 0) * 64 + 4 * c4);
        float4 w1 = *(float4*)(WlA + (4 * i4 + 1) * 64 + 4 * c4);
        float4 w2 = *(float4*)(WlA + (4 * i4 + 2) * 64 + 4 * c4);
        float4 w3 = *(float4*)(WlA + (4 * i4 + 3) * 64 + 4 * c4);
        float4 x0 = *(float4*)(&Xs[0][(rg * 4 + 0) * 68 + 4 * i4]);
        float4 x1 = *(float4*)(&Xs[0][(rg * 4 + 1) * 68 + 4 * i4]);
        float4 x2 = *(float4*)(&Xs[0][(rg * 4 + 2) * 68 + 4 * i4]);
        float4 x3 = *(float4*)(&Xs[0][(rg * 4 + 3) * 68 + 4 * i4]);
        FMA4(a0, x0.x, w0); FMA4(a0, x0.y, w1); FMA4(a0, x0.z, w2); FMA4(a0, x0.w, w3);
        FMA4(a1, x1.x, w0); FMA4(a1, x1.y, w1); FMA4(a1, x1.z, w2); FMA4(a1, x1.w, w3);
        FMA4(a2, x2.x, w0); FMA4(a2, x2.y, w1); FMA4(a2, x2.z, w2); FMA4(a2, x2.w, w3);
        FMA4(a3, x3.x, w0); FMA4(a3, x3.y, w1); FMA4(a3, x3.z, w2); FMA4(a3, x3.w, w3);
      }
      int n0 = base + rg * 4;
      float4 aa[4] = {a0, a1, a2, a3};
#pragma unroll
      for (int j = 0; j < 4; ++j) {
        int n = n0 + j;
        if (n < NN) {
          uint2 u;
          u.x = pk_bf16(aa[j].x, aa[j].y);
          u.y = pk_bf16(aa[j].z, aa[j].w);
          *(uint2*)(outA + (long)n * 192 + k * 64 + 4 * c4) = u;
        }
      }
    }

    // ---- phase B: root term -> f32 [k][n][f] ----
    {
      float4 a0 = z4, a1 = z4, a2 = z4, a3 = z4;
      for (int i4 = 0; i4 < 16; ++i4) {
        float4 w0 = *(float4*)(WlB + (4 * i4 + 0) * 64 + 4 * c4);
        float4 w1 = *(float4*)(WlB + (4 * i4 + 1) * 64 + 4 * c4);
        float4 w2 = *(float4*)(WlB + (4 * i4 + 2) * 64 + 4 * c4);
        float4 w3 = *(float4*)(WlB + (4 * i4 + 3) * 64 + 4 * c4);
        float4 x0 = *(float4*)(&Xs[1][(rg * 4 + 0) * 68 + 4 * i4]);
        float4 x1 = *(float4*)(&Xs[1][(rg * 4 + 1) * 68 + 4 * i4]);
        float4 x2 = *(float4*)(&Xs[1][(rg * 4 + 2) * 68 + 4 * i4]);
        float4 x3 = *(float4*)(&Xs[1][(rg * 4 + 3) * 68 + 4 * i4]);
        FMA4(a0, x0.x, w0); FMA4(a0, x0.y, w1); FMA4(a0, x0.z, w2); FMA4(a0, x0.w, w3);
        FMA4(a1, x1.x, w0); FMA4(a1, x1.y, w1); FMA4(a1, x1.z, w2); FMA4(a1, x1.w, w3);
        FMA4(a2, x2.x, w0); FMA4(a2, x2.y, w1); FMA4(a2, x2.z, w2); FMA4(a2, x2.w, w3);
        FMA4(a3, x3.x, w0); FMA4(a3, x3.y, w1); FMA4(a3, x3.z, w2); FMA4(a3, x3.w, w3);
      }
      int n0 = base + rg * 4;
      float4 aa[4] = {a0, a1, a2, a3};
#pragma unroll
      for (int j = 0; j < 4; ++j) {
        int n = n0 + j;
        if (n < NN)
          *(float4*)(outB + (long)k * NF + (long)n * 64 + 4 * c4) = aa[j];
      }
    }
  }
}

// ---------------- fused gather + root + bias + relu (+ optional k-mean) ----------------
// MODE 0: B[k][n][f] = relu(B + msg + bias)      MODE 1: hm[n][f] = mean_k relu(B + msg + bias)
template <int MODE>
__global__ __launch_bounds__(256) void k_gather(const int* __restrict__ rowstart,
                                                const int2* __restrict__ edges,
                                                const ushort* __restrict__ Abf,
                                                float* __restrict__ B,
                                                float* __restrict__ hm,
                                                const float* __restrict__ bias, int t) {
  int wave = threadIdx.x >> 6;
  int f = threadIdx.x & 63;
  int n = blockIdx.x * 4 + wave;
  if (n >= NN) return;
  int s = rowstart[n], e = rowstart[n + 1];
  float a0 = 0.f, a1 = 0.f, a2 = 0.f;
  int j = s;
  for (; j + 4 <= e; j += 4) {
    int2 e0 = edges[j], e1 = edges[j + 1], e2 = edges[j + 2], e3 = edges[j + 3];
    const ushort* p0 = Abf + (long)e0.x * 192 + f;
    const ushort* p1 = Abf + (long)e1.x * 192 + f;
    const ushort* p2 = Abf + (long)e2.x * 192 + f;
    const ushort* p3 = Abf + (long)e3.x * 192 + f;
    ushort u00 = p0[0], u01 = p0[64], u02 = p0[128];
    ushort u10 = p1[0], u11 = p1[64], u12 = p1[128];
    ushort u20 = p2[0], u21 = p2[64], u22 = p2[128];
    ushort u30 = p3[0], u31 = p3[64], u32 = p3[128];
    float m0 = __int_as_float(e0.y), m1 = __int_as_float(e1.y);
    float m2 = __int_as_float(e2.y), m3 = __int_as_float(e3.y);
    a0 = fmaf(bf2f(u00), m0, a0); a1 = fmaf(bf2f(u01), m0, a1); a2 = fmaf(bf2f(u02), m0, a2);
    a0 = fmaf(bf2f(u10), m1, a0); a1 = fmaf(bf2f(u11), m1, a1); a2 = fmaf(bf2f(u12), m1, a2);
    a0 = fmaf(bf2f(u20), m2, a0); a1 = fmaf(bf2f(u21), m2, a1); a2 = fmaf(bf2f(u22), m2, a2);
    a0 = fmaf(bf2f(u30), m3, a0); a1 = fmaf(bf2f(u31), m3, a1); a2 = fmaf(bf2f(u32), m3, a2);
  }
  for (; j < e; ++j) {
    int2 eh = edges[j];
    float nm = __int_as_float(eh.y);
    const ushort* p = Abf + (long)eh.x * 192 + f;
    a0 = fmaf(bf2f(p[0]), nm, a0);
    a1 = fmaf(bf2f(p[64]), nm, a1);
    a2 = fmaf(bf2f(p[128]), nm, a2);
  }
  long o = (long)n * 64 + f;
  float v0 = fmaxf(B[o]           + a0 + bias[(0 * 2 + t) * 64 + f], 0.f);
  float v1 = fmaxf(B[NF + o]      + a1 + bias[(1 * 2 + t) * 64 + f], 0.f);
  float v2 = fmaxf(B[2L * NF + o] + a2 + bias[(2 * 2 + t) * 64 + f], 0.f);
  if (MODE == 0) {
    B[o] = v0; B[NF + o] = v1; B[2L * NF + o] = v2;
  } else {
    hm[o] = (v0 + v1 + v2) * (1.f / 3.f);
  }
}

// ---------------- BN stats on h ----------------
__global__ __launch_bounds__(256) void k_bnstats(const float* __restrict__ h,
                                                 float* __restrict__ sum,
                                                 float* __restrict__ sq) {
  int f = threadIdx.x & 63, g = threadIdx.x >> 6;
  float s = 0.f, s2 = 0.f;
  for (int n = blockIdx.x * 4 + g; n < NN; n += gridDim.x * 4) {
    float v = h[(long)n * 64 + f];
    s += v; s2 += v * v;
  }
  __shared__ float ls[512];
  ls[threadIdx.x] = s;
  ls[256 + threadIdx.x] = s2;
  __syncthreads();
  if (threadIdx.x < 64) {
    float ts  = ls[f] + ls[64 + f] + ls[128 + f] + ls[192 + f];
    float ts2 = ls[256 + f] + ls[320 + f] + ls[384 + f] + ls[448 + f];
    atomicAdd(&sum[f], ts);
    atomicAdd(&sq[f], ts2);
  }
}

// ---------------- out = relu(g*(h-mu)*rsqrt(var+eps)+be)
__global__ void k_bnfin(const float* __restrict__ h, const float* __restrict__ sum,
                        const float* __restrict__ sq, const float* __restrict__ gam,
                        const float* __restrict__ bet, float* __restrict__ out) {
  long i4 = (long)blockIdx.x * 256 + threadIdx.x;
  if (i4 >= (long)NF / 4) return;
  long i = i4 * 4;
  int f = (int)(i & 63);
  float4 v = *(const float4*)(h + i);
  float o[4] = {v.x, v.y, v.z, v.w};
  float r[4];
#pragma unroll
  for (int j = 0; j < 4; ++j) {
    int fj = f + j;
    float mu = sum[fj] * (1.f / NN);
    float var = sq[fj] * (1.f / NN) - mu * mu;
    float inv = rsqrtf(var + EPSBN);
    float y = gam[fj] * (o[j] - mu) * inv + bet[fj];
    r[j] = fmaxf(y, 0.f);
  }
  float4 ov = {r[0], r[1], r[2], r[3]};
  *(float4*)(out + i) = ov;
}

extern "C" void kernel_launch(void* const* d_in, const int* in_sizes, int n_in,
                              void* d_out, int out_size, void* d_ws, size_t ws_size,
                              hipStream_t stream) {
  const float* x   = (const float*)d_in[0];
  const int*   ei  = (const int*)d_in[1];
  const float* wts = (const float*)d_in[2];
  const int* row = ei;        // edge_index[0]
  const int* col = ei + NE;   // edge_index[1]

  // workspace layout (4B units)
  int*   cnt      = (int*)d_ws;                // NN
  int*   rowstart = cnt + NN;                  // NN+1
  int*   cursor   = rowstart + NN + 1;         // NN
  int2*  edges    = (int2*)(cursor + NN);      // NE int2 (2*NE words)
  float* dis      = (float*)(edges + NE);      // NN
  float* h        = dis + NN;                  // NF
  float* B        = h + NF;                    // KNF
  ushort* Abf     = (ushort*)(B + KNF);        // NN*192 ushorts
  float* bns      = (float*)(Abf + (long)NN * 192); // 128
  int*   part     = (int*)(bns + 128);         // 512
  int*   pbase    = part + 512;                // 512

  // --- norm + CSR build (once) ---
  hipMemsetAsync(dis, 0, NN * sizeof(float), stream);
  hipMemsetAsync(cnt, 0, NN * sizeof(int), stream);
  int eb = (NE + 255) / 256;
  k_degcnt<<<eb, 256, 0, stream>>>(col, wts, dis, cnt);
  k_dis<<<(NN + 255) / 256, 256, 0, stream>>>(dis);
  k_sblk<<<SBLK, 256, 0, stream>>>(cnt, part);
  k_sscan<<<1, 512, 0, stream>>>(part, pbase);
  k_sfin<<<SBLK, 256, 0, stream>>>(cnt, pbase, rowstart, cursor);
  k_place<<<eb, 256, 0, stream>>>(row, col, wts, dis, cursor, edges);

  dim3 gg((NN + 255) / 256, KK);
  int gatherBlocks = (NN + 3) / 4;
  int nfBlocks = NF / 4 / 256;      // 6250 exact

  for (int layer = 0; layer < 3; ++layer) {
    const float* iw = (const float*)d_in[3 + 6 * layer];  // [K,F,F]
    const float* w  = (const float*)d_in[4 + 6 * layer];  // [K,1,F,F]
    const float* rw = (const float*)d_in[5 + 6 * layer];  // [K,2,F,F]
    const float* bs = (const float*)d_in[6 + 6 * layer];  // [K,2,1,F]
    const float* gm = (const float*)d_in[7 + 6 * layer];  // [F]
    const float* bt = (const float*)d_in[8 + 6 * layer];  // [F]
    const float* xin = (layer == 0) ? x : h;

    // t=0: Abf = xin@iw (bf16), B = xin@rw0; B = relu(gather(Abf) + B + b0)
    k_gemm2<<<gg, 256, 0, stream>>>(xin, 0, xin, iw, 4096, rw, 8192, Abf, B);
    k_gather<0><<<gatherBlocks, 256, 0, stream>>>(rowstart, edges, Abf, B, h, bs, 0);
    // t=1: Abf = B@w (bf16), B = xin@rw1; h = mean_k relu(gather(Abf) + B + b1)
    k_gemm2<<<gg, 256, 0, stream>>>(B, NF, xin, w, 4096, rw + 4096, 8192, Abf, B);
    k_gather<1><<<gatherBlocks, 256, 0, stream>>>(rowstart, edges, Abf, B, h, bs, 1);
    // BN stats + finalize + relu
    hipMemsetAsync(bns, 0, 2 * 64 * sizeof(float), stream);
    k_bnstats<<<1024, 256, 0, stream>>>(h, bns, bns + 64);
    float* dst = (layer == 2) ? (float*)d_out : h;
    k_bnfin<<<nfBlocks, 256, 0, stream>>>(h, bns, bns + 64, gm, bt, dst);
  }
}

// Round 6
// 1602.420 us; speedup vs baseline: 64.7781x; 1.0625x over previous
//
#include <hip/hip_runtime.h>

#define NN 100000
#define NE 1600000
#define FD 64
#define KK 3
#define NF (NN*FD)            // 6,400,000
#define KNF (KK*NF)           // 19,200,000
#define EPSBN 1e-5f
#define SBLK ((NN + 255) / 256)   // 391 scan blocks
#define DEGSCALE 262144.0f        // 2^18 fixed-point for weighted degree

typedef unsigned short ushort;
typedef unsigned int uint;

__device__ inline float bf2f(ushort u) { return __uint_as_float((unsigned)u << 16); }
__device__ inline unsigned pk_bf16(float a, float b) {
  unsigned ua = __float_as_uint(a); ua += 0x7FFF + ((ua >> 16) & 1);
  unsigned ub = __float_as_uint(b); ub += 0x7FFF + ((ub >> 16) & 1);
  return (ua >> 16) | (ub & 0xFFFF0000u);
}

#define FMA4(A, s, W) do { (A).x = fmaf((s), (W).x, (A).x); (A).y = fmaf((s), (W).y, (A).y); \
                           (A).z = fmaf((s), (W).z, (A).z); (A).w = fmaf((s), (W).w, (A).w); } while (0)

// ---------------- graph norm + CSR build ----------------
// one 64-bit atomic per edge: hi32 = edge count, lo32 = fixed-point weighted degree
__global__ void k_degcnt(const int* __restrict__ col, const float* __restrict__ w,
                         unsigned long long* __restrict__ dc) {
  int e = blockIdx.x * 256 + threadIdx.x;
  if (e < NE) {
    unsigned fx = __float2uint_rn(w[e] * DEGSCALE);
    atomicAdd(&dc[col[e]], (1ULL << 32) | (unsigned long long)fx);
  }
}

__global__ void k_dis(const unsigned long long* __restrict__ dc,
                      float* __restrict__ dis, int* __restrict__ cnt) {
  int i = blockIdx.x * 256 + threadIdx.x;
  if (i < NN) {
    unsigned long long v = dc[i];
    float d = (float)(unsigned)v * (1.0f / DEGSCALE);
    dis[i] = d > 0.f ? rsqrtf(d) : 0.f;
    cnt[i] = (int)(v >> 32);
  }
}

// ---- multi-block exclusive scan of cnt[NN] -> rowstart[NN+1] (+cursor copy) ----
__global__ __launch_bounds__(256) void k_sblk(const int* __restrict__ cnt,
                                              int* __restrict__ part) {
  int i = blockIdx.x * 256 + threadIdx.x;
  int v = (i < NN) ? cnt[i] : 0;
#pragma unroll
  for (int off = 32; off; off >>= 1) v += __shfl_down(v, off);
  __shared__ int ws[4];
  if ((threadIdx.x & 63) == 0) ws[threadIdx.x >> 6] = v;
  __syncthreads();
  if (threadIdx.x == 0) part[blockIdx.x] = ws[0] + ws[1] + ws[2] + ws[3];
}

__global__ __launch_bounds__(512) void k_sscan(const int* __restrict__ part,
                                               int* __restrict__ base) {
  __shared__ int ls[512];
  int tid = threadIdx.x;
  int v = (tid < SBLK) ? part[tid] : 0;
  ls[tid] = v;
  __syncthreads();
  for (int off = 1; off < 512; off <<= 1) {
    int u = (tid >= off) ? ls[tid - off] : 0;
    __syncthreads();
    ls[tid] += u;
    __syncthreads();
  }
  base[tid] = tid ? ls[tid - 1] : 0;
}

__global__ __launch_bounds__(256) void k_sfin(const int* __restrict__ cnt,
                                              const int* __restrict__ base,
                                              int* __restrict__ rowstart,
                                              int* __restrict__ cursor) {
  __shared__ int ls[256];
  int i = blockIdx.x * 256 + threadIdx.x;
  int v = (i < NN) ? cnt[i] : 0;
  ls[threadIdx.x] = v;
  __syncthreads();
  for (int off = 1; off < 256; off <<= 1) {
    int u = (threadIdx.x >= off) ? ls[threadIdx.x - off] : 0;
    __syncthreads();
    ls[threadIdx.x] += u;
    __syncthreads();
  }
  int excl = base[blockIdx.x] + ls[threadIdx.x] - v;
  if (i < NN) {
    rowstart[i] = excl;
    cursor[i] = excl;
    if (i == NN - 1) rowstart[NN] = excl + v;
  }
}

__global__ void k_place(const int* __restrict__ row, const int* __restrict__ col,
                        const float* __restrict__ w, const float* __restrict__ dis,
                        int* __restrict__ cursor, int2* __restrict__ edges) {
  int e = blockIdx.x * 256 + threadIdx.x;
  if (e >= NE) return;
  int r = row[e], c = col[e];
  float nm = dis[r] * w[e] * dis[c];
  int p = atomicAdd(&cursor[c], 1);
  edges[p] = make_int2(r, __float_as_int(nm));
}

// ---------------- fused dual GEMM, LDS-tiled, register-blocked ----------------
template <bool SAME>
__global__ __launch_bounds__(256) void k_gemm2(
    const float* __restrict__ inA, long inASK,
    const float* __restrict__ inB,
    const float* __restrict__ WA, long wASK,
    const float* __restrict__ WB, long wBSK,
    ushort* __restrict__ outA, float* __restrict__ outB) {
  __shared__ float WlA[4096];
  __shared__ float WlB[4096];
  __shared__ float Xs[(SAME ? 1 : 2) * 64 * 68];
  float* XA = Xs;
  float* XB = Xs + (SAME ? 0 : 64 * 68);
  const int t = threadIdx.x;
  const int k = blockIdx.y;
  {
    const float* wa = WA + (long)k * wASK;
    const float* wb = WB + (long)k * wBSK;
    for (int i = t; i < 1024; i += 256) {
      *(float4*)(WlA + 4 * i) = *(const float4*)(wa + 4 * i);
      *(float4*)(WlB + 4 * i) = *(const float4*)(wb + 4 * i);
    }
  }
  const int c4 = t & 15;
  const int rg = t >> 4;
  const int blockBase = blockIdx.x * 256;
  const float4 z4 = {0.f, 0.f, 0.f, 0.f};

  for (int ch = 0; ch < 4; ++ch) {
    int base = blockBase + ch * 64;
    if (base >= NN) break;
    if (ch) __syncthreads();
    for (int p = 0; p < 4; ++p) {
      int j = p * 256 + t;
      int r = j >> 4, cq = j & 15;
      int n = base + r;
      long go = (long)n * 64 + 4 * cq;
      float4 vb = (n < NN) ? *(const float4*)(inB + go) : z4;
      *(float4*)(&XB[r * 68 + 4 * cq]) = vb;
      if (!SAME) {
        float4 va = (n < NN) ? *(const float4*)(inA + (long)k * inASK + go) : z4;
        *(float4*)(&XA[r * 68 + 4 * cq]) = va;
      }
    }
    __syncthreads();

    // ---- phase A: message operand -> bf16 [n][k][f] ----
    {
      float4 a0 = z4, a1 = z4, a2 = z4, a3 = z4;
      for (int i4 = 0; i4 < 16; ++i4) {
        float4 w0 = *(float4*)(WlA + (4 * i4 + 0) * 64 + 4 * c4);
        float4 w1 = *(float4*)(WlA + (4 * i4 + 1) * 64 + 4 * c4);
        float4 w2 = *(float4*)(WlA + (4 * i4 + 2) * 64 + 4 * c4);
        float4 w3 = *(float4*)(WlA + (4 * i4 + 3) * 64 + 4 * c4);
        float4 x0 = *(float4*)(&XA[(rg * 4 + 0) * 68 + 4 * i4]);
        float4 x1 = *(float4*)(&XA[(rg * 4 + 1) * 68 + 4 * i4]);
        float4 x2 = *(float4*)(&XA[(rg * 4 + 2) * 68 + 4 * i4]);
        float4 x3 = *(float4*)(&XA[(rg * 4 + 3) * 68 + 4 * i4]);
        FMA4(a0, x0.x, w0); FMA4(a0, x0.y, w1); FMA4(a0, x0.z, w2); FMA4(a0, x0.w, w3);
        FMA4(a1, x1.x, w0); FMA4(a1, x1.y, w1); FMA4(a1, x1.z, w2); FMA4(a1, x1.w, w3);
        FMA4(a2, x2.x, w0); FMA4(a2, x2.y, w1); FMA4(a2, x2.z, w2); FMA4(a2, x2.w, w3);
        FMA4(a3, x3.x, w0); FMA4(a3, x3.y, w1); FMA4(a3, x3.z, w2); FMA4(a3, x3.w, w3);
      }
      int n0 = base + rg * 4;
      float4 aa[4] = {a0, a1, a2, a3};
#pragma unroll
      for (int j = 0; j < 4; ++j) {
        int n = n0 + j;
        if (n < NN) {
          uint2 u;
          u.x = pk_bf16(aa[j].x, aa[j].y);
          u.y = pk_bf16(aa[j].z, aa[j].w);
          *(uint2*)(outA + (long)n * 192 + k * 64 + 4 * c4) = u;
        }
      }
    }

    // ---- phase B: root term -> f32 [k][n][f] ----
    {
      float4 a0 = z4, a1 = z4, a2 = z4, a3 = z4;
      for (int i4 = 0; i4 < 16; ++i4) {
        float4 w0 = *(float4*)(WlB + (4 * i4 + 0) * 64 + 4 * c4);
        float4 w1 = *(float4*)(WlB + (4 * i4 + 1) * 64 + 4 * c4);
        float4 w2 = *(float4*)(WlB + (4 * i4 + 2) * 64 + 4 * c4);
        float4 w3 = *(float4*)(WlB + (4 * i4 + 3) * 64 + 4 * c4);
        float4 x0 = *(float4*)(&XB[(rg * 4 + 0) * 68 + 4 * i4]);
        float4 x1 = *(float4*)(&XB[(rg * 4 + 1) * 68 + 4 * i4]);
        float4 x2 = *(float4*)(&XB[(rg * 4 + 2) * 68 + 4 * i4]);
        float4 x3 = *(float4*)(&XB[(rg * 4 + 3) * 68 + 4 * i4]);
        FMA4(a0, x0.x, w0); FMA4(a0, x0.y, w1); FMA4(a0, x0.z, w2); FMA4(a0, x0.w, w3);
        FMA4(a1, x1.x, w0); FMA4(a1, x1.y, w1); FMA4(a1, x1.z, w2); FMA4(a1, x1.w, w3);
        FMA4(a2, x2.x, w0); FMA4(a2, x2.y, w1); FMA4(a2, x2.z, w2); FMA4(a2, x2.w, w3);
        FMA4(a3, x3.x, w0); FMA4(a3, x3.y, w1); FMA4(a3, x3.z, w2); FMA4(a3, x3.w, w3);
      }
      int n0 = base + rg * 4;
      float4 aa[4] = {a0, a1, a2, a3};
#pragma unroll
      for (int j = 0; j < 4; ++j) {
        int n = n0 + j;
        if (n < NN)
          *(float4*)(outB + (long)k * NF + (long)n * 64 + 4 * c4) = aa[j];
      }
    }
  }
}

// ---------------- fused gather + root + bias + relu (+ optional k-mean) ----------------
// Wave handles node n; lanes split 32/32 across an edge pair; each lane owns
// 2 features (packed uint = 2 bf16). Halves combined via shfl_xor(32).
#define GSTEP(EV) do { \
  int2 _e = (EV); \
  float _m = __int_as_float(_e.y); \
  const uint* _p = (const uint*)(Abf + (long)_e.x * 192) + fi; \
  uint _u0 = _p[0], _u1 = _p[32], _u2 = _p[64]; \
  a0x = fmaf(bf2f((ushort)_u0), _m, a0x); a0y = fmaf(bf2f((ushort)(_u0 >> 16)), _m, a0y); \
  a1x = fmaf(bf2f((ushort)_u1), _m, a1x); a1y = fmaf(bf2f((ushort)(_u1 >> 16)), _m, a1y); \
  a2x = fmaf(bf2f((ushort)_u2), _m, a2x); a2y = fmaf(bf2f((ushort)(_u2 >> 16)), _m, a2y); \
} while (0)

template <int MODE>
__global__ __launch_bounds__(256) void k_gather(const int* __restrict__ rowstart,
                                                const int2* __restrict__ edges,
                                                const ushort* __restrict__ Abf,
                                                float* __restrict__ B,
                                                float* __restrict__ hm,
                                                const float* __restrict__ bias, int t) {
  int wave = threadIdx.x >> 6;
  int lane = threadIdx.x & 63;
  int half = lane >> 5;
  int fi = lane & 31;                 // features 2*fi, 2*fi+1
  int n = blockIdx.x * 4 + wave;
  if (n >= NN) return;
  int s = rowstart[n], e = rowstart[n + 1];
  float a0x = 0.f, a0y = 0.f, a1x = 0.f, a1y = 0.f, a2x = 0.f, a2y = 0.f;
  int j = s;
  for (; j + 4 <= e; j += 4) {        // 4 edges per iter (2 pairs)
    GSTEP(edges[j + half]);
    GSTEP(edges[j + 2 + half]);
  }
  if (j + 2 <= e) { GSTEP(edges[j + half]); j += 2; }
  if (j < e) {                        // single leftover: half1 contributes 0
    int2 le = edges[j];
    if (half) le.y = 0;
    GSTEP(le);
  }
  a0x += __shfl_xor(a0x, 32); a0y += __shfl_xor(a0y, 32);
  a1x += __shfl_xor(a1x, 32); a1y += __shfl_xor(a1y, 32);
  a2x += __shfl_xor(a2x, 32); a2y += __shfl_xor(a2y, 32);

  long o2 = (long)n * 64 + 2 * fi;
  float2 bb0 = *(const float2*)(bias + (0 * 2 + t) * 64 + 2 * fi);
  float2 bb1 = *(const float2*)(bias + (1 * 2 + t) * 64 + 2 * fi);
  float2 bb2 = *(const float2*)(bias + (2 * 2 + t) * 64 + 2 * fi);
  float2 B0 = *(const float2*)(B + o2);
  float2 B1 = *(const float2*)(B + NF + o2);
  float2 B2 = *(const float2*)(B + 2L * NF + o2);
  float v0x = fmaxf(B0.x + a0x + bb0.x, 0.f), v0y = fmaxf(B0.y + a0y + bb0.y, 0.f);
  float v1x = fmaxf(B1.x + a1x + bb1.x, 0.f), v1y = fmaxf(B1.y + a1y + bb1.y, 0.f);
  float v2x = fmaxf(B2.x + a2x + bb2.x, 0.f), v2y = fmaxf(B2.y + a2y + bb2.y, 0.f);
  if (MODE == 0) {
    if (!half) {
      *(float2*)(B + o2) = make_float2(v0x, v0y);
      *(float2*)(B + NF + o2) = make_float2(v1x, v1y);
    } else {
      *(float2*)(B + 2L * NF + o2) = make_float2(v2x, v2y);
    }
  } else {
    if (!half)
      *(float2*)(hm + o2) = make_float2((v0x + v1x + v2x) * (1.f / 3.f),
                                        (v0y + v1y + v2y) * (1.f / 3.f));
  }
}

// ---------------- BN stats on h ----------------
__global__ __launch_bounds__(256) void k_bnstats(const float* __restrict__ h,
                                                 float* __restrict__ sum,
                                                 float* __restrict__ sq) {
  int f = threadIdx.x & 63, g = threadIdx.x >> 6;
  float s = 0.f, s2 = 0.f;
  for (int n = blockIdx.x * 4 + g; n < NN; n += gridDim.x * 4) {
    float v = h[(long)n * 64 + f];
    s += v; s2 += v * v;
  }
  __shared__ float ls[512];
  ls[threadIdx.x] = s;
  ls[256 + threadIdx.x] = s2;
  __syncthreads();
  if (threadIdx.x < 64) {
    float ts  = ls[f] + ls[64 + f] + ls[128 + f] + ls[192 + f];
    float ts2 = ls[256 + f] + ls[320 + f] + ls[384 + f] + ls[448 + f];
    atomicAdd(&sum[f], ts);
    atomicAdd(&sq[f], ts2);
  }
}

// ---------------- out = relu(g*(h-mu)*rsqrt(var+eps)+be)
__global__ void k_bnfin(const float* __restrict__ h, const float* __restrict__ sum,
                        const float* __restrict__ sq, const float* __restrict__ gam,
                        const float* __restrict__ bet, float* __restrict__ out) {
  long i4 = (long)blockIdx.x * 256 + threadIdx.x;
  if (i4 >= (long)NF / 4) return;
  long i = i4 * 4;
  int f = (int)(i & 63);
  float4 v = *(const float4*)(h + i);
  float o[4] = {v.x, v.y, v.z, v.w};
  float r[4];
#pragma unroll
  for (int j = 0; j < 4; ++j) {
    int fj = f + j;
    float mu = sum[fj] * (1.f / NN);
    float var = sq[fj] * (1.f / NN) - mu * mu;
    float inv = rsqrtf(var + EPSBN);
    float y = gam[fj] * (o[j] - mu) * inv + bet[fj];
    r[j] = fmaxf(y, 0.f);
  }
  float4 ov = {r[0], r[1], r[2], r[3]};
  *(float4*)(out + i) = ov;
}

extern "C" void kernel_launch(void* const* d_in, const int* in_sizes, int n_in,
                              void* d_out, int out_size, void* d_ws, size_t ws_size,
                              hipStream_t stream) {
  const float* x   = (const float*)d_in[0];
  const int*   ei  = (const int*)d_in[1];
  const float* wts = (const float*)d_in[2];
  const int* row = ei;        // edge_index[0]
  const int* col = ei + NE;   // edge_index[1]

  // workspace layout (4B units; dc/edges need 8B alignment)
  unsigned long long* dc = (unsigned long long*)d_ws;  // NN u64 (2*NN words)
  int*   cnt      = (int*)(dc + NN);           // NN
  int*   rowstart = cnt + NN;                  // NN+1
  int*   cursor   = rowstart + NN + 1;         // NN
  int*   pad      = cursor + NN;               // 1 (align to 8B)
  int2*  edges    = (int2*)(pad + 1);          // NE int2
  float* dis      = (float*)(edges + NE);      // NN
  float* h        = dis + NN;                  // NF
  float* B        = h + NF;                    // KNF
  ushort* Abf     = (ushort*)(B + KNF);        // NN*192 ushorts
  float* bns      = (float*)(Abf + (long)NN * 192); // 128
  int*   part     = (int*)(bns + 128);         // 512
  int*   pbase    = part + 512;                // 512

  // --- norm + CSR build (once) ---
  hipMemsetAsync(dc, 0, NN * sizeof(unsigned long long), stream);
  int eb = (NE + 255) / 256;
  k_degcnt<<<eb, 256, 0, stream>>>(col, wts, dc);
  k_dis<<<(NN + 255) / 256, 256, 0, stream>>>(dc, dis, cnt);
  k_sblk<<<SBLK, 256, 0, stream>>>(cnt, part);
  k_sscan<<<1, 512, 0, stream>>>(part, pbase);
  k_sfin<<<SBLK, 256, 0, stream>>>(cnt, pbase, rowstart, cursor);
  k_place<<<eb, 256, 0, stream>>>(row, col, wts, dis, cursor, edges);

  dim3 gg((NN + 255) / 256, KK);
  int gatherBlocks = (NN + 3) / 4;
  int nfBlocks = NF / 4 / 256;      // 6250 exact

  for (int layer = 0; layer < 3; ++layer) {
    const float* iw = (const float*)d_in[3 + 6 * layer];  // [K,F,F]
    const float* w  = (const float*)d_in[4 + 6 * layer];  // [K,1,F,F]
    const float* rw = (const float*)d_in[5 + 6 * layer];  // [K,2,F,F]
    const float* bs = (const float*)d_in[6 + 6 * layer];  // [K,2,1,F]
    const float* gm = (const float*)d_in[7 + 6 * layer];  // [F]
    const float* bt = (const float*)d_in[8 + 6 * layer];  // [F]
    const float* xin = (layer == 0) ? x : h;

    // t=0: Abf = xin@iw (bf16), B = xin@rw0; B = relu(gather(Abf) + B + b0)
    k_gemm2<true><<<gg, 256, 0, stream>>>(xin, 0, xin, iw, 4096, rw, 8192, Abf, B);
    k_gather<0><<<gatherBlocks, 256, 0, stream>>>(rowstart, edges, Abf, B, h, bs, 0);
    // t=1: Abf = B@w (bf16), B = xin@rw1; h = mean_k relu(gather(Abf) + B + b1)
    k_gemm2<false><<<gg, 256, 0, stream>>>(B, NF, xin, w, 4096, rw + 4096, 8192, Abf, B);
    k_gather<1><<<gatherBlocks, 256, 0, stream>>>(rowstart, edges, Abf, B, h, bs, 1);
    // BN stats + finalize + relu
    hipMemsetAsync(bns, 0, 2 * 64 * sizeof(float), stream);
    k_bnstats<<<1024, 256, 0, stream>>>(h, bns, bns + 64);
    float* dst = (layer == 2) ? (float*)d_out : h;
    k_bnfin<<<nfBlocks, 256, 0, stream>>>(h, bns, bns + 64, gm, bt, dst);
  }
}

// Round 7
// 1548.833 us; speedup vs baseline: 67.0193x; 1.0346x over previous
//
#include <hip/hip_runtime.h>

#define NN 100000
#define NE 1600000
#define FD 64
#define KK 3
#define NF (NN*FD)            // 6,400,000
#define KNF (KK*NF)           // 19,200,000
#define EPSBN 1e-5f
#define SBLK ((NN + 255) / 256)   // 391 scan blocks
#define DEGSCALE 262144.0f        // 2^18 fixed-point for weighted degree

typedef unsigned short ushort;
typedef unsigned int uint;

__device__ inline float bf2f(ushort u) { return __uint_as_float((unsigned)u << 16); }
__device__ inline unsigned pk_bf16(float a, float b) {
  unsigned ua = __float_as_uint(a); ua += 0x7FFF + ((ua >> 16) & 1);
  unsigned ub = __float_as_uint(b); ub += 0x7FFF + ((ub >> 16) & 1);
  return (ua >> 16) | (ub & 0xFFFF0000u);
}

#define FMA4(A, s, W) do { (A).x = fmaf((s), (W).x, (A).x); (A).y = fmaf((s), (W).y, (A).y); \
                           (A).z = fmaf((s), (W).z, (A).z); (A).w = fmaf((s), (W).w, (A).w); } while (0)

// ---------------- graph norm + CSR build ----------------
__global__ void k_degcnt(const int* __restrict__ col, const float* __restrict__ w,
                         unsigned long long* __restrict__ dc) {
  int e = blockIdx.x * 256 + threadIdx.x;
  if (e < NE) {
    unsigned fx = __float2uint_rn(w[e] * DEGSCALE);
    atomicAdd(&dc[col[e]], (1ULL << 32) | (unsigned long long)fx);
  }
}

__global__ void k_dis(const unsigned long long* __restrict__ dc,
                      float* __restrict__ dis, int* __restrict__ cnt) {
  int i = blockIdx.x * 256 + threadIdx.x;
  if (i < NN) {
    unsigned long long v = dc[i];
    float d = (float)(unsigned)v * (1.0f / DEGSCALE);
    dis[i] = d > 0.f ? rsqrtf(d) : 0.f;
    cnt[i] = (int)(v >> 32);
  }
}

// ---- multi-block exclusive scan of cnt[NN] -> rowstart[NN+1] (+cursor copy) ----
__global__ __launch_bounds__(256) void k_sblk(const int* __restrict__ cnt,
                                              int* __restrict__ part) {
  int i = blockIdx.x * 256 + threadIdx.x;
  int v = (i < NN) ? cnt[i] : 0;
#pragma unroll
  for (int off = 32; off; off >>= 1) v += __shfl_down(v, off);
  __shared__ int ws[4];
  if ((threadIdx.x & 63) == 0) ws[threadIdx.x >> 6] = v;
  __syncthreads();
  if (threadIdx.x == 0) part[blockIdx.x] = ws[0] + ws[1] + ws[2] + ws[3];
}

__global__ __launch_bounds__(512) void k_sscan(const int* __restrict__ part,
                                               int* __restrict__ base) {
  __shared__ int ls[512];
  int tid = threadIdx.x;
  int v = (tid < SBLK) ? part[tid] : 0;
  ls[tid] = v;
  __syncthreads();
  for (int off = 1; off < 512; off <<= 1) {
    int u = (tid >= off) ? ls[tid - off] : 0;
    __syncthreads();
    ls[tid] += u;
    __syncthreads();
  }
  base[tid] = tid ? ls[tid - 1] : 0;
}

__global__ __launch_bounds__(256) void k_sfin(const int* __restrict__ cnt,
                                              const int* __restrict__ base,
                                              int* __restrict__ rowstart,
                                              int* __restrict__ cursor) {
  __shared__ int ls[256];
  int i = blockIdx.x * 256 + threadIdx.x;
  int v = (i < NN) ? cnt[i] : 0;
  ls[threadIdx.x] = v;
  __syncthreads();
  for (int off = 1; off < 256; off <<= 1) {
    int u = (threadIdx.x >= off) ? ls[threadIdx.x - off] : 0;
    __syncthreads();
    ls[threadIdx.x] += u;
    __syncthreads();
  }
  int excl = base[blockIdx.x] + ls[threadIdx.x] - v;
  if (i < NN) {
    rowstart[i] = excl;
    cursor[i] = excl;
    if (i == NN - 1) rowstart[NN] = excl + v;
  }
}

__global__ void k_place(const int* __restrict__ row, const int* __restrict__ col,
                        const float* __restrict__ w, const float* __restrict__ dis,
                        int* __restrict__ cursor, int2* __restrict__ edges) {
  int e = blockIdx.x * 256 + threadIdx.x;
  if (e >= NE) return;
  int r = row[e], c = col[e];
  float nm = dis[r] * w[e] * dis[c];
  int p = atomicAdd(&cursor[c], 1);
  edges[p] = make_int2(r, __float_as_int(nm));
}

// ---------------- fused dual GEMM, LDS-tiled, register-blocked ----------------
// Single shared X buffer, sequential phases (A then B) => 49.4 KB LDS, 3 blocks/CU.
// Phase A first is REQUIRED for t=1 in-place (inA == outB): rows staged before overwrite.
#define STAGEX(SRC) do { \
  for (int p_ = 0; p_ < 4; ++p_) { \
    int j_ = p_ * 256 + t; \
    int r_ = j_ >> 4, cq_ = j_ & 15; \
    int n_ = base + r_; \
    long go_ = (long)n_ * 64 + 4 * cq_; \
    float4 v_ = (n_ < NN) ? *(const float4*)((SRC) + go_) : z4; \
    *(float4*)(&Xs[r_ * 68 + 4 * cq_]) = v_; \
  } \
} while (0)

template <bool SAME>
__global__ __launch_bounds__(256) void k_gemm2(
    const float* __restrict__ inA, long inASK,
    const float* __restrict__ inB,
    const float* __restrict__ WA, long wASK,
    const float* __restrict__ WB, long wBSK,
    ushort* __restrict__ outA, float* __restrict__ outB) {
  __shared__ float WlA[4096];
  __shared__ float WlB[4096];
  __shared__ float Xs[64 * 68];
  const int t = threadIdx.x;
  const int k = blockIdx.y;
  {
    const float* wa = WA + (long)k * wASK;
    const float* wb = WB + (long)k * wBSK;
    for (int i = t; i < 1024; i += 256) {
      *(float4*)(WlA + 4 * i) = *(const float4*)(wa + 4 * i);
      *(float4*)(WlB + 4 * i) = *(const float4*)(wb + 4 * i);
    }
  }
  const int c4 = t & 15;
  const int rg = t >> 4;
  const int blockBase = blockIdx.x * 256;
  const float4 z4 = {0.f, 0.f, 0.f, 0.f};
  const float* srcA = SAME ? inB : (inA + (long)k * inASK);

  for (int ch = 0; ch < 4; ++ch) {
    int base = blockBase + ch * 64;
    if (base >= NN) break;
    if (ch) __syncthreads();
    STAGEX(srcA);
    __syncthreads();

    // ---- phase A: message operand -> bf16 [n][k][f] ----
    {
      float4 a0 = z4, a1 = z4, a2 = z4, a3 = z4;
      for (int i4 = 0; i4 < 16; ++i4) {
        float4 w0 = *(float4*)(WlA + (4 * i4 + 0) * 64 + 4 * c4);
        float4 w1 = *(float4*)(WlA + (4 * i4 + 1) * 64 + 4 * c4);
        float4 w2 = *(float4*)(WlA + (4 * i4 + 2) * 64 + 4 * c4);
        float4 w3 = *(float4*)(WlA + (4 * i4 + 3) * 64 + 4 * c4);
        float4 x0 = *(float4*)(&Xs[(rg * 4 + 0) * 68 + 4 * i4]);
        float4 x1 = *(float4*)(&Xs[(rg * 4 + 1) * 68 + 4 * i4]);
        float4 x2 = *(float4*)(&Xs[(rg * 4 + 2) * 68 + 4 * i4]);
        float4 x3 = *(float4*)(&Xs[(rg * 4 + 3) * 68 + 4 * i4]);
        FMA4(a0, x0.x, w0); FMA4(a0, x0.y, w1); FMA4(a0, x0.z, w2); FMA4(a0, x0.w, w3);
        FMA4(a1, x1.x, w0); FMA4(a1, x1.y, w1); FMA4(a1, x1.z, w2); FMA4(a1, x1.w, w3);
        FMA4(a2, x2.x, w0); FMA4(a2, x2.y, w1); FMA4(a2, x2.z, w2); FMA4(a2, x2.w, w3);
        FMA4(a3, x3.x, w0); FMA4(a3, x3.y, w1); FMA4(a3, x3.z, w2); FMA4(a3, x3.w, w3);
      }
      int n0 = base + rg * 4;
      float4 aa[4] = {a0, a1, a2, a3};
#pragma unroll
      for (int j = 0; j < 4; ++j) {
        int n = n0 + j;
        if (n < NN) {
          uint2 u;
          u.x = pk_bf16(aa[j].x, aa[j].y);
          u.y = pk_bf16(aa[j].z, aa[j].w);
          *(uint2*)(outA + (long)n * 192 + k * 64 + 4 * c4) = u;
        }
      }
    }

    if (!SAME) {
      __syncthreads();
      STAGEX(inB);
      __syncthreads();
    }

    // ---- phase B: root term -> f32 [k][n][f] ----
    {
      float4 a0 = z4, a1 = z4, a2 = z4, a3 = z4;
      for (int i4 = 0; i4 < 16; ++i4) {
        float4 w0 = *(float4*)(WlB + (4 * i4 + 0) * 64 + 4 * c4);
        float4 w1 = *(float4*)(WlB + (4 * i4 + 1) * 64 + 4 * c4);
        float4 w2 = *(float4*)(WlB + (4 * i4 + 2) * 64 + 4 * c4);
        float4 w3 = *(float4*)(WlB + (4 * i4 + 3) * 64 + 4 * c4);
        float4 x0 = *(float4*)(&Xs[(rg * 4 + 0) * 68 + 4 * i4]);
        float4 x1 = *(float4*)(&Xs[(rg * 4 + 1) * 68 + 4 * i4]);
        float4 x2 = *(float4*)(&Xs[(rg * 4 + 2) * 68 + 4 * i4]);
        float4 x3 = *(float4*)(&Xs[(rg * 4 + 3) * 68 + 4 * i4]);
        FMA4(a0, x0.x, w0); FMA4(a0, x0.y, w1); FMA4(a0, x0.z, w2); FMA4(a0, x0.w, w3);
        FMA4(a1, x1.x, w0); FMA4(a1, x1.y, w1); FMA4(a1, x1.z, w2); FMA4(a1, x1.w, w3);
        FMA4(a2, x2.x, w0); FMA4(a2, x2.y, w1); FMA4(a2, x2.z, w2); FMA4(a2, x2.w, w3);
        FMA4(a3, x3.x, w0); FMA4(a3, x3.y, w1); FMA4(a3, x3.z, w2); FMA4(a3, x3.w, w3);
      }
      int n0 = base + rg * 4;
      float4 aa[4] = {a0, a1, a2, a3};
#pragma unroll
      for (int j = 0; j < 4; ++j) {
        int n = n0 + j;
        if (n < NN)
          *(float4*)(outB + (long)k * NF + (long)n * 64 + 4 * c4) = aa[j];
      }
    }
  }
}

// ---------------- fused gather + root + bias + relu (+ optional k-mean) ----------------
// Wave handles node n; lanes in 4 groups of 16, each group owns one edge of a
// 4-edge batch; each lane owns 4 features (uint2 = 4 bf16 per plane).
#define GSTEP4(EV) do { \
  int2 _e = (EV); \
  float _m = __int_as_float(_e.y); \
  const uint2* _p = (const uint2*)(Abf + (long)_e.x * 192) + fi; \
  uint2 _u0 = _p[0], _u1 = _p[16], _u2 = _p[32]; \
  a00 = fmaf(bf2f((ushort)_u0.x), _m, a00); a01 = fmaf(bf2f((ushort)(_u0.x >> 16)), _m, a01); \
  a02 = fmaf(bf2f((ushort)_u0.y), _m, a02); a03 = fmaf(bf2f((ushort)(_u0.y >> 16)), _m, a03); \
  a10 = fmaf(bf2f((ushort)_u1.x), _m, a10); a11 = fmaf(bf2f((ushort)(_u1.x >> 16)), _m, a11); \
  a12 = fmaf(bf2f((ushort)_u1.y), _m, a12); a13 = fmaf(bf2f((ushort)(_u1.y >> 16)), _m, a13); \
  a20 = fmaf(bf2f((ushort)_u2.x), _m, a20); a21 = fmaf(bf2f((ushort)(_u2.x >> 16)), _m, a21); \
  a22 = fmaf(bf2f((ushort)_u2.y), _m, a22); a23 = fmaf(bf2f((ushort)(_u2.y >> 16)), _m, a23); \
} while (0)

#define RED2(v) do { (v) += __shfl_xor((v), 16); (v) += __shfl_xor((v), 32); } while (0)

template <int MODE>
__global__ __launch_bounds__(256) void k_gather(const int* __restrict__ rowstart,
                                                const int2* __restrict__ edges,
                                                const ushort* __restrict__ Abf,
                                                float* __restrict__ B,
                                                float* __restrict__ hm,
                                                const float* __restrict__ bias, int t) {
  int wave = threadIdx.x >> 6;
  int lane = threadIdx.x & 63;
  int grp = lane >> 4;                // edge slot 0..3
  int fi = lane & 15;                 // features 4*fi .. 4*fi+3
  int n = blockIdx.x * 4 + wave;
  if (n >= NN) return;
  int s = rowstart[n], e = rowstart[n + 1];
  float a00 = 0.f, a01 = 0.f, a02 = 0.f, a03 = 0.f;
  float a10 = 0.f, a11 = 0.f, a12 = 0.f, a13 = 0.f;
  float a20 = 0.f, a21 = 0.f, a22 = 0.f, a23 = 0.f;
  int j = s;
  for (; j + 8 <= e; j += 8) {
    GSTEP4(edges[j + grp]);
    GSTEP4(edges[j + 4 + grp]);
  }
  if (j + 4 <= e) { GSTEP4(edges[j + grp]); j += 4; }
  if (j < e) {
    int idx = j + grp;
    int2 ee = edges[idx < e ? idx : (e - 1)];
    if (idx >= e) ee.y = 0;
    GSTEP4(ee);
  }
  RED2(a00); RED2(a01); RED2(a02); RED2(a03);
  RED2(a10); RED2(a11); RED2(a12); RED2(a13);
  RED2(a20); RED2(a21); RED2(a22); RED2(a23);

  long o4 = (long)n * 64 + 4 * fi;
  if (MODE == 0) {
    if (grp == 0) {
      float4 bv = *(const float4*)(B + o4);
      float4 bb = *(const float4*)(bias + (0 * 2 + t) * 64 + 4 * fi);
      float4 r;
      r.x = fmaxf(bv.x + a00 + bb.x, 0.f); r.y = fmaxf(bv.y + a01 + bb.y, 0.f);
      r.z = fmaxf(bv.z + a02 + bb.z, 0.f); r.w = fmaxf(bv.w + a03 + bb.w, 0.f);
      *(float4*)(B + o4) = r;
    } else if (grp == 1) {
      float4 bv = *(const float4*)(B + NF + o4);
      float4 bb = *(const float4*)(bias + (1 * 2 + t) * 64 + 4 * fi);
      float4 r;
      r.x = fmaxf(bv.x + a10 + bb.x, 0.f); r.y = fmaxf(bv.y + a11 + bb.y, 0.f);
      r.z = fmaxf(bv.z + a12 + bb.z, 0.f); r.w = fmaxf(bv.w + a13 + bb.w, 0.f);
      *(float4*)(B + NF + o4) = r;
    } else if (grp == 2) {
      float4 bv = *(const float4*)(B + 2L * NF + o4);
      float4 bb = *(const float4*)(bias + (2 * 2 + t) * 64 + 4 * fi);
      float4 r;
      r.x = fmaxf(bv.x + a20 + bb.x, 0.f); r.y = fmaxf(bv.y + a21 + bb.y, 0.f);
      r.z = fmaxf(bv.z + a22 + bb.z, 0.f); r.w = fmaxf(bv.w + a23 + bb.w, 0.f);
      *(float4*)(B + 2L * NF + o4) = r;
    }
  } else {
    if (grp == 0) {
      float4 b0 = *(const float4*)(B + o4);
      float4 b1 = *(const float4*)(B + NF + o4);
      float4 b2 = *(const float4*)(B + 2L * NF + o4);
      float4 c0 = *(const float4*)(bias + (0 * 2 + t) * 64 + 4 * fi);
      float4 c1 = *(const float4*)(bias + (1 * 2 + t) * 64 + 4 * fi);
      float4 c2 = *(const float4*)(bias + (2 * 2 + t) * 64 + 4 * fi);
      float4 r;
      r.x = (fmaxf(b0.x + a00 + c0.x, 0.f) + fmaxf(b1.x + a10 + c1.x, 0.f) + fmaxf(b2.x + a20 + c2.x, 0.f)) * (1.f / 3.f);
      r.y = (fmaxf(b0.y + a01 + c0.y, 0.f) + fmaxf(b1.y + a11 + c1.y, 0.f) + fmaxf(b2.y + a21 + c2.y, 0.f)) * (1.f / 3.f);
      r.z = (fmaxf(b0.z + a02 + c0.z, 0.f) + fmaxf(b1.z + a12 + c1.z, 0.f) + fmaxf(b2.z + a22 + c2.z, 0.f)) * (1.f / 3.f);
      r.w = (fmaxf(b0.w + a03 + c0.w, 0.f) + fmaxf(b1.w + a13 + c1.w, 0.f) + fmaxf(b2.w + a23 + c2.w, 0.f)) * (1.f / 3.f);
      *(float4*)(hm + o4) = r;
    }
  }
}

// ---------------- BN stats on h ----------------
__global__ __launch_bounds__(256) void k_bnstats(const float* __restrict__ h,
                                                 float* __restrict__ sum,
                                                 float* __restrict__ sq) {
  int f = threadIdx.x & 63, g = threadIdx.x >> 6;
  float s = 0.f, s2 = 0.f;
  for (int n = blockIdx.x * 4 + g; n < NN; n += gridDim.x * 4) {
    float v = h[(long)n * 64 + f];
    s += v; s2 += v * v;
  }
  __shared__ float ls[512];
  ls[threadIdx.x] = s;
  ls[256 + threadIdx.x] = s2;
  __syncthreads();
  if (threadIdx.x < 64) {
    float ts  = ls[f] + ls[64 + f] + ls[128 + f] + ls[192 + f];
    float ts2 = ls[256 + f] + ls[320 + f] + ls[384 + f] + ls[448 + f];
    atomicAdd(&sum[f], ts);
    atomicAdd(&sq[f], ts2);
  }
}

// ---------------- out = relu(g*(h-mu)*rsqrt(var+eps)+be)
__global__ void k_bnfin(const float* __restrict__ h, const float* __restrict__ sum,
                        const float* __restrict__ sq, const float* __restrict__ gam,
                        const float* __restrict__ bet, float* __restrict__ out) {
  long i4 = (long)blockIdx.x * 256 + threadIdx.x;
  if (i4 >= (long)NF / 4) return;
  long i = i4 * 4;
  int f = (int)(i & 63);
  float4 v = *(const float4*)(h + i);
  float o[4] = {v.x, v.y, v.z, v.w};
  float r[4];
#pragma unroll
  for (int j = 0; j < 4; ++j) {
    int fj = f + j;
    float mu = sum[fj] * (1.f / NN);
    float var = sq[fj] * (1.f / NN) - mu * mu;
    float inv = rsqrtf(var + EPSBN);
    float y = gam[fj] * (o[j] - mu) * inv + bet[fj];
    r[j] = fmaxf(y, 0.f);
  }
  float4 ov = {r[0], r[1], r[2], r[3]};
  *(float4*)(out + i) = ov;
}

extern "C" void kernel_launch(void* const* d_in, const int* in_sizes, int n_in,
                              void* d_out, int out_size, void* d_ws, size_t ws_size,
                              hipStream_t stream) {
  const float* x   = (const float*)d_in[0];
  const int*   ei  = (const int*)d_in[1];
  const float* wts = (const float*)d_in[2];
  const int* row = ei;        // edge_index[0]
  const int* col = ei + NE;   // edge_index[1]

  // workspace layout (4B units; dc/edges need 8B alignment)
  unsigned long long* dc = (unsigned long long*)d_ws;  // NN u64
  int*   cnt      = (int*)(dc + NN);           // NN
  int*   rowstart = cnt + NN;                  // NN+1
  int*   cursor   = rowstart + NN + 1;         // NN
  int*   pad      = cursor + NN;               // 1 (align to 8B)
  int2*  edges    = (int2*)(pad + 1);          // NE int2
  float* dis      = (float*)(edges + NE);      // NN
  float* h        = dis + NN;                  // NF
  float* B        = h + NF;                    // KNF
  ushort* Abf     = (ushort*)(B + KNF);        // NN*192 ushorts
  float* bns      = (float*)(Abf + (long)NN * 192); // 128
  int*   part     = (int*)(bns + 128);         // 512
  int*   pbase    = part + 512;                // 512

  // --- norm + CSR build (once) ---
  hipMemsetAsync(dc, 0, NN * sizeof(unsigned long long), stream);
  int eb = (NE + 255) / 256;
  k_degcnt<<<eb, 256, 0, stream>>>(col, wts, dc);
  k_dis<<<(NN + 255) / 256, 256, 0, stream>>>(dc, dis, cnt);
  k_sblk<<<SBLK, 256, 0, stream>>>(cnt, part);
  k_sscan<<<1, 512, 0, stream>>>(part, pbase);
  k_sfin<<<SBLK, 256, 0, stream>>>(cnt, pbase, rowstart, cursor);
  k_place<<<eb, 256, 0, stream>>>(row, col, wts, dis, cursor, edges);

  dim3 gg((NN + 255) / 256, KK);
  int gatherBlocks = (NN + 3) / 4;
  int nfBlocks = NF / 4 / 256;      // 6250 exact

  for (int layer = 0; layer < 3; ++layer) {
    const float* iw = (const float*)d_in[3 + 6 * layer];  // [K,F,F]
    const float* w  = (const float*)d_in[4 + 6 * layer];  // [K,1,F,F]
    const float* rw = (const float*)d_in[5 + 6 * layer];  // [K,2,F,F]
    const float* bs = (const float*)d_in[6 + 6 * layer];  // [K,2,1,F]
    const float* gm = (const float*)d_in[7 + 6 * layer];  // [F]
    const float* bt = (const float*)d_in[8 + 6 * layer];  // [F]
    const float* xin = (layer == 0) ? x : h;

    // t=0: Abf = xin@iw (bf16), B = xin@rw0; B = relu(gather(Abf) + B + b0)
    k_gemm2<true><<<gg, 256, 0, stream>>>(xin, 0, xin, iw, 4096, rw, 8192, Abf, B);
    k_gather<0><<<gatherBlocks, 256, 0, stream>>>(rowstart, edges, Abf, B, h, bs, 0);
    // t=1: Abf = B@w (bf16), B = xin@rw1; h = mean_k relu(gather(Abf) + B + b1)
    k_gemm2<false><<<gg, 256, 0, stream>>>(B, NF, xin, w, 4096, rw + 4096, 8192, Abf, B);
    k_gather<1><<<gatherBlocks, 256, 0, stream>>>(rowstart, edges, Abf, B, h, bs, 1);
    // BN stats + finalize + relu
    hipMemsetAsync(bns, 0, 2 * 64 * sizeof(float), stream);
    k_bnstats<<<1024, 256, 0, stream>>>(h, bns, bns + 64);
    float* dst = (layer == 2) ? (float*)d_out : h;
    k_bnfin<<<nfBlocks, 256, 0, stream>>>(h, bns, bns + 64, gm, bt, dst);
  }
}

// Round 8
// 1528.352 us; speedup vs baseline: 67.9174x; 1.0134x over previous
//
#include <hip/hip_runtime.h>

#define NN 100000
#define NE 1600000
#define FD 64
#define KK 3
#define NF (NN*FD)            // 6,400,000
#define KNF (KK*NF)           // 19,200,000
#define EPSBN 1e-5f
#define SBLK ((NN + 255) / 256)   // 391 scan blocks
#define DEGSCALE 262144.0f        // 2^18 fixed-point for weighted degree

typedef unsigned short ushort;
typedef unsigned int uint;

__device__ inline float bf2f(ushort u) { return __uint_as_float((unsigned)u << 16); }
__device__ inline unsigned pk_bf16(float a, float b) {
  unsigned ua = __float_as_uint(a); ua += 0x7FFF + ((ua >> 16) & 1);
  unsigned ub = __float_as_uint(b); ub += 0x7FFF + ((ub >> 16) & 1);
  return (ua >> 16) | (ub & 0xFFFF0000u);
}

#define FMA4(A, s, W) do { (A).x = fmaf((s), (W).x, (A).x); (A).y = fmaf((s), (W).y, (A).y); \
                           (A).z = fmaf((s), (W).z, (A).z); (A).w = fmaf((s), (W).w, (A).w); } while (0)

// ---------------- graph norm + CSR build ----------------
__global__ void k_degcnt(const int* __restrict__ col, const float* __restrict__ w,
                         unsigned long long* __restrict__ dc) {
  int e = blockIdx.x * 256 + threadIdx.x;
  if (e < NE) {
    unsigned fx = __float2uint_rn(w[e] * DEGSCALE);
    atomicAdd(&dc[col[e]], (1ULL << 32) | (unsigned long long)fx);
  }
}

// dis + cnt extraction fused with per-block partial sums
__global__ __launch_bounds__(256) void k_sblk(const unsigned long long* __restrict__ dc,
                                              float* __restrict__ dis, int* __restrict__ cnt,
                                              int* __restrict__ part) {
  int i = blockIdx.x * 256 + threadIdx.x;
  int v = 0;
  if (i < NN) {
    unsigned long long u = dc[i];
    float d = (float)(unsigned)u * (1.0f / DEGSCALE);
    dis[i] = d > 0.f ? rsqrtf(d) : 0.f;
    v = (int)(u >> 32);
    cnt[i] = v;
  }
#pragma unroll
  for (int off = 32; off; off >>= 1) v += __shfl_down(v, off);
  __shared__ int ws[4];
  if ((threadIdx.x & 63) == 0) ws[threadIdx.x >> 6] = v;
  __syncthreads();
  if (threadIdx.x == 0) part[blockIdx.x] = ws[0] + ws[1] + ws[2] + ws[3];
}

__global__ __launch_bounds__(512) void k_sscan(const int* __restrict__ part,
                                               int* __restrict__ base) {
  __shared__ int ls[512];
  int tid = threadIdx.x;
  int v = (tid < SBLK) ? part[tid] : 0;
  ls[tid] = v;
  __syncthreads();
  for (int off = 1; off < 512; off <<= 1) {
    int u = (tid >= off) ? ls[tid - off] : 0;
    __syncthreads();
    ls[tid] += u;
    __syncthreads();
  }
  base[tid] = tid ? ls[tid - 1] : 0;
}

__global__ __launch_bounds__(256) void k_sfin(const int* __restrict__ cnt,
                                              const int* __restrict__ base,
                                              int* __restrict__ rowstart,
                                              int* __restrict__ cursor) {
  __shared__ int ls[256];
  int i = blockIdx.x * 256 + threadIdx.x;
  int v = (i < NN) ? cnt[i] : 0;
  ls[threadIdx.x] = v;
  __syncthreads();
  for (int off = 1; off < 256; off <<= 1) {
    int u = (threadIdx.x >= off) ? ls[threadIdx.x - off] : 0;
    __syncthreads();
    ls[threadIdx.x] += u;
    __syncthreads();
  }
  int excl = base[blockIdx.x] + ls[threadIdx.x] - v;
  if (i < NN) {
    rowstart[i] = excl;
    cursor[i] = excl;
    if (i == NN - 1) rowstart[NN] = excl + v;
  }
}

__global__ void k_place(const int* __restrict__ row, const int* __restrict__ col,
                        const float* __restrict__ w, const float* __restrict__ dis,
                        int* __restrict__ cursor, int2* __restrict__ edges) {
  int e = blockIdx.x * 256 + threadIdx.x;
  if (e >= NE) return;
  int r = row[e], c = col[e];
  float nm = dis[r] * w[e] * dis[c];
  int p = atomicAdd(&cursor[c], 1);
  edges[p] = make_int2(r, __float_as_int(nm));
}

// ---------------- fused dual GEMM, LDS-tiled, register-blocked ----------------
// outA[n][k][f] (bf16) = inA_row @ WA[k];  outB[k][n][f] (bf16) = inB_row @ WB[k]
// SAME: inA == inB == xin (f32). !SAME: inA = bf16 planar [k][n][f] (Y0bf).
#define STAGEX(SRC) do { \
  for (int p_ = 0; p_ < 4; ++p_) { \
    int j_ = p_ * 256 + t; \
    int r_ = j_ >> 4, cq_ = j_ & 15; \
    int n_ = base + r_; \
    long go_ = (long)n_ * 64 + 4 * cq_; \
    float4 v_ = (n_ < NN) ? *(const float4*)((SRC) + go_) : z4; \
    *(float4*)(&Xs[r_ * 68 + 4 * cq_]) = v_; \
  } \
} while (0)

#define STAGEXBF(SRC) do { \
  for (int p_ = 0; p_ < 4; ++p_) { \
    int j_ = p_ * 256 + t; \
    int r_ = j_ >> 4, cq_ = j_ & 15; \
    int n_ = base + r_; \
    float4 v_ = z4; \
    if (n_ < NN) { \
      uint2 u_ = *(const uint2*)((SRC) + (long)n_ * 64 + 4 * cq_); \
      v_.x = bf2f((ushort)u_.x); v_.y = bf2f((ushort)(u_.x >> 16)); \
      v_.z = bf2f((ushort)u_.y); v_.w = bf2f((ushort)(u_.y >> 16)); \
    } \
    *(float4*)(&Xs[r_ * 68 + 4 * cq_]) = v_; \
  } \
} while (0)

template <bool SAME>
__global__ __launch_bounds__(256) void k_gemm2(
    const ushort* __restrict__ inAbf,
    const float* __restrict__ inB,
    const float* __restrict__ WA, long wASK,
    const float* __restrict__ WB, long wBSK,
    ushort* __restrict__ outA, ushort* __restrict__ outB) {
  __shared__ float WlA[4096];
  __shared__ float WlB[4096];
  __shared__ float Xs[64 * 68];
  const int t = threadIdx.x;
  const int k = blockIdx.y;
  {
    const float* wa = WA + (long)k * wASK;
    const float* wb = WB + (long)k * wBSK;
    for (int i = t; i < 1024; i += 256) {
      *(float4*)(WlA + 4 * i) = *(const float4*)(wa + 4 * i);
      *(float4*)(WlB + 4 * i) = *(const float4*)(wb + 4 * i);
    }
  }
  const int c4 = t & 15;
  const int rg = t >> 4;
  const int blockBase = blockIdx.x * 256;
  const float4 z4 = {0.f, 0.f, 0.f, 0.f};
  const ushort* srcA = SAME ? (const ushort*)0 : (inAbf + (long)k * NF);

  for (int ch = 0; ch < 4; ++ch) {
    int base = blockBase + ch * 64;
    if (base >= NN) break;
    if (ch) __syncthreads();
    if (SAME) STAGEX(inB); else STAGEXBF(srcA);
    __syncthreads();

    // ---- phase A: message operand -> bf16 [n][k][f] ----
    {
      float4 a0 = z4, a1 = z4, a2 = z4, a3 = z4;
      for (int i4 = 0; i4 < 16; ++i4) {
        float4 w0 = *(float4*)(WlA + (4 * i4 + 0) * 64 + 4 * c4);
        float4 w1 = *(float4*)(WlA + (4 * i4 + 1) * 64 + 4 * c4);
        float4 w2 = *(float4*)(WlA + (4 * i4 + 2) * 64 + 4 * c4);
        float4 w3 = *(float4*)(WlA + (4 * i4 + 3) * 64 + 4 * c4);
        float4 x0 = *(float4*)(&Xs[(rg * 4 + 0) * 68 + 4 * i4]);
        float4 x1 = *(float4*)(&Xs[(rg * 4 + 1) * 68 + 4 * i4]);
        float4 x2 = *(float4*)(&Xs[(rg * 4 + 2) * 68 + 4 * i4]);
        float4 x3 = *(float4*)(&Xs[(rg * 4 + 3) * 68 + 4 * i4]);
        FMA4(a0, x0.x, w0); FMA4(a0, x0.y, w1); FMA4(a0, x0.z, w2); FMA4(a0, x0.w, w3);
        FMA4(a1, x1.x, w0); FMA4(a1, x1.y, w1); FMA4(a1, x1.z, w2); FMA4(a1, x1.w, w3);
        FMA4(a2, x2.x, w0); FMA4(a2, x2.y, w1); FMA4(a2, x2.z, w2); FMA4(a2, x2.w, w3);
        FMA4(a3, x3.x, w0); FMA4(a3, x3.y, w1); FMA4(a3, x3.z, w2); FMA4(a3, x3.w, w3);
      }
      int n0 = base + rg * 4;
      float4 aa[4] = {a0, a1, a2, a3};
#pragma unroll
      for (int j = 0; j < 4; ++j) {
        int n = n0 + j;
        if (n < NN) {
          uint2 u;
          u.x = pk_bf16(aa[j].x, aa[j].y);
          u.y = pk_bf16(aa[j].z, aa[j].w);
          *(uint2*)(outA + (long)n * 192 + k * 64 + 4 * c4) = u;
        }
      }
    }

    if (!SAME) {
      __syncthreads();
      STAGEX(inB);
      __syncthreads();
    }

    // ---- phase B: root term -> bf16 [k][n][f] ----
    {
      float4 a0 = z4, a1 = z4, a2 = z4, a3 = z4;
      for (int i4 = 0; i4 < 16; ++i4) {
        float4 w0 = *(float4*)(WlB + (4 * i4 + 0) * 64 + 4 * c4);
        float4 w1 = *(float4*)(WlB + (4 * i4 + 1) * 64 + 4 * c4);
        float4 w2 = *(float4*)(WlB + (4 * i4 + 2) * 64 + 4 * c4);
        float4 w3 = *(float4*)(WlB + (4 * i4 + 3) * 64 + 4 * c4);
        float4 x0 = *(float4*)(&Xs[(rg * 4 + 0) * 68 + 4 * i4]);
        float4 x1 = *(float4*)(&Xs[(rg * 4 + 1) * 68 + 4 * i4]);
        float4 x2 = *(float4*)(&Xs[(rg * 4 + 2) * 68 + 4 * i4]);
        float4 x3 = *(float4*)(&Xs[(rg * 4 + 3) * 68 + 4 * i4]);
        FMA4(a0, x0.x, w0); FMA4(a0, x0.y, w1); FMA4(a0, x0.z, w2); FMA4(a0, x0.w, w3);
        FMA4(a1, x1.x, w0); FMA4(a1, x1.y, w1); FMA4(a1, x1.z, w2); FMA4(a1, x1.w, w3);
        FMA4(a2, x2.x, w0); FMA4(a2, x2.y, w1); FMA4(a2, x2.z, w2); FMA4(a2, x2.w, w3);
        FMA4(a3, x3.x, w0); FMA4(a3, x3.y, w1); FMA4(a3, x3.z, w2); FMA4(a3, x3.w, w3);
      }
      int n0 = base + rg * 4;
      float4 aa[4] = {a0, a1, a2, a3};
#pragma unroll
      for (int j = 0; j < 4; ++j) {
        int n = n0 + j;
        if (n < NN) {
          uint2 u;
          u.x = pk_bf16(aa[j].x, aa[j].y);
          u.y = pk_bf16(aa[j].z, aa[j].w);
          *(uint2*)(outB + (long)k * NF + (long)n * 64 + 4 * c4) = u;
        }
      }
    }
  }
}

// ---------------- fused gather + root + bias + relu (+ optional k-mean) ----------------
// Wave = node n; 4 groups of 16 lanes own one edge each of a 4-edge batch;
// each lane owns 4 features (uint2 = 4 bf16 per plane).
#define GSTEP4(EV) do { \
  int2 _e = (EV); \
  float _m = __int_as_float(_e.y); \
  const uint2* _p = (const uint2*)(Abf + (long)_e.x * 192) + fi; \
  uint2 _u0 = _p[0], _u1 = _p[16], _u2 = _p[32]; \
  a00 = fmaf(bf2f((ushort)_u0.x), _m, a00); a01 = fmaf(bf2f((ushort)(_u0.x >> 16)), _m, a01); \
  a02 = fmaf(bf2f((ushort)_u0.y), _m, a02); a03 = fmaf(bf2f((ushort)(_u0.y >> 16)), _m, a03); \
  a10 = fmaf(bf2f((ushort)_u1.x), _m, a10); a11 = fmaf(bf2f((ushort)(_u1.x >> 16)), _m, a11); \
  a12 = fmaf(bf2f((ushort)_u1.y), _m, a12); a13 = fmaf(bf2f((ushort)(_u1.y >> 16)), _m, a13); \
  a20 = fmaf(bf2f((ushort)_u2.x), _m, a20); a21 = fmaf(bf2f((ushort)(_u2.x >> 16)), _m, a21); \
  a22 = fmaf(bf2f((ushort)_u2.y), _m, a22); a23 = fmaf(bf2f((ushort)(_u2.y >> 16)), _m, a23); \
} while (0)

#define RED2(v) do { (v) += __shfl_xor((v), 16); (v) += __shfl_xor((v), 32); } while (0)

template <int MODE>   // 0: write y0 (bf16 planar), 1: write hm = mean_k (f32)
__global__ __launch_bounds__(256) void k_gather(const int* __restrict__ rowstart,
                                                const int2* __restrict__ edges,
                                                const ushort* __restrict__ Abf,
                                                const ushort* __restrict__ Broot,
                                                ushort* __restrict__ y0,
                                                float* __restrict__ hm,
                                                const float* __restrict__ bias, int t) {
  int wave = threadIdx.x >> 6;
  int lane = threadIdx.x & 63;
  int grp = lane >> 4;
  int fi = lane & 15;
  int n = blockIdx.x * 4 + wave;
  if (n >= NN) return;
  int s = rowstart[n], e = rowstart[n + 1];
  float a00 = 0.f, a01 = 0.f, a02 = 0.f, a03 = 0.f;
  float a10 = 0.f, a11 = 0.f, a12 = 0.f, a13 = 0.f;
  float a20 = 0.f, a21 = 0.f, a22 = 0.f, a23 = 0.f;
  int j = s;
  for (; j + 8 <= e; j += 8) {
    GSTEP4(edges[j + grp]);
    GSTEP4(edges[j + 4 + grp]);
  }
  if (j + 4 <= e) { GSTEP4(edges[j + grp]); j += 4; }
  if (j < e) {
    int idx = j + grp;
    int2 ee = edges[idx < e ? idx : (e - 1)];
    if (idx >= e) ee.y = 0;
    GSTEP4(ee);
  }
  RED2(a00); RED2(a01); RED2(a02); RED2(a03);
  RED2(a10); RED2(a11); RED2(a12); RED2(a13);
  RED2(a20); RED2(a21); RED2(a22); RED2(a23);
  // after RED2 every lane holds the full per-feature sums

  long o4 = (long)n * 64 + 4 * fi;
  if (MODE == 0) {
    if (grp < 3) {
      float4 bb = *(const float4*)(bias + (grp * 2 + t) * 64 + 4 * fi);
      uint2 ru = *(const uint2*)(Broot + (long)grp * NF + o4);
      float aX, aY, aZ, aW;
      if (grp == 0)      { aX = a00; aY = a01; aZ = a02; aW = a03; }
      else if (grp == 1) { aX = a10; aY = a11; aZ = a12; aW = a13; }
      else               { aX = a20; aY = a21; aZ = a22; aW = a23; }
      float rx = fmaxf(bf2f((ushort)ru.x)         + aX + bb.x, 0.f);
      float ry = fmaxf(bf2f((ushort)(ru.x >> 16)) + aY + bb.y, 0.f);
      float rz = fmaxf(bf2f((ushort)ru.y)         + aZ + bb.z, 0.f);
      float rw = fmaxf(bf2f((ushort)(ru.y >> 16)) + aW + bb.w, 0.f);
      uint2 ou;
      ou.x = pk_bf16(rx, ry);
      ou.y = pk_bf16(rz, rw);
      *(uint2*)(y0 + (long)grp * NF + o4) = ou;
    }
  } else {
    if (grp == 0) {
      uint2 r0 = *(const uint2*)(Broot + o4);
      uint2 r1 = *(const uint2*)(Broot + NF + o4);
      uint2 r2 = *(const uint2*)(Broot + 2L * NF + o4);
      float4 c0 = *(const float4*)(bias + (0 * 2 + t) * 64 + 4 * fi);
      float4 c1 = *(const float4*)(bias + (1 * 2 + t) * 64 + 4 * fi);
      float4 c2 = *(const float4*)(bias + (2 * 2 + t) * 64 + 4 * fi);
      float4 r;
      r.x = (fmaxf(bf2f((ushort)r0.x) + a00 + c0.x, 0.f) +
             fmaxf(bf2f((ushort)r1.x) + a10 + c1.x, 0.f) +
             fmaxf(bf2f((ushort)r2.x) + a20 + c2.x, 0.f)) * (1.f / 3.f);
      r.y = (fmaxf(bf2f((ushort)(r0.x >> 16)) + a01 + c0.y, 0.f) +
             fmaxf(bf2f((ushort)(r1.x >> 16)) + a11 + c1.y, 0.f) +
             fmaxf(bf2f((ushort)(r2.x >> 16)) + a21 + c2.y, 0.f)) * (1.f / 3.f);
      r.z = (fmaxf(bf2f((ushort)r0.y) + a02 + c0.z, 0.f) +
             fmaxf(bf2f((ushort)r1.y) + a12 + c1.z, 0.f) +
             fmaxf(bf2f((ushort)r2.y) + a22 + c2.z, 0.f)) * (1.f / 3.f);
      r.w = (fmaxf(bf2f((ushort)(r0.y >> 16)) + a03 + c0.w, 0.f) +
             fmaxf(bf2f((ushort)(r1.y >> 16)) + a13 + c1.w, 0.f) +
             fmaxf(bf2f((ushort)(r2.y >> 16)) + a23 + c2.w, 0.f)) * (1.f / 3.f);
      *(float4*)(hm + o4) = r;
    }
  }
}

// ---------------- BN stats on h ----------------
__global__ __launch_bounds__(256) void k_bnstats(const float* __restrict__ h,
                                                 float* __restrict__ sum,
                                                 float* __restrict__ sq) {
  int f = threadIdx.x & 63, g = threadIdx.x >> 6;
  float s = 0.f, s2 = 0.f;
  for (int n = blockIdx.x * 4 + g; n < NN; n += gridDim.x * 4) {
    float v = h[(long)n * 64 + f];
    s += v; s2 += v * v;
  }
  __shared__ float ls[512];
  ls[threadIdx.x] = s;
  ls[256 + threadIdx.x] = s2;
  __syncthreads();
  if (threadIdx.x < 64) {
    float ts  = ls[f] + ls[64 + f] + ls[128 + f] + ls[192 + f];
    float ts2 = ls[256 + f] + ls[320 + f] + ls[384 + f] + ls[448 + f];
    atomicAdd(&sum[f], ts);
    atomicAdd(&sq[f], ts2);
  }
}

// ---------------- out = relu(g*(h-mu)*rsqrt(var+eps)+be)
__global__ void k_bnfin(const float* __restrict__ h, const float* __restrict__ sum,
                        const float* __restrict__ sq, const float* __restrict__ gam,
                        const float* __restrict__ bet, float* __restrict__ out) {
  long i4 = (long)blockIdx.x * 256 + threadIdx.x;
  if (i4 >= (long)NF / 4) return;
  long i = i4 * 4;
  int f = (int)(i & 63);
  float4 v = *(const float4*)(h + i);
  float o[4] = {v.x, v.y, v.z, v.w};
  float r[4];
#pragma unroll
  for (int j = 0; j < 4; ++j) {
    int fj = f + j;
    float mu = sum[fj] * (1.f / NN);
    float var = sq[fj] * (1.f / NN) - mu * mu;
    float inv = rsqrtf(var + EPSBN);
    float y = gam[fj] * (o[j] - mu) * inv + bet[fj];
    r[j] = fmaxf(y, 0.f);
  }
  float4 ov = {r[0], r[1], r[2], r[3]};
  *(float4*)(out + i) = ov;
}

extern "C" void kernel_launch(void* const* d_in, const int* in_sizes, int n_in,
                              void* d_out, int out_size, void* d_ws, size_t ws_size,
                              hipStream_t stream) {
  const float* x   = (const float*)d_in[0];
  const int*   ei  = (const int*)d_in[1];
  const float* wts = (const float*)d_in[2];
  const int* row = ei;        // edge_index[0]
  const int* col = ei + NE;   // edge_index[1]

  // workspace layout (8B-aligned where needed)
  unsigned long long* dc = (unsigned long long*)d_ws;  // NN u64
  int*   cnt      = (int*)(dc + NN);           // NN
  int*   rowstart = cnt + NN;                  // NN+1
  int*   cursor   = rowstart + NN + 1;         // NN
  int*   pad      = cursor + NN;               // 1 (align edges to 8B)
  int2*  edges    = (int2*)(pad + 1);          // NE int2
  float* dis      = (float*)(edges + NE);      // NN
  float* h        = dis + NN;                  // NF f32
  ushort* Bbf     = (ushort*)(h + NF);         // KNF bf16 root [k][n][f]
  ushort* Y0bf    = Bbf + KNF;                 // KNF bf16 t=0 result [k][n][f]
  ushort* AbfM    = Y0bf + KNF;                // NN*192 bf16 messages [n][k][f]
  float* bns      = (float*)(AbfM + (long)NN * 192); // 128
  int*   part     = (int*)(bns + 128);         // 512
  int*   pbase    = part + 512;                // 512

  // --- norm + CSR build (once) ---
  hipMemsetAsync(dc, 0, NN * sizeof(unsigned long long), stream);
  int eb = (NE + 255) / 256;
  k_degcnt<<<eb, 256, 0, stream>>>(col, wts, dc);
  k_sblk<<<SBLK, 256, 0, stream>>>(dc, dis, cnt, part);
  k_sscan<<<1, 512, 0, stream>>>(part, pbase);
  k_sfin<<<SBLK, 256, 0, stream>>>(cnt, pbase, rowstart, cursor);
  k_place<<<eb, 256, 0, stream>>>(row, col, wts, dis, cursor, edges);

  dim3 gg((NN + 255) / 256, KK);
  int gatherBlocks = (NN + 3) / 4;
  int nfBlocks = NF / 4 / 256;      // 6250 exact

  for (int layer = 0; layer < 3; ++layer) {
    const float* iw = (const float*)d_in[3 + 6 * layer];  // [K,F,F]
    const float* w  = (const float*)d_in[4 + 6 * layer];  // [K,1,F,F]
    const float* rw = (const float*)d_in[5 + 6 * layer];  // [K,2,F,F]
    const float* bs = (const float*)d_in[6 + 6 * layer];  // [K,2,1,F]
    const float* gm = (const float*)d_in[7 + 6 * layer];  // [F]
    const float* bt = (const float*)d_in[8 + 6 * layer];  // [F]
    const float* xin = (layer == 0) ? x : h;

    // t=0: AbfM = xin@iw (bf16), Bbf = xin@rw0 (bf16); Y0bf = relu(gather + root + b0)
    k_gemm2<true><<<gg, 256, 0, stream>>>((const ushort*)0, xin, iw, 4096, rw, 8192, AbfM, Bbf);
    k_gather<0><<<gatherBlocks, 256, 0, stream>>>(rowstart, edges, AbfM, Bbf, Y0bf, h, bs, 0);
    // t=1: AbfM = Y0bf@w (bf16), Bbf = xin@rw1 (bf16); h = mean_k relu(gather + root + b1)
    k_gemm2<false><<<gg, 256, 0, stream>>>(Y0bf, xin, w, 4096, rw + 4096, 8192, AbfM, Bbf);
    k_gather<1><<<gatherBlocks, 256, 0, stream>>>(rowstart, edges, AbfM, Bbf, Y0bf, h, bs, 1);
    // BN stats + finalize + relu
    hipMemsetAsync(bns, 0, 2 * 64 * sizeof(float), stream);
    k_bnstats<<<1024, 256, 0, stream>>>(h, bns, bns + 64);
    float* dst = (layer == 2) ? (float*)d_out : h;
    k_bnfin<<<nfBlocks, 256, 0, stream>>>(h, bns, bns + 64, gm, bt, dst);
  }
}

// Round 9
// 1199.713 us; speedup vs baseline: 86.5222x; 1.2739x over previous
//
#include <hip/hip_runtime.h>

#define NN 100000
#define NE 1600000
#define FD 64
#define KK 3
#define NF (NN*FD)            // 6,400,000
#define KNF (KK*NF)           // 19,200,000
#define EPSBN 1e-5f
#define SBLK ((NN + 255) / 256)   // 391 scan blocks
#define DEGSCALE 262144.0f        // 2^18 fixed-point for weighted degree

typedef unsigned short ushort;
typedef unsigned int uint;
typedef __attribute__((ext_vector_type(8))) short short8;
typedef __attribute__((ext_vector_type(4))) float f32x4;

__device__ inline float bf2f(ushort u) { return __uint_as_float((unsigned)u << 16); }
__device__ inline unsigned pk_bf16(float a, float b) {
  unsigned ua = __float_as_uint(a); ua += 0x7FFF + ((ua >> 16) & 1);
  unsigned ub = __float_as_uint(b); ub += 0x7FFF + ((ub >> 16) & 1);
  return (ua >> 16) | (ub & 0xFFFF0000u);
}
__device__ inline ushort f2bf(float v) {
  unsigned u = __float_as_uint(v); u += 0x7FFF + ((u >> 16) & 1);
  return (ushort)(u >> 16);
}

// ---------------- graph norm + CSR build ----------------
__global__ void k_degcnt(const int* __restrict__ col, const float* __restrict__ w,
                         unsigned long long* __restrict__ dc) {
  int e = blockIdx.x * 256 + threadIdx.x;
  if (e < NE) {
    unsigned fx = __float2uint_rn(w[e] * DEGSCALE);
    atomicAdd(&dc[col[e]], (1ULL << 32) | (unsigned long long)fx);
  }
}

__global__ __launch_bounds__(256) void k_sblk(const unsigned long long* __restrict__ dc,
                                              float* __restrict__ dis, int* __restrict__ cnt,
                                              int* __restrict__ part) {
  int i = blockIdx.x * 256 + threadIdx.x;
  int v = 0;
  if (i < NN) {
    unsigned long long u = dc[i];
    float d = (float)(unsigned)u * (1.0f / DEGSCALE);
    dis[i] = d > 0.f ? rsqrtf(d) : 0.f;
    v = (int)(u >> 32);
    cnt[i] = v;
  }
#pragma unroll
  for (int off = 32; off; off >>= 1) v += __shfl_down(v, off);
  __shared__ int ws[4];
  if ((threadIdx.x & 63) == 0) ws[threadIdx.x >> 6] = v;
  __syncthreads();
  if (threadIdx.x == 0) part[blockIdx.x] = ws[0] + ws[1] + ws[2] + ws[3];
}

__global__ __launch_bounds__(512) void k_sscan(const int* __restrict__ part,
                                               int* __restrict__ base) {
  __shared__ int ls[512];
  int tid = threadIdx.x;
  int v = (tid < SBLK) ? part[tid] : 0;
  ls[tid] = v;
  __syncthreads();
  for (int off = 1; off < 512; off <<= 1) {
    int u = (tid >= off) ? ls[tid - off] : 0;
    __syncthreads();
    ls[tid] += u;
    __syncthreads();
  }
  base[tid] = tid ? ls[tid - 1] : 0;
}

__global__ __launch_bounds__(256) void k_sfin(const int* __restrict__ cnt,
                                              const int* __restrict__ base,
                                              int* __restrict__ rowstart,
                                              int* __restrict__ cursor) {
  __shared__ int ls[256];
  int i = blockIdx.x * 256 + threadIdx.x;
  int v = (i < NN) ? cnt[i] : 0;
  ls[threadIdx.x] = v;
  __syncthreads();
  for (int off = 1; off < 256; off <<= 1) {
    int u = (threadIdx.x >= off) ? ls[threadIdx.x - off] : 0;
    __syncthreads();
    ls[threadIdx.x] += u;
    __syncthreads();
  }
  int excl = base[blockIdx.x] + ls[threadIdx.x] - v;
  if (i < NN) {
    rowstart[i] = excl;
    cursor[i] = excl;
    if (i == NN - 1) rowstart[NN] = excl + v;
  }
}

__global__ void k_place(const int* __restrict__ row, const int* __restrict__ col,
                        const float* __restrict__ w, const float* __restrict__ dis,
                        int* __restrict__ cursor, int2* __restrict__ edges) {
  int e = blockIdx.x * 256 + threadIdx.x;
  if (e >= NE) return;
  int r = row[e], c = col[e];
  float nm = dis[r] * w[e] * dis[c];
  int p = atomicAdd(&cursor[c], 1);
  edges[p] = make_int2(r, __float_as_int(nm));
}

// ---------------- weight fragment prep (per layer) ----------------
// frag[(which*3+k)*8 + ct*2 + ks][lane] = uint4 of 8 bf16:
//   W[ks*32 + (lane>>4)*8 + j][ct*16 + (lane&15)], j = 0..7
// which: 0 = iw[k], 1 = w[k][0], 2 = rw[k][0], 3 = rw[k][1]
__global__ __launch_bounds__(64) void k_wfrag(const float* __restrict__ iw,
                                              const float* __restrict__ w,
                                              const float* __restrict__ rw,
                                              uint4* __restrict__ frag) {
  int m = blockIdx.x;              // which*3 + k, 0..11
  int which = m / 3, k = m % 3;
  const float* src;
  if (which == 0) src = iw + k * 4096;
  else if (which == 1) src = w + k * 4096;
  else if (which == 2) src = rw + k * 8192;
  else src = rw + k * 8192 + 4096;
  int sub = blockIdx.y;            // ct*2 + ks, 0..7
  int ks = sub & 1, ct = sub >> 1;
  int l = threadIdx.x;
  int r0 = ks * 32 + (l >> 4) * 8;
  int c = ct * 16 + (l & 15);
  uint4 o;
  o.x = pk_bf16(src[(r0 + 0) * 64 + c], src[(r0 + 1) * 64 + c]);
  o.y = pk_bf16(src[(r0 + 2) * 64 + c], src[(r0 + 3) * 64 + c]);
  o.z = pk_bf16(src[(r0 + 4) * 64 + c], src[(r0 + 5) * 64 + c]);
  o.w = pk_bf16(src[(r0 + 6) * 64 + c], src[(r0 + 7) * 64 + c]);
  frag[(m * 8 + sub) * 64 + l] = o;
}

// ---------------- f32 -> bf16 conversion ----------------
__global__ void k_tobf(const float* __restrict__ in, ushort* __restrict__ out) {
  long i = ((long)blockIdx.x * 256 + threadIdx.x) * 4;
  float4 v = *(const float4*)(in + i);
  uint2 u;
  u.x = pk_bf16(v.x, v.y);
  u.y = pk_bf16(v.z, v.w);
  *(uint2*)(out + i) = u;
}

// ---------------- MFMA dual GEMM ----------------
// outA[n][k][f] (bf16) = inA_row @ WA[k];  outB[k][n][f] (bf16) = inB_row @ WB[k]
// SAME: phase-A input == inB (xbf). !SAME: phase-A input = inA (Y0bf, [k][n][f]).
// Block = 4 waves x 4 row-tiles of 16 = 256 rows. MFMA 16x16x32 bf16.
template <bool SAME>
__global__ __launch_bounds__(256) void k_gemm2m(
    const ushort* __restrict__ inA,
    const ushort* __restrict__ inB,
    const uint4* __restrict__ wfA,
    const uint4* __restrict__ wfB,
    ushort* __restrict__ outA, ushort* __restrict__ outB) {
  const int k = blockIdx.y;
  const int wv = threadIdx.x >> 6;
  const int l = threadIdx.x & 63;
  const int lg = l >> 4;          // k-chunk for operands; row-group for D
  const int lr = l & 15;          // row for A-frag; col for B-frag / D
  short8 fA[4][2], fB[4][2];
#pragma unroll
  for (int ct = 0; ct < 4; ++ct)
#pragma unroll
    for (int ks = 0; ks < 2; ++ks) {
      fA[ct][ks] = *(const short8*)&wfA[(k * 8 + ct * 2 + ks) * 64 + l];
      fB[ct][ks] = *(const short8*)&wfB[(k * 8 + ct * 2 + ks) * 64 + l];
    }
  const ushort* srcA = SAME ? inB : (inA + (long)k * NF);
  const int bb = blockIdx.x * 256;
  for (int rt = 0; rt < 4; ++rt) {
    const int tb = bb + rt * 64 + wv * 16;
    int ra = tb + lr; if (ra >= NN) ra = NN - 1;     // clamp loads; stores predicated
    const long ao = (long)ra * 64 + lg * 8;
    short8 a0 = *(const short8*)(srcA + ao);
    short8 a1 = *(const short8*)(srcA + ao + 32);
    // ---- phase A: message operand -> AbfM [n][k][f] ----
#pragma unroll
    for (int ct = 0; ct < 4; ++ct) {
      f32x4 acc = {0.f, 0.f, 0.f, 0.f};
      acc = __builtin_amdgcn_mfma_f32_16x16x32_bf16(a0, fA[ct][0], acc, 0, 0, 0);
      acc = __builtin_amdgcn_mfma_f32_16x16x32_bf16(a1, fA[ct][1], acc, 0, 0, 0);
      const int f = ct * 16 + lr;
      ushort* op = outA + (long)(tb + lg * 4) * 192 + k * 64 + f;
#pragma unroll
      for (int r = 0; r < 4; ++r)
        if (tb + lg * 4 + r < NN) op[(long)r * 192] = f2bf(acc[r]);
    }
    // ---- phase B: root term -> Bbf [k][n][f] ----
    short8 b0, b1;
    if (SAME) { b0 = a0; b1 = a1; }
    else {
      b0 = *(const short8*)(inB + ao);
      b1 = *(const short8*)(inB + ao + 32);
    }
#pragma unroll
    for (int ct = 0; ct < 4; ++ct) {
      f32x4 acc = {0.f, 0.f, 0.f, 0.f};
      acc = __builtin_amdgcn_mfma_f32_16x16x32_bf16(b0, fB[ct][0], acc, 0, 0, 0);
      acc = __builtin_amdgcn_mfma_f32_16x16x32_bf16(b1, fB[ct][1], acc, 0, 0, 0);
      const int f = ct * 16 + lr;
      ushort* op = outB + (long)k * NF + (long)(tb + lg * 4) * 64 + f;
#pragma unroll
      for (int r = 0; r < 4; ++r)
        if (tb + lg * 4 + r < NN) op[(long)r * 64] = f2bf(acc[r]);
    }
  }
}

// ---------------- fused gather + root + bias + relu (+ optional k-mean) ----------------
#define GSTEP4(EV) do { \
  int2 _e = (EV); \
  float _m = __int_as_float(_e.y); \
  const uint2* _p = (const uint2*)(Abf + (long)_e.x * 192) + fi; \
  uint2 _u0 = _p[0], _u1 = _p[16], _u2 = _p[32]; \
  a00 = fmaf(bf2f((ushort)_u0.x), _m, a00); a01 = fmaf(bf2f((ushort)(_u0.x >> 16)), _m, a01); \
  a02 = fmaf(bf2f((ushort)_u0.y), _m, a02); a03 = fmaf(bf2f((ushort)(_u0.y >> 16)), _m, a03); \
  a10 = fmaf(bf2f((ushort)_u1.x), _m, a10); a11 = fmaf(bf2f((ushort)(_u1.x >> 16)), _m, a11); \
  a12 = fmaf(bf2f((ushort)_u1.y), _m, a12); a13 = fmaf(bf2f((ushort)(_u1.y >> 16)), _m, a13); \
  a20 = fmaf(bf2f((ushort)_u2.x), _m, a20); a21 = fmaf(bf2f((ushort)(_u2.x >> 16)), _m, a21); \
  a22 = fmaf(bf2f((ushort)_u2.y), _m, a22); a23 = fmaf(bf2f((ushort)(_u2.y >> 16)), _m, a23); \
} while (0)

#define RED2(v) do { (v) += __shfl_xor((v), 16); (v) += __shfl_xor((v), 32); } while (0)

template <int MODE>   // 0: write y0 (bf16 planar), 1: write hm = mean_k (f32)
__global__ __launch_bounds__(256) void k_gather(const int* __restrict__ rowstart,
                                                const int2* __restrict__ edges,
                                                const ushort* __restrict__ Abf,
                                                const ushort* __restrict__ Broot,
                                                ushort* __restrict__ y0,
                                                float* __restrict__ hm,
                                                const float* __restrict__ bias, int t) {
  int wave = threadIdx.x >> 6;
  int lane = threadIdx.x & 63;
  int grp = lane >> 4;
  int fi = lane & 15;
  int n = blockIdx.x * 4 + wave;
  if (n >= NN) return;
  int s = rowstart[n], e = rowstart[n + 1];
  float a00 = 0.f, a01 = 0.f, a02 = 0.f, a03 = 0.f;
  float a10 = 0.f, a11 = 0.f, a12 = 0.f, a13 = 0.f;
  float a20 = 0.f, a21 = 0.f, a22 = 0.f, a23 = 0.f;
  int j = s;
  for (; j + 8 <= e; j += 8) {
    GSTEP4(edges[j + grp]);
    GSTEP4(edges[j + 4 + grp]);
  }
  if (j + 4 <= e) { GSTEP4(edges[j + grp]); j += 4; }
  if (j < e) {
    int idx = j + grp;
    int2 ee = edges[idx < e ? idx : (e - 1)];
    if (idx >= e) ee.y = 0;
    GSTEP4(ee);
  }
  RED2(a00); RED2(a01); RED2(a02); RED2(a03);
  RED2(a10); RED2(a11); RED2(a12); RED2(a13);
  RED2(a20); RED2(a21); RED2(a22); RED2(a23);

  long o4 = (long)n * 64 + 4 * fi;
  if (MODE == 0) {
    if (grp < 3) {
      float4 bb = *(const float4*)(bias + (grp * 2 + t) * 64 + 4 * fi);
      uint2 ru = *(const uint2*)(Broot + (long)grp * NF + o4);
      float aX, aY, aZ, aW;
      if (grp == 0)      { aX = a00; aY = a01; aZ = a02; aW = a03; }
      else if (grp == 1) { aX = a10; aY = a11; aZ = a12; aW = a13; }
      else               { aX = a20; aY = a21; aZ = a22; aW = a23; }
      float rx = fmaxf(bf2f((ushort)ru.x)         + aX + bb.x, 0.f);
      float ry = fmaxf(bf2f((ushort)(ru.x >> 16)) + aY + bb.y, 0.f);
      float rz = fmaxf(bf2f((ushort)ru.y)         + aZ + bb.z, 0.f);
      float rw = fmaxf(bf2f((ushort)(ru.y >> 16)) + aW + bb.w, 0.f);
      uint2 ou;
      ou.x = pk_bf16(rx, ry);
      ou.y = pk_bf16(rz, rw);
      *(uint2*)(y0 + (long)grp * NF + o4) = ou;
    }
  } else {
    if (grp == 0) {
      uint2 r0 = *(const uint2*)(Broot + o4);
      uint2 r1 = *(const uint2*)(Broot + NF + o4);
      uint2 r2 = *(const uint2*)(Broot + 2L * NF + o4);
      float4 c0 = *(const float4*)(bias + (0 * 2 + t) * 64 + 4 * fi);
      float4 c1 = *(const float4*)(bias + (1 * 2 + t) * 64 + 4 * fi);
      float4 c2 = *(const float4*)(bias + (2 * 2 + t) * 64 + 4 * fi);
      float4 r;
      r.x = (fmaxf(bf2f((ushort)r0.x) + a00 + c0.x, 0.f) +
             fmaxf(bf2f((ushort)r1.x) + a10 + c1.x, 0.f) +
             fmaxf(bf2f((ushort)r2.x) + a20 + c2.x, 0.f)) * (1.f / 3.f);
      r.y = (fmaxf(bf2f((ushort)(r0.x >> 16)) + a01 + c0.y, 0.f) +
             fmaxf(bf2f((ushort)(r1.x >> 16)) + a11 + c1.y, 0.f) +
             fmaxf(bf2f((ushort)(r2.x >> 16)) + a21 + c2.y, 0.f)) * (1.f / 3.f);
      r.z = (fmaxf(bf2f((ushort)r0.y) + a02 + c0.z, 0.f) +
             fmaxf(bf2f((ushort)r1.y) + a12 + c1.z, 0.f) +
             fmaxf(bf2f((ushort)r2.y) + a22 + c2.z, 0.f)) * (1.f / 3.f);
      r.w = (fmaxf(bf2f((ushort)(r0.y >> 16)) + a03 + c0.w, 0.f) +
             fmaxf(bf2f((ushort)(r1.y >> 16)) + a13 + c1.w, 0.f) +
             fmaxf(bf2f((ushort)(r2.y >> 16)) + a23 + c2.w, 0.f)) * (1.f / 3.f);
      *(float4*)(hm + o4) = r;
    }
  }
}

// ---------------- BN stats on hm ----------------
__global__ __launch_bounds__(256) void k_bnstats(const float* __restrict__ h,
                                                 float* __restrict__ sum,
                                                 float* __restrict__ sq) {
  int f = threadIdx.x & 63, g = threadIdx.x >> 6;
  float s = 0.f, s2 = 0.f;
  for (int n = blockIdx.x * 4 + g; n < NN; n += gridDim.x * 4) {
    float v = h[(long)n * 64 + f];
    s += v; s2 += v * v;
  }
  __shared__ float ls[512];
  ls[threadIdx.x] = s;
  ls[256 + threadIdx.x] = s2;
  __syncthreads();
  if (threadIdx.x < 64) {
    float ts  = ls[f] + ls[64 + f] + ls[128 + f] + ls[192 + f];
    float ts2 = ls[256 + f] + ls[320 + f] + ls[384 + f] + ls[448 + f];
    atomicAdd(&sum[f], ts);
    atomicAdd(&sq[f], ts2);
  }
}

// ---------------- BN finalize: FINAL -> f32 d_out, else bf16 next-layer input ----
template <bool FINAL>
__global__ void k_bnfin(const float* __restrict__ h, const float* __restrict__ sum,
                        const float* __restrict__ sq, const float* __restrict__ gam,
                        const float* __restrict__ bet,
                        float* __restrict__ outf, ushort* __restrict__ outbf) {
  long i4 = (long)blockIdx.x * 256 + threadIdx.x;
  if (i4 >= (long)NF / 4) return;
  long i = i4 * 4;
  int f = (int)(i & 63);
  float4 v = *(const float4*)(h + i);
  float o[4] = {v.x, v.y, v.z, v.w};
  float r[4];
#pragma unroll
  for (int j = 0; j < 4; ++j) {
    int fj = f + j;
    float mu = sum[fj] * (1.f / NN);
    float var = sq[fj] * (1.f / NN) - mu * mu;
    float inv = rsqrtf(var + EPSBN);
    float y = gam[fj] * (o[j] - mu) * inv + bet[fj];
    r[j] = fmaxf(y, 0.f);
  }
  if (FINAL) {
    float4 ov = {r[0], r[1], r[2], r[3]};
    *(float4*)(outf + i) = ov;
  } else {
    uint2 u;
    u.x = pk_bf16(r[0], r[1]);
    u.y = pk_bf16(r[2], r[3]);
    *(uint2*)(outbf + i) = u;
  }
}

extern "C" void kernel_launch(void* const* d_in, const int* in_sizes, int n_in,
                              void* d_out, int out_size, void* d_ws, size_t ws_size,
                              hipStream_t stream) {
  const float* x   = (const float*)d_in[0];
  const int*   ei  = (const int*)d_in[1];
  const float* wts = (const float*)d_in[2];
  const int* row = ei;        // edge_index[0]
  const int* col = ei + NE;   // edge_index[1]

  // workspace layout (4B words; all vector-accessed arrays 16B-aligned)
  unsigned long long* dc = (unsigned long long*)d_ws;        // 2*NN w
  uint4* wfrag    = (uint4*)((int*)d_ws + 2 * NN);           // 18432 uint4 = 73728 w
  int2*  edges    = (int2*)((int*)wfrag + 73728);            // 2*NE w
  int*   cnt      = (int*)edges + 2 * NE;                    // NN
  int*   rowstart = cnt + NN;                                // NN+1 (pad to NN+4)
  int*   cursor   = rowstart + NN + 4;                       // NN
  float* dis      = (float*)(cursor + NN);                   // NN
  float* hm       = dis + NN;                                // NF f32
  ushort* xbf     = (ushort*)(hm + NF);                      // NF bf16  (NF/2 w)
  ushort* Bbf     = xbf + NF;                                // KNF bf16 root [k][n][f]
  ushort* Y0bf    = Bbf + KNF;                               // KNF bf16 t=0 act [k][n][f]
  ushort* AbfM    = Y0bf + KNF;                              // NN*192 bf16 msgs [n][k][f]
  float* bns      = (float*)(AbfM + (long)NN * 192);         // 128
  int*   part     = (int*)(bns + 128);                       // 512
  int*   pbase    = part + 512;                              // 512

  // --- norm + CSR build + weight frags + x->bf16 (once) ---
  hipMemsetAsync(dc, 0, NN * sizeof(unsigned long long), stream);
  int eb = (NE + 255) / 256;
  k_degcnt<<<eb, 256, 0, stream>>>(col, wts, dc);
  k_sblk<<<SBLK, 256, 0, stream>>>(dc, dis, cnt, part);
  k_sscan<<<1, 512, 0, stream>>>(part, pbase);
  k_sfin<<<SBLK, 256, 0, stream>>>(cnt, pbase, rowstart, cursor);
  k_place<<<eb, 256, 0, stream>>>(row, col, wts, dis, cursor, edges);
  for (int L = 0; L < 3; ++L) {
    k_wfrag<<<dim3(12, 8), 64, 0, stream>>>((const float*)d_in[3 + 6 * L],
                                            (const float*)d_in[4 + 6 * L],
                                            (const float*)d_in[5 + 6 * L],
                                            wfrag + (long)L * 6144);
  }
  k_tobf<<<NF / 4 / 256, 256, 0, stream>>>(x, xbf);

  dim3 gg((NN + 255) / 256, KK);
  int gatherBlocks = (NN + 3) / 4;
  int nfBlocks = NF / 4 / 256;      // 6250 exact

  for (int layer = 0; layer < 3; ++layer) {
    const float* bs = (const float*)d_in[6 + 6 * layer];  // [K,2,1,F]
    const float* gm = (const float*)d_in[7 + 6 * layer];  // [F]
    const float* bt = (const float*)d_in[8 + 6 * layer];  // [F]
    const uint4* wfL = wfrag + (long)layer * 6144;
    // which blocks: 0=iw, 1=w, 2=rw0, 3=rw1 (each 1536 uint4)
    // t=0: AbfM = xbf@iw, Bbf = xbf@rw0 (both bf16); Y0bf = relu(gather + root + b0)
    k_gemm2m<true><<<gg, 256, 0, stream>>>((const ushort*)0, xbf,
                                           wfL + 0 * 1536, wfL + 2 * 1536, AbfM, Bbf);
    k_gather<0><<<gatherBlocks, 256, 0, stream>>>(rowstart, edges, AbfM, Bbf, Y0bf, hm, bs, 0);
    // t=1: AbfM = Y0bf@w, Bbf = xbf@rw1; hm = mean_k relu(gather + root + b1)
    k_gemm2m<false><<<gg, 256, 0, stream>>>(Y0bf, xbf,
                                            wfL + 1 * 1536, wfL + 3 * 1536, AbfM, Bbf);
    k_gather<1><<<gatherBlocks, 256, 0, stream>>>(rowstart, edges, AbfM, Bbf, Y0bf, hm, bs, 1);
    // BN stats + finalize + relu
    hipMemsetAsync(bns, 0, 2 * 64 * sizeof(float), stream);
    k_bnstats<<<1024, 256, 0, stream>>>(hm, bns, bns + 64);
    if (layer == 2)
      k_bnfin<true><<<nfBlocks, 256, 0, stream>>>(hm, bns, bns + 64, gm, bt, (float*)d_out, (ushort*)0);
    else
      k_bnfin<false><<<nfBlocks, 256, 0, stream>>>(hm, bns, bns + 64, gm, bt, (float*)0, xbf);
  }
}

// Round 10
// 963.690 us; speedup vs baseline: 107.7128x; 1.2449x over previous
//
#include <hip/hip_runtime.h>

#define NN 100000
#define NE 1600000
#define FD 64
#define KK 3
#define NF (NN*FD)            // 6,400,000
#define EPSBN 1e-5f
#define SBLK ((NN + 255) / 256)   // 391
#define DEGSCALE 262144.0f        // 2^18 fixed-point for weighted degree

typedef unsigned short ushort;
typedef unsigned int uint;
typedef __attribute__((ext_vector_type(8))) short short8;
typedef __attribute__((ext_vector_type(4))) float f32x4;

__device__ inline float bf2f(ushort u) { return __uint_as_float((unsigned)u << 16); }
__device__ inline unsigned pk_bf16(float a, float b) {
  unsigned ua = __float_as_uint(a); ua += 0x7FFF + ((ua >> 16) & 1);
  unsigned ub = __float_as_uint(b); ub += 0x7FFF + ((ub >> 16) & 1);
  return (ua >> 16) | (ub & 0xFFFF0000u);
}
__device__ inline ushort f2bf(float v) {
  unsigned u = __float_as_uint(v); u += 0x7FFF + ((u >> 16) & 1);
  return (ushort)(u >> 16);
}

// ---------------- graph norm + CSR build ----------------
__global__ void k_degcnt(const int* __restrict__ col, const float* __restrict__ w,
                         unsigned long long* __restrict__ dc) {
  int e = blockIdx.x * 256 + threadIdx.x;
  if (e < NE) {
    unsigned fx = __float2uint_rn(w[e] * DEGSCALE);
    atomicAdd(&dc[col[e]], (1ULL << 32) | (unsigned long long)fx);
  }
}

__global__ __launch_bounds__(256) void k_sblk(const unsigned long long* __restrict__ dc,
                                              float* __restrict__ dis, int* __restrict__ cnt,
                                              int* __restrict__ part) {
  int i = blockIdx.x * 256 + threadIdx.x;
  int v = 0;
  if (i < NN) {
    unsigned long long u = dc[i];
    float d = (float)(unsigned)u * (1.0f / DEGSCALE);
    dis[i] = d > 0.f ? rsqrtf(d) : 0.f;
    v = (int)(u >> 32);
    cnt[i] = v;
  }
#pragma unroll
  for (int off = 32; off; off >>= 1) v += __shfl_down(v, off);
  __shared__ int ws[4];
  if ((threadIdx.x & 63) == 0) ws[threadIdx.x >> 6] = v;
  __syncthreads();
  if (threadIdx.x == 0) part[blockIdx.x] = ws[0] + ws[1] + ws[2] + ws[3];
}

__global__ __launch_bounds__(512) void k_sscan(const int* __restrict__ part,
                                               int* __restrict__ base) {
  __shared__ int ls[512];
  int tid = threadIdx.x;
  int v = (tid < SBLK) ? part[tid] : 0;
  ls[tid] = v;
  __syncthreads();
  for (int off = 1; off < 512; off <<= 1) {
    int u = (tid >= off) ? ls[tid - off] : 0;
    __syncthreads();
    ls[tid] += u;
    __syncthreads();
  }
  base[tid] = tid ? ls[tid - 1] : 0;
}

__global__ __launch_bounds__(256) void k_sfin(const int* __restrict__ cnt,
                                              const int* __restrict__ base,
                                              int* __restrict__ rowstart,
                                              int* __restrict__ cursor) {
  __shared__ int ls[256];
  int i = blockIdx.x * 256 + threadIdx.x;
  int v = (i < NN) ? cnt[i] : 0;
  ls[threadIdx.x] = v;
  __syncthreads();
  for (int off = 1; off < 256; off <<= 1) {
    int u = (threadIdx.x >= off) ? ls[threadIdx.x - off] : 0;
    __syncthreads();
    ls[threadIdx.x] += u;
    __syncthreads();
  }
  int excl = base[blockIdx.x] + ls[threadIdx.x] - v;
  if (i < NN) {
    rowstart[i] = excl;
    cursor[i] = excl;
    if (i == NN - 1) rowstart[NN] = excl + v;
  }
}

__global__ void k_place(const int* __restrict__ row, const int* __restrict__ col,
                        const float* __restrict__ w, const float* __restrict__ dis,
                        int* __restrict__ cursor, int2* __restrict__ edges) {
  int e = blockIdx.x * 256 + threadIdx.x;
  if (e >= NE) return;
  int r = row[e], c = col[e];
  float nm = dis[r] * w[e] * dis[c];
  int p = atomicAdd(&cursor[c], 1);
  edges[p] = make_int2(r, __float_as_int(nm));
}

// ---------------- weight fragment prep (per layer) ----------------
// frag[(which*3+k)*8 + ct*2 + ks][lane] = 8 bf16: W[ks*32+(l>>4)*8+j][ct*16+(l&15)]
// which: 0 = iw[k], 1 = w[k][0], 2 = rw[k][0], 3 = rw[k][1]
__global__ __launch_bounds__(64) void k_wfrag(const float* __restrict__ iw,
                                              const float* __restrict__ w,
                                              const float* __restrict__ rw,
                                              uint4* __restrict__ frag) {
  int m = blockIdx.x;              // which*3 + k
  int which = m / 3, k = m % 3;
  const float* src;
  if (which == 0) src = iw + k * 4096;
  else if (which == 1) src = w + k * 4096;
  else if (which == 2) src = rw + k * 8192;
  else src = rw + k * 8192 + 4096;
  int sub = blockIdx.y;            // ct*2 + ks
  int ks = sub & 1, ct = sub >> 1;
  int l = threadIdx.x;
  int r0 = ks * 32 + (l >> 4) * 8;
  int c = ct * 16 + (l & 15);
  uint4 o;
  o.x = pk_bf16(src[(r0 + 0) * 64 + c], src[(r0 + 1) * 64 + c]);
  o.y = pk_bf16(src[(r0 + 2) * 64 + c], src[(r0 + 3) * 64 + c]);
  o.z = pk_bf16(src[(r0 + 4) * 64 + c], src[(r0 + 5) * 64 + c]);
  o.w = pk_bf16(src[(r0 + 6) * 64 + c], src[(r0 + 7) * 64 + c]);
  frag[(m * 8 + sub) * 64 + l] = o;
}

// ---------------- f32 -> bf16 ----------------
__global__ void k_tobf(const float* __restrict__ in, ushort* __restrict__ out) {
  long i = ((long)blockIdx.x * 256 + threadIdx.x) * 4;
  float4 v = *(const float4*)(in + i);
  uint2 u;
  u.x = pk_bf16(v.x, v.y);
  u.y = pk_bf16(v.z, v.w);
  *(uint2*)(out + i) = u;
}

#define RED2(v) do { (v) += __shfl_xor((v), 16); (v) += __shfl_xor((v), 32); } while (0)

// ---------------- gather of raw x (64 feats): g[n] = sum norm * x[r] ----------------
#define G0STEP(EV) do { \
  int2 _e = (EV); \
  float _m = __int_as_float(_e.y); \
  uint2 _u = ((const uint2*)(xsrc + (long)_e.x * 64))[fi]; \
  a0 = fmaf(bf2f((ushort)_u.x), _m, a0); a1 = fmaf(bf2f((ushort)(_u.x >> 16)), _m, a1); \
  a2 = fmaf(bf2f((ushort)_u.y), _m, a2); a3 = fmaf(bf2f((ushort)(_u.y >> 16)), _m, a3); \
} while (0)

__global__ __launch_bounds__(256) void k_gath0(const int* __restrict__ rowstart,
                                               const int2* __restrict__ edges,
                                               const ushort* __restrict__ xsrc,
                                               ushort* __restrict__ g) {
  int wave = threadIdx.x >> 6;
  int lane = threadIdx.x & 63;
  int grp = lane >> 4;
  int fi = lane & 15;
  int n = blockIdx.x * 4 + wave;
  if (n >= NN) return;
  int s = rowstart[n], e = rowstart[n + 1];
  float a0 = 0.f, a1 = 0.f, a2 = 0.f, a3 = 0.f;
  int j = s;
  for (; j + 8 <= e; j += 8) {
    G0STEP(edges[j + grp]);
    G0STEP(edges[j + 4 + grp]);
  }
  if (j + 4 <= e) { G0STEP(edges[j + grp]); j += 4; }
  if (j < e) {
    int idx = j + grp;
    int2 ee = edges[idx < e ? idx : (e - 1)];
    if (idx >= e) ee.y = 0;
    G0STEP(ee);
  }
  RED2(a0); RED2(a1); RED2(a2); RED2(a3);
  if (grp == 0) {
    uint2 o;
    o.x = pk_bf16(a0, a1);
    o.y = pk_bf16(a2, a3);
    *(uint2*)(g + (long)n * 64 + 4 * fi) = o;
  }
}

// ---------------- gather of y0 (3 planes, [n][192]): G[n][k] = sum norm * y0[r][k] ----------------
#define G1STEP(EV) do { \
  int2 _e = (EV); \
  float _m = __int_as_float(_e.y); \
  const uint2* _p = (const uint2*)(y0 + (long)_e.x * 192) + fi; \
  uint2 _u0 = _p[0], _u1 = _p[16], _u2 = _p[32]; \
  a00 = fmaf(bf2f((ushort)_u0.x), _m, a00); a01 = fmaf(bf2f((ushort)(_u0.x >> 16)), _m, a01); \
  a02 = fmaf(bf2f((ushort)_u0.y), _m, a02); a03 = fmaf(bf2f((ushort)(_u0.y >> 16)), _m, a03); \
  a10 = fmaf(bf2f((ushort)_u1.x), _m, a10); a11 = fmaf(bf2f((ushort)(_u1.x >> 16)), _m, a11); \
  a12 = fmaf(bf2f((ushort)_u1.y), _m, a12); a13 = fmaf(bf2f((ushort)(_u1.y >> 16)), _m, a13); \
  a20 = fmaf(bf2f((ushort)_u2.x), _m, a20); a21 = fmaf(bf2f((ushort)(_u2.x >> 16)), _m, a21); \
  a22 = fmaf(bf2f((ushort)_u2.y), _m, a22); a23 = fmaf(bf2f((ushort)(_u2.y >> 16)), _m, a23); \
} while (0)

__global__ __launch_bounds__(256) void k_gath1(const int* __restrict__ rowstart,
                                               const int2* __restrict__ edges,
                                               const ushort* __restrict__ y0,
                                               ushort* __restrict__ G) {
  int wave = threadIdx.x >> 6;
  int lane = threadIdx.x & 63;
  int grp = lane >> 4;
  int fi = lane & 15;
  int n = blockIdx.x * 4 + wave;
  if (n >= NN) return;
  int s = rowstart[n], e = rowstart[n + 1];
  float a00 = 0.f, a01 = 0.f, a02 = 0.f, a03 = 0.f;
  float a10 = 0.f, a11 = 0.f, a12 = 0.f, a13 = 0.f;
  float a20 = 0.f, a21 = 0.f, a22 = 0.f, a23 = 0.f;
  int j = s;
  for (; j + 8 <= e; j += 8) {
    G1STEP(edges[j + grp]);
    G1STEP(edges[j + 4 + grp]);
  }
  if (j + 4 <= e) { G1STEP(edges[j + grp]); j += 4; }
  if (j < e) {
    int idx = j + grp;
    int2 ee = edges[idx < e ? idx : (e - 1)];
    if (idx >= e) ee.y = 0;
    G1STEP(ee);
  }
  RED2(a00); RED2(a01); RED2(a02); RED2(a03);
  RED2(a10); RED2(a11); RED2(a12); RED2(a13);
  RED2(a20); RED2(a21); RED2(a22); RED2(a23);
  if (grp < 3) {
    float aX, aY, aZ, aW;
    if (grp == 0)      { aX = a00; aY = a01; aZ = a02; aW = a03; }
    else if (grp == 1) { aX = a10; aY = a11; aZ = a12; aW = a13; }
    else               { aX = a20; aY = a21; aZ = a22; aW = a23; }
    uint2 o;
    o.x = pk_bf16(aX, aY);
    o.y = pk_bf16(aZ, aW);
    *(uint2*)(G + (long)n * 192 + grp * 64 + 4 * fi) = o;
  }
}

// ---------------- t=0 fused MFMA: y0[n][k*64+f] = relu(g@iw_k + x@rw0_k + b0_k) ----------------
__global__ __launch_bounds__(256) void k_gemmY0(
    const ushort* __restrict__ g, const ushort* __restrict__ xbf,
    const uint4* __restrict__ wfA, const uint4* __restrict__ wfB,
    const float* __restrict__ bias, ushort* __restrict__ y0) {
  const int k = blockIdx.y;
  const int wv = threadIdx.x >> 6;
  const int l = threadIdx.x & 63;
  const int lg = l >> 4;
  const int lr = l & 15;
  short8 fA[4][2], fB[4][2];
#pragma unroll
  for (int ct = 0; ct < 4; ++ct)
#pragma unroll
    for (int ks = 0; ks < 2; ++ks) {
      fA[ct][ks] = *(const short8*)&wfA[(k * 8 + ct * 2 + ks) * 64 + l];
      fB[ct][ks] = *(const short8*)&wfB[(k * 8 + ct * 2 + ks) * 64 + l];
    }
  const int bb = blockIdx.x * 256;
  for (int rt = 0; rt < 4; ++rt) {
    const int tb = bb + rt * 64 + wv * 16;
    int ra = tb + lr; if (ra >= NN) ra = NN - 1;
    const long ao = (long)ra * 64 + lg * 8;
    short8 a0 = *(const short8*)(g + ao);
    short8 a1 = *(const short8*)(g + ao + 32);
    short8 b0 = *(const short8*)(xbf + ao);
    short8 b1 = *(const short8*)(xbf + ao + 32);
#pragma unroll
    for (int ct = 0; ct < 4; ++ct) {
      f32x4 acc = {0.f, 0.f, 0.f, 0.f};
      acc = __builtin_amdgcn_mfma_f32_16x16x32_bf16(a0, fA[ct][0], acc, 0, 0, 0);
      acc = __builtin_amdgcn_mfma_f32_16x16x32_bf16(a1, fA[ct][1], acc, 0, 0, 0);
      acc = __builtin_amdgcn_mfma_f32_16x16x32_bf16(b0, fB[ct][0], acc, 0, 0, 0);
      acc = __builtin_amdgcn_mfma_f32_16x16x32_bf16(b1, fB[ct][1], acc, 0, 0, 0);
      const int f = ct * 16 + lr;
      const float bv = bias[(k * 2 + 0) * 64 + f];
      ushort* op = y0 + (long)(tb + lg * 4) * 192 + k * 64 + f;
#pragma unroll
      for (int r = 0; r < 4; ++r)
        if (tb + lg * 4 + r < NN) op[(long)r * 192] = f2bf(fmaxf(acc[r] + bv, 0.f));
    }
  }
}

// ---------------- t=1 fused MFMA + mean: hm[n][f] = mean_k relu(G_k@w_k + x@rw1_k + b1_k) ----------------
__global__ __launch_bounds__(256) void k_gemmY1(
    const ushort* __restrict__ G, const ushort* __restrict__ xbf,
    const uint4* __restrict__ wfW, const uint4* __restrict__ wfR,
    const float* __restrict__ bias, float* __restrict__ hm) {
  const int wv = threadIdx.x >> 6;
  const int l = threadIdx.x & 63;
  const int lg = l >> 4;
  const int lr = l & 15;
  const int bb = blockIdx.x * 256;
  for (int rt = 0; rt < 4; ++rt) {
    const int tb = bb + rt * 64 + wv * 16;
    int ra = tb + lr; if (ra >= NN) ra = NN - 1;
    const long xo = (long)ra * 64 + lg * 8;
    short8 ax0 = *(const short8*)(xbf + xo);
    short8 ax1 = *(const short8*)(xbf + xo + 32);
    f32x4 m0 = {0.f, 0.f, 0.f, 0.f}, m1 = m0, m2 = m0, m3 = m0;
#pragma unroll
    for (int k = 0; k < 3; ++k) {
      const long go = (long)ra * 192 + k * 64 + lg * 8;
      short8 g0 = *(const short8*)(G + go);
      short8 g1 = *(const short8*)(G + go + 32);
      const int k8 = k * 8;
#define YCT(CT, M) { \
      short8 fw0 = *(const short8*)&wfW[(k8 + CT * 2 + 0) * 64 + l]; \
      short8 fw1 = *(const short8*)&wfW[(k8 + CT * 2 + 1) * 64 + l]; \
      short8 fr0 = *(const short8*)&wfR[(k8 + CT * 2 + 0) * 64 + l]; \
      short8 fr1 = *(const short8*)&wfR[(k8 + CT * 2 + 1) * 64 + l]; \
      f32x4 acc = {0.f, 0.f, 0.f, 0.f}; \
      acc = __builtin_amdgcn_mfma_f32_16x16x32_bf16(g0, fw0, acc, 0, 0, 0); \
      acc = __builtin_amdgcn_mfma_f32_16x16x32_bf16(g1, fw1, acc, 0, 0, 0); \
      acc = __builtin_amdgcn_mfma_f32_16x16x32_bf16(ax0, fr0, acc, 0, 0, 0); \
      acc = __builtin_amdgcn_mfma_f32_16x16x32_bf16(ax1, fr1, acc, 0, 0, 0); \
      float bv = bias[(k * 2 + 1) * 64 + CT * 16 + lr]; \
      M[0] += fmaxf(acc[0] + bv, 0.f); M[1] += fmaxf(acc[1] + bv, 0.f); \
      M[2] += fmaxf(acc[2] + bv, 0.f); M[3] += fmaxf(acc[3] + bv, 0.f); }
      YCT(0, m0) YCT(1, m1) YCT(2, m2) YCT(3, m3)
#undef YCT
    }
    const int rb = tb + lg * 4;
#pragma unroll
    for (int r = 0; r < 4; ++r) {
      if (rb + r < NN) {
        float* hp = hm + (long)(rb + r) * 64 + lr;
        hp[0]  = m0[r] * (1.f / 3.f);
        hp[16] = m1[r] * (1.f / 3.f);
        hp[32] = m2[r] * (1.f / 3.f);
        hp[48] = m3[r] * (1.f / 3.f);
      }
    }
  }
}

// ---------------- BN stats on hm ----------------
__global__ __launch_bounds__(256) void k_bnstats(const float* __restrict__ h,
                                                 float* __restrict__ sum,
                                                 float* __restrict__ sq) {
  int f = threadIdx.x & 63, g = threadIdx.x >> 6;
  float s = 0.f, s2 = 0.f;
  for (int n = blockIdx.x * 4 + g; n < NN; n += gridDim.x * 4) {
    float v = h[(long)n * 64 + f];
    s += v; s2 += v * v;
  }
  __shared__ float ls[512];
  ls[threadIdx.x] = s;
  ls[256 + threadIdx.x] = s2;
  __syncthreads();
  if (threadIdx.x < 64) {
    float ts  = ls[f] + ls[64 + f] + ls[128 + f] + ls[192 + f];
    float ts2 = ls[256 + f] + ls[320 + f] + ls[384 + f] + ls[448 + f];
    atomicAdd(&sum[f], ts);
    atomicAdd(&sq[f], ts2);
  }
}

// ---------------- BN finalize: FINAL -> f32 d_out, else bf16 next-layer input ----
template <bool FINAL>
__global__ void k_bnfin(const float* __restrict__ h, const float* __restrict__ sum,
                        const float* __restrict__ sq, const float* __restrict__ gam,
                        const float* __restrict__ bet,
                        float* __restrict__ outf, ushort* __restrict__ outbf) {
  long i4 = (long)blockIdx.x * 256 + threadIdx.x;
  if (i4 >= (long)NF / 4) return;
  long i = i4 * 4;
  int f = (int)(i & 63);
  float4 v = *(const float4*)(h + i);
  float o[4] = {v.x, v.y, v.z, v.w};
  float r[4];
#pragma unroll
  for (int j = 0; j < 4; ++j) {
    int fj = f + j;
    float mu = sum[fj] * (1.f / NN);
    float var = sq[fj] * (1.f / NN) - mu * mu;
    float inv = rsqrtf(var + EPSBN);
    float y = gam[fj] * (o[j] - mu) * inv + bet[fj];
    r[j] = fmaxf(y, 0.f);
  }
  if (FINAL) {
    float4 ov = {r[0], r[1], r[2], r[3]};
    *(float4*)(outf + i) = ov;
  } else {
    uint2 u;
    u.x = pk_bf16(r[0], r[1]);
    u.y = pk_bf16(r[2], r[3]);
    *(uint2*)(outbf + i) = u;
  }
}

extern "C" void kernel_launch(void* const* d_in, const int* in_sizes, int n_in,
                              void* d_out, int out_size, void* d_ws, size_t ws_size,
                              hipStream_t stream) {
  const float* x   = (const float*)d_in[0];
  const int*   ei  = (const int*)d_in[1];
  const float* wts = (const float*)d_in[2];
  const int* row = ei;        // edge_index[0]
  const int* col = ei + NE;   // edge_index[1]

  // workspace layout (4B words; vector-accessed arrays kept 16B-aligned)
  unsigned long long* dc = (unsigned long long*)d_ws;        // 2*NN w
  uint4* wfrag    = (uint4*)((int*)d_ws + 2 * NN);           // 18432 uint4 (73728 w)
  int2*  edges    = (int2*)((int*)wfrag + 73728);            // 2*NE w
  int*   cnt      = (int*)edges + 2 * NE;                    // NN
  int*   rowstart = cnt + NN;                                // NN+4
  int*   cursor   = rowstart + NN + 4;                       // NN
  float* dis      = (float*)(cursor + NN);                   // NN
  float* hm       = dis + NN;                                // NF f32
  ushort* xbf     = (ushort*)(hm + NF);                      // NF bf16
  ushort* g       = xbf + NF;                                // NF bf16 (aggregated x)
  ushort* y0      = g + NF;                                  // NN*192 bf16 [n][k*64+f]
  ushort* Gb      = y0 + (long)NN * 192;                     // NN*192 bf16 [n][k*64+f]
  float* bns      = (float*)(Gb + (long)NN * 192);           // 128
  int*   part     = (int*)(bns + 128);                       // 512
  int*   pbase    = part + 512;                              // 512

  // --- norm + CSR build + weight frags + x->bf16 (once) ---
  hipMemsetAsync(dc, 0, NN * sizeof(unsigned long long), stream);
  int eb = (NE + 255) / 256;
  k_degcnt<<<eb, 256, 0, stream>>>(col, wts, dc);
  k_sblk<<<SBLK, 256, 0, stream>>>(dc, dis, cnt, part);
  k_sscan<<<1, 512, 0, stream>>>(part, pbase);
  k_sfin<<<SBLK, 256, 0, stream>>>(cnt, pbase, rowstart, cursor);
  k_place<<<eb, 256, 0, stream>>>(row, col, wts, dis, cursor, edges);
  for (int L = 0; L < 3; ++L) {
    k_wfrag<<<dim3(12, 8), 64, 0, stream>>>((const float*)d_in[3 + 6 * L],
                                            (const float*)d_in[4 + 6 * L],
                                            (const float*)d_in[5 + 6 * L],
                                            wfrag + (long)L * 6144);
  }
  k_tobf<<<NF / 4 / 256, 256, 0, stream>>>(x, xbf);

  int gB = (NN + 3) / 4;            // 25000
  int nfBlocks = NF / 4 / 256;      // 6250

  for (int layer = 0; layer < 3; ++layer) {
    const float* bs = (const float*)d_in[6 + 6 * layer];  // [K,2,1,F]
    const float* gm = (const float*)d_in[7 + 6 * layer];  // [F]
    const float* bt = (const float*)d_in[8 + 6 * layer];  // [F]
    const uint4* wfL = wfrag + (long)layer * 6144;
    // frag blocks: 0=iw, 1=w, 2=rw0, 3=rw1 (1536 uint4 each)

    // t=0: g = A@x (raw gather); y0_k = relu(g@iw_k + x@rw0_k + b0_k)
    k_gath0<<<gB, 256, 0, stream>>>(rowstart, edges, xbf, g);
    k_gemmY0<<<dim3(SBLK, 3), 256, 0, stream>>>(g, xbf, wfL, wfL + 2 * 1536, bs, y0);
    // t=1: G_k = A@y0_k; hm = mean_k relu(G_k@w_k + x@rw1_k + b1_k)
    k_gath1<<<gB, 256, 0, stream>>>(rowstart, edges, y0, Gb);
    k_gemmY1<<<SBLK, 256, 0, stream>>>(Gb, xbf, wfL + 1 * 1536, wfL + 3 * 1536, bs, hm);
    // BN stats + finalize + relu
    hipMemsetAsync(bns, 0, 2 * 64 * sizeof(float), stream);
    k_bnstats<<<1024, 256, 0, stream>>>(hm, bns, bns + 64);
    if (layer == 2)
      k_bnfin<true><<<nfBlocks, 256, 0, stream>>>(hm, bns, bns + 64, gm, bt, (float*)d_out, (ushort*)0);
    else
      k_bnfin<false><<<nfBlocks, 256, 0, stream>>>(hm, bns, bns + 64, gm, bt, (float*)0, xbf);
  }
}

// Round 12
// 954.901 us; speedup vs baseline: 108.7043x; 1.0092x over previous
//
#include <hip/hip_runtime.h>

#define NN 100000
#define NE 1600000
#define FD 64
#define KK 3
#define NF (NN*FD)            // 6,400,000
#define EPSBN 1e-5f
#define SBLK ((NN + 255) / 256)   // 391
#define BLK64 ((NN + 63) / 64)    // 1563
#define DEGSCALE 262144.0f        // 2^18 fixed-point for weighted degree

typedef unsigned short ushort;
typedef unsigned int uint;
typedef __attribute__((ext_vector_type(8))) short short8;
typedef __attribute__((ext_vector_type(4))) float f32x4;

#define MFMA __builtin_amdgcn_mfma_f32_16x16x32_bf16

__device__ inline float bf2f(ushort u) { return __uint_as_float((unsigned)u << 16); }
__device__ inline ushort f2bf(float v) {
  unsigned u = __float_as_uint(v); u += 0x7FFF + ((u >> 16) & 1);
  return (ushort)(u >> 16);
}
// split a,b into packed hi-word and lo-word (hi = rnd(v), lo = rnd(v - hi))
__device__ inline void split2(float a, float b, uint& hi, uint& lo) {
  ushort ha = f2bf(a), hb = f2bf(b);
  float ra = a - bf2f(ha), rb = b - bf2f(hb);
  hi = (uint)ha | ((uint)hb << 16);
  lo = (uint)f2bf(ra) | ((uint)f2bf(rb) << 16);
}

// ---------------- graph norm + CSR build ----------------
__global__ void k_degcnt(const int* __restrict__ col, const float* __restrict__ w,
                         unsigned long long* __restrict__ dc) {
  int e = blockIdx.x * 256 + threadIdx.x;
  if (e < NE) {
    unsigned fx = __float2uint_rn(w[e] * DEGSCALE);
    atomicAdd(&dc[col[e]], (1ULL << 32) | (unsigned long long)fx);
  }
}

__global__ __launch_bounds__(256) void k_sblk(const unsigned long long* __restrict__ dc,
                                              float* __restrict__ dis, int* __restrict__ cnt,
                                              int* __restrict__ part) {
  int i = blockIdx.x * 256 + threadIdx.x;
  int v = 0;
  if (i < NN) {
    unsigned long long u = dc[i];
    float d = (float)(unsigned)u * (1.0f / DEGSCALE);
    dis[i] = d > 0.f ? rsqrtf(d) : 0.f;
    v = (int)(u >> 32);
    cnt[i] = v;
  }
#pragma unroll
  for (int off = 32; off; off >>= 1) v += __shfl_down(v, off);
  __shared__ int ws[4];
  if ((threadIdx.x & 63) == 0) ws[threadIdx.x >> 6] = v;
  __syncthreads();
  if (threadIdx.x == 0) part[blockIdx.x] = ws[0] + ws[1] + ws[2] + ws[3];
}

__global__ __launch_bounds__(512) void k_sscan(const int* __restrict__ part,
                                               int* __restrict__ base) {
  __shared__ int ls[512];
  int tid = threadIdx.x;
  int v = (tid < SBLK) ? part[tid] : 0;
  ls[tid] = v;
  __syncthreads();
  for (int off = 1; off < 512; off <<= 1) {
    int u = (tid >= off) ? ls[tid - off] : 0;
    __syncthreads();
    ls[tid] += u;
    __syncthreads();
  }
  base[tid] = tid ? ls[tid - 1] : 0;
}

__global__ __launch_bounds__(256) void k_sfin(const int* __restrict__ cnt,
                                              const int* __restrict__ base,
                                              int* __restrict__ rowstart,
                                              int* __restrict__ cursor) {
  __shared__ int ls[256];
  int i = blockIdx.x * 256 + threadIdx.x;
  int v = (i < NN) ? cnt[i] : 0;
  ls[threadIdx.x] = v;
  __syncthreads();
  for (int off = 1; off < 256; off <<= 1) {
    int u = (threadIdx.x >= off) ? ls[threadIdx.x - off] : 0;
    __syncthreads();
    ls[threadIdx.x] += u;
    __syncthreads();
  }
  int excl = base[blockIdx.x] + ls[threadIdx.x] - v;
  if (i < NN) {
    rowstart[i] = excl;
    cursor[i] = excl;
    if (i == NN - 1) rowstart[NN] = excl + v;
  }
}

__global__ void k_place(const int* __restrict__ row, const int* __restrict__ col,
                        const float* __restrict__ w, const float* __restrict__ dis,
                        int* __restrict__ cursor, int2* __restrict__ edges) {
  int e = blockIdx.x * 256 + threadIdx.x;
  if (e >= NE) return;
  int r = row[e], c = col[e];
  float nm = dis[r] * w[e] * dis[c];
  int p = atomicAdd(&cursor[c], 1);
  edges[p] = make_int2(r, __float_as_int(nm));
}

// ---------------- weight fragment prep (per layer, hi + lo) ----------------
// hi frag[(which*3+k)*8 + ct*2 + ks][lane]; lo at +6144 uint4.
// which: 0 = iw[k], 1 = w[k][0], 2 = rw[k][0], 3 = rw[k][1]
__global__ __launch_bounds__(64) void k_wfrag(const float* __restrict__ iw,
                                              const float* __restrict__ w,
                                              const float* __restrict__ rw,
                                              uint4* __restrict__ frag) {
  int m = blockIdx.x;
  int which = m / 3, k = m % 3;
  const float* src;
  if (which == 0) src = iw + k * 4096;
  else if (which == 1) src = w + k * 4096;
  else if (which == 2) src = rw + k * 8192;
  else src = rw + k * 8192 + 4096;
  int sub = blockIdx.y;            // ct*2 + ks
  int ks = sub & 1, ct = sub >> 1;
  int l = threadIdx.x;
  int r0 = ks * 32 + (l >> 4) * 8;
  int c = ct * 16 + (l & 15);
  uint4 oh, ol;
  split2(src[(r0 + 0) * 64 + c], src[(r0 + 1) * 64 + c], oh.x, ol.x);
  split2(src[(r0 + 2) * 64 + c], src[(r0 + 3) * 64 + c], oh.y, ol.y);
  split2(src[(r0 + 4) * 64 + c], src[(r0 + 5) * 64 + c], oh.z, ol.z);
  split2(src[(r0 + 6) * 64 + c], src[(r0 + 7) * 64 + c], oh.w, ol.w);
  frag[(m * 8 + sub) * 64 + l] = oh;
  frag[6144 + (m * 8 + sub) * 64 + l] = ol;
}

// ---------------- f32 -> bf16 hi/lo planes ----------------
__global__ void k_tobf2(const float* __restrict__ in,
                        ushort* __restrict__ hi, ushort* __restrict__ lo) {
  long i = ((long)blockIdx.x * 256 + threadIdx.x) * 4;
  float4 v = *(const float4*)(in + i);
  uint2 uh, ul;
  split2(v.x, v.y, uh.x, ul.x);
  split2(v.z, v.w, uh.y, ul.y);
  *(uint2*)(hi + i) = uh;
  *(uint2*)(lo + i) = ul;
}

#define RED2(v) do { (v) += __shfl_xor((v), 16); (v) += __shfl_xor((v), 32); } while (0)

#define G0STEP(EV) do { \
  int2 _e = (EV); \
  float _m = __int_as_float(_e.y); \
  uint2 _u = ((const uint2*)(xhi + (long)_e.x * 64))[fi]; \
  a0 = fmaf(bf2f((ushort)_u.x), _m, a0); a1 = fmaf(bf2f((ushort)(_u.x >> 16)), _m, a1); \
  a2 = fmaf(bf2f((ushort)_u.y), _m, a2); a3 = fmaf(bf2f((ushort)(_u.y >> 16)), _m, a3); \
} while (0)

#define G1STEP(EV) do { \
  int2 _e = (EV); \
  float _m = __int_as_float(_e.y); \
  const uint2* _p = (const uint2*)(y0 + (long)_e.x * 192) + fi; \
  uint2 _u0 = _p[0], _u1 = _p[16], _u2 = _p[32]; \
  a00 = fmaf(bf2f((ushort)_u0.x), _m, a00); a01 = fmaf(bf2f((ushort)(_u0.x >> 16)), _m, a01); \
  a02 = fmaf(bf2f((ushort)_u0.y), _m, a02); a03 = fmaf(bf2f((ushort)(_u0.y >> 16)), _m, a03); \
  a10 = fmaf(bf2f((ushort)_u1.x), _m, a10); a11 = fmaf(bf2f((ushort)(_u1.x >> 16)), _m, a11); \
  a12 = fmaf(bf2f((ushort)_u1.y), _m, a12); a13 = fmaf(bf2f((ushort)(_u1.y >> 16)), _m, a13); \
  a20 = fmaf(bf2f((ushort)_u2.x), _m, a20); a21 = fmaf(bf2f((ushort)(_u2.x >> 16)), _m, a21); \
  a22 = fmaf(bf2f((ushort)_u2.y), _m, a22); a23 = fmaf(bf2f((ushort)(_u2.y >> 16)), _m, a23); \
} while (0)

// ---------------- fused t=0: gather x -> LDS (hi/lo), MFMA, y0 = relu(...) ----------------
__global__ __launch_bounds__(256) void k_l0(
    const int* __restrict__ rowstart, const int2* __restrict__ edges,
    const ushort* __restrict__ xhi, const ushort* __restrict__ xlo,
    const uint4* __restrict__ wfAh, const uint4* __restrict__ wfAl,
    const uint4* __restrict__ wfBh, const uint4* __restrict__ wfBl,
    const float* __restrict__ bias, ushort* __restrict__ y0) {
  __shared__ ushort Gh[64 * 72];
  __shared__ ushort Gl[64 * 72];
  const int wv = threadIdx.x >> 6;
  const int l = threadIdx.x & 63;
  const int grp = l >> 4, fi = l & 15;
  const int nb = blockIdx.x * 64;
  // ---- phase 1: gather x (hi plane), keep f32 sum via hi/lo store ----
  for (int i = 0; i < 16; ++i) {
    int n = nb + wv * 16 + i;
    float a0 = 0.f, a1 = 0.f, a2 = 0.f, a3 = 0.f;
    if (n < NN) {
      int s = rowstart[n], e = rowstart[n + 1];
      int j = s;
      for (; j + 8 <= e; j += 8) { G0STEP(edges[j + grp]); G0STEP(edges[j + 4 + grp]); }
      if (j + 4 <= e) { G0STEP(edges[j + grp]); j += 4; }
      if (j < e) {
        int idx = j + grp;
        int2 ee = edges[idx < e ? idx : (e - 1)];
        if (idx >= e) ee.y = 0;
        G0STEP(ee);
      }
    }
    RED2(a0); RED2(a1); RED2(a2); RED2(a3);
    if (grp == 0) {
      uint2 uh, ul;
      split2(a0, a1, uh.x, ul.x);
      split2(a2, a3, uh.y, ul.y);
      *(uint2*)&Gh[(wv * 16 + i) * 72 + 4 * fi] = uh;
      *(uint2*)&Gl[(wv * 16 + i) * 72 + 4 * fi] = ul;
    }
  }
  __syncthreads();
  // ---- phase 2: MFMA with hi/lo compensation ----
  const int lg = grp, lr = fi;
  const int tb = nb + wv * 16;
  int ra = tb + lr; if (ra >= NN) ra = NN - 1;
  const long xo = (long)ra * 64 + lg * 8;
  short8 xh0 = *(const short8*)(xhi + xo);
  short8 xh1 = *(const short8*)(xhi + xo + 32);
  short8 xl0 = *(const short8*)(xlo + xo);
  short8 xl1 = *(const short8*)(xlo + xo + 32);
  short8 gh0 = *(const short8*)&Gh[(wv * 16 + lr) * 72 + lg * 8];
  short8 gh1 = *(const short8*)&Gh[(wv * 16 + lr) * 72 + lg * 8 + 32];
  short8 gl0 = *(const short8*)&Gl[(wv * 16 + lr) * 72 + lg * 8];
  short8 gl1 = *(const short8*)&Gl[(wv * 16 + lr) * 72 + lg * 8 + 32];
#pragma unroll
  for (int k = 0; k < 3; ++k) {
    const int k8 = k * 8;
#pragma unroll
    for (int ct = 0; ct < 4; ++ct) {
      short8 ah0 = *(const short8*)&wfAh[(k8 + ct * 2 + 0) * 64 + l];
      short8 ah1 = *(const short8*)&wfAh[(k8 + ct * 2 + 1) * 64 + l];
      short8 al0 = *(const short8*)&wfAl[(k8 + ct * 2 + 0) * 64 + l];
      short8 al1 = *(const short8*)&wfAl[(k8 + ct * 2 + 1) * 64 + l];
      short8 bh0 = *(const short8*)&wfBh[(k8 + ct * 2 + 0) * 64 + l];
      short8 bh1 = *(const short8*)&wfBh[(k8 + ct * 2 + 1) * 64 + l];
      short8 bl0 = *(const short8*)&wfBl[(k8 + ct * 2 + 0) * 64 + l];
      short8 bl1 = *(const short8*)&wfBl[(k8 + ct * 2 + 1) * 64 + l];
      f32x4 acc = {0.f, 0.f, 0.f, 0.f};
      acc = MFMA(gh0, ah0, acc, 0, 0, 0); acc = MFMA(gh1, ah1, acc, 0, 0, 0);
      acc = MFMA(gl0, ah0, acc, 0, 0, 0); acc = MFMA(gl1, ah1, acc, 0, 0, 0);
      acc = MFMA(gh0, al0, acc, 0, 0, 0); acc = MFMA(gh1, al1, acc, 0, 0, 0);
      acc = MFMA(xh0, bh0, acc, 0, 0, 0); acc = MFMA(xh1, bh1, acc, 0, 0, 0);
      acc = MFMA(xl0, bh0, acc, 0, 0, 0); acc = MFMA(xl1, bh1, acc, 0, 0, 0);
      acc = MFMA(xh0, bl0, acc, 0, 0, 0); acc = MFMA(xh1, bl1, acc, 0, 0, 0);
      const int f = ct * 16 + lr;
      const float bv = bias[(k * 2 + 0) * 64 + f];
      ushort* op = y0 + (long)(tb + lg * 4) * 192 + k * 64 + f;
#pragma unroll
      for (int r = 0; r < 4; ++r)
        if (tb + lg * 4 + r < NN) op[(long)r * 192] = f2bf(fmaxf(acc[r] + bv, 0.f));
    }
  }
}

// ---------------- t=1 gather: G(hi/lo)[n][k*64+f] = sum norm * y0[r][k] ----------------
__global__ __launch_bounds__(256) void k_gath1(const int* __restrict__ rowstart,
                                               const int2* __restrict__ edges,
                                               const ushort* __restrict__ y0,
                                               ushort* __restrict__ Ghi,
                                               ushort* __restrict__ Glo) {
  int wave = threadIdx.x >> 6;
  int lane = threadIdx.x & 63;
  int grp = lane >> 4;
  int fi = lane & 15;
  int n = blockIdx.x * 4 + wave;
  if (n >= NN) return;
  int s = rowstart[n], e = rowstart[n + 1];
  float a00 = 0.f, a01 = 0.f, a02 = 0.f, a03 = 0.f;
  float a10 = 0.f, a11 = 0.f, a12 = 0.f, a13 = 0.f;
  float a20 = 0.f, a21 = 0.f, a22 = 0.f, a23 = 0.f;
  int j = s;
  for (; j + 8 <= e; j += 8) { G1STEP(edges[j + grp]); G1STEP(edges[j + 4 + grp]); }
  if (j + 4 <= e) { G1STEP(edges[j + grp]); j += 4; }
  if (j < e) {
    int idx = j + grp;
    int2 ee = edges[idx < e ? idx : (e - 1)];
    if (idx >= e) ee.y = 0;
    G1STEP(ee);
  }
  RED2(a00); RED2(a01); RED2(a02); RED2(a03);
  RED2(a10); RED2(a11); RED2(a12); RED2(a13);
  RED2(a20); RED2(a21); RED2(a22); RED2(a23);
  if (grp < 3) {
    float aX, aY, aZ, aW;
    if (grp == 0)      { aX = a00; aY = a01; aZ = a02; aW = a03; }
    else if (grp == 1) { aX = a10; aY = a11; aZ = a12; aW = a13; }
    else               { aX = a20; aY = a21; aZ = a22; aW = a23; }
    uint2 uh, ul;
    split2(aX, aY, uh.x, ul.x);
    split2(aZ, aW, uh.y, ul.y);
    long o = (long)n * 192 + grp * 64 + 4 * fi;
    *(uint2*)(Ghi + o) = uh;
    *(uint2*)(Glo + o) = ul;
  }
}

// ---------------- t=1 MFMA + mean + BN partials ----------------
__global__ __launch_bounds__(256) void k_gemmY1(
    const ushort* __restrict__ Ghi, const ushort* __restrict__ Glo,
    const ushort* __restrict__ xhi, const ushort* __restrict__ xlo,
    const uint4* __restrict__ wfWh, const uint4* __restrict__ wfWl,
    const uint4* __restrict__ wfRh, const uint4* __restrict__ wfRl,
    const float* __restrict__ bias, float* __restrict__ hm,
    float* __restrict__ bns) {
  __shared__ float bnl[128];
  if (threadIdx.x < 128) bnl[threadIdx.x] = 0.f;
  __syncthreads();
  const int wv = threadIdx.x >> 6;
  const int l = threadIdx.x & 63;
  const int lg = l >> 4, lr = l & 15;
  const int bb = blockIdx.x * 256;
  for (int rt = 0; rt < 4; ++rt) {
    const int tb = bb + rt * 64 + wv * 16;
    int ra = tb + lr; if (ra >= NN) ra = NN - 1;
    const long xo = (long)ra * 64 + lg * 8;
    short8 xh0 = *(const short8*)(xhi + xo);
    short8 xh1 = *(const short8*)(xhi + xo + 32);
    short8 xl0 = *(const short8*)(xlo + xo);
    short8 xl1 = *(const short8*)(xlo + xo + 32);
    f32x4 m0 = {0.f, 0.f, 0.f, 0.f}, m1 = m0, m2 = m0, m3 = m0;
#pragma unroll
    for (int k = 0; k < 3; ++k) {
      const long go = (long)ra * 192 + k * 64 + lg * 8;
      short8 gh0 = *(const short8*)(Ghi + go);
      short8 gh1 = *(const short8*)(Ghi + go + 32);
      short8 gl0 = *(const short8*)(Glo + go);
      short8 gl1 = *(const short8*)(Glo + go + 32);
      const int k8 = k * 8;
#define YCT(CT, M) { \
      short8 wh0 = *(const short8*)&wfWh[(k8 + CT * 2 + 0) * 64 + l]; \
      short8 wh1 = *(const short8*)&wfWh[(k8 + CT * 2 + 1) * 64 + l]; \
      short8 wl0 = *(const short8*)&wfWl[(k8 + CT * 2 + 0) * 64 + l]; \
      short8 wl1 = *(const short8*)&wfWl[(k8 + CT * 2 + 1) * 64 + l]; \
      short8 rh0 = *(const short8*)&wfRh[(k8 + CT * 2 + 0) * 64 + l]; \
      short8 rh1 = *(const short8*)&wfRh[(k8 + CT * 2 + 1) * 64 + l]; \
      short8 rl0 = *(const short8*)&wfRl[(k8 + CT * 2 + 0) * 64 + l]; \
      short8 rl1 = *(const short8*)&wfRl[(k8 + CT * 2 + 1) * 64 + l]; \
      f32x4 acc = {0.f, 0.f, 0.f, 0.f}; \
      acc = MFMA(gh0, wh0, acc, 0, 0, 0); acc = MFMA(gh1, wh1, acc, 0, 0, 0); \
      acc = MFMA(gl0, wh0, acc, 0, 0, 0); acc = MFMA(gl1, wh1, acc, 0, 0, 0); \
      acc = MFMA(gh0, wl0, acc, 0, 0, 0); acc = MFMA(gh1, wl1, acc, 0, 0, 0); \
      acc = MFMA(xh0, rh0, acc, 0, 0, 0); acc = MFMA(xh1, rh1, acc, 0, 0, 0); \
      acc = MFMA(xl0, rh0, acc, 0, 0, 0); acc = MFMA(xl1, rh1, acc, 0, 0, 0); \
      acc = MFMA(xh0, rl0, acc, 0, 0, 0); acc = MFMA(xh1, rl1, acc, 0, 0, 0); \
      float bv = bias[(k * 2 + 1) * 64 + CT * 16 + lr]; \
      M[0] += fmaxf(acc[0] + bv, 0.f); M[1] += fmaxf(acc[1] + bv, 0.f); \
      M[2] += fmaxf(acc[2] + bv, 0.f); M[3] += fmaxf(acc[3] + bv, 0.f); }
      YCT(0, m0) YCT(1, m1) YCT(2, m2) YCT(3, m3)
#undef YCT
    }
    const int rb = tb + lg * 4;
    m0 *= (1.f / 3.f); m1 *= (1.f / 3.f); m2 *= (1.f / 3.f); m3 *= (1.f / 3.f);
#pragma unroll
    for (int r = 0; r < 4; ++r) {
      if (rb + r < NN) {
        float* hp = hm + (long)(rb + r) * 64 + lr;
        hp[0] = m0[r]; hp[16] = m1[r]; hp[32] = m2[r]; hp[48] = m3[r];
      }
    }
#define BNCT(M, CT) { \
    float s = 0.f, q = 0.f; \
    for (int r = 0; r < 4; ++r) if (rb + r < NN) { s += M[r]; q += M[r] * M[r]; } \
    s += __shfl_xor(s, 16); s += __shfl_xor(s, 32); \
    q += __shfl_xor(q, 16); q += __shfl_xor(q, 32); \
    if (lg == 0) { atomicAdd(&bnl[CT * 16 + lr], s); atomicAdd(&bnl[64 + CT * 16 + lr], q); } }
    BNCT(m0, 0) BNCT(m1, 1) BNCT(m2, 2) BNCT(m3, 3)
#undef BNCT
  }
  __syncthreads();
  if (threadIdx.x < 128) atomicAdd(&bns[threadIdx.x], bnl[threadIdx.x]);
}

// ---------------- BN finalize: FINAL -> f32 d_out, else bf16 hi/lo next-layer input ----
template <bool FINAL>
__global__ void k_bnfin(const float* __restrict__ h, const float* __restrict__ sum,
                        const float* __restrict__ sq, const float* __restrict__ gam,
                        const float* __restrict__ bet,
                        float* __restrict__ outf,
                        ushort* __restrict__ ohi, ushort* __restrict__ olo) {
  long i4 = (long)blockIdx.x * 256 + threadIdx.x;
  if (i4 >= (long)NF / 4) return;
  long i = i4 * 4;
  int f = (int)(i & 63);
  float4 v = *(const float4*)(h + i);
  float o[4] = {v.x, v.y, v.z, v.w};
  float r[4];
#pragma unroll
  for (int j = 0; j < 4; ++j) {
    int fj = f + j;
    float mu = sum[fj] * (1.f / NN);
    float var = sq[fj] * (1.f / NN) - mu * mu;
    float inv = rsqrtf(var + EPSBN);
    float y = gam[fj] * (o[j] - mu) * inv + bet[fj];
    r[j] = fmaxf(y, 0.f);
  }
  if (FINAL) {
    float4 ov = {r[0], r[1], r[2], r[3]};
    *(float4*)(outf + i) = ov;
  } else {
    uint2 uh, ul;
    split2(r[0], r[1], uh.x, ul.x);
    split2(r[2], r[3], uh.y, ul.y);
    *(uint2*)(ohi + i) = uh;
    *(uint2*)(olo + i) = ul;
  }
}

extern "C" void kernel_launch(void* const* d_in, const int* in_sizes, int n_in,
                              void* d_out, int out_size, void* d_ws, size_t ws_size,
                              hipStream_t stream) {
  const float* x   = (const float*)d_in[0];
  const int*   ei  = (const int*)d_in[1];
  const float* wts = (const float*)d_in[2];
  const int* row = ei;        // edge_index[0]
  const int* col = ei + NE;   // edge_index[1]

  // workspace layout (4B words; vector arrays 16B-aligned)
  unsigned long long* dc = (unsigned long long*)d_ws;        // 2*NN w
  uint4* wfrag    = (uint4*)((int*)d_ws + 2 * NN);           // 36864 uint4 (147456 w)
  int2*  edges    = (int2*)((int*)wfrag + 147456);           // 2*NE w
  int*   cnt      = (int*)edges + 2 * NE;                    // NN
  int*   rowstart = cnt + NN;                                // NN+4
  int*   cursor   = rowstart + NN + 4;                       // NN
  float* dis      = (float*)(cursor + NN);                   // NN
  float* hm       = dis + NN;                                // NF f32
  ushort* xhi     = (ushort*)(hm + NF);                      // NF bf16
  ushort* xlo     = xhi + NF;                                // NF bf16
  ushort* y0      = xlo + NF;                                // NN*192 bf16 [n][k*64+f]
  ushort* Ghi     = y0 + (long)NN * 192;                     // NN*192 bf16
  ushort* Glo     = Ghi + (long)NN * 192;                    // NN*192 bf16
  float* bns      = (float*)(Glo + (long)NN * 192);          // 128
  int*   part     = (int*)(bns + 128);                       // 512
  int*   pbase    = part + 512;                              // 512

  // --- norm + CSR build + weight frags + x->bf16 hi/lo (once) ---
  hipMemsetAsync(dc, 0, NN * sizeof(unsigned long long), stream);
  int eb = (NE + 255) / 256;
  k_degcnt<<<eb, 256, 0, stream>>>(col, wts, dc);
  k_sblk<<<SBLK, 256, 0, stream>>>(dc, dis, cnt, part);
  k_sscan<<<1, 512, 0, stream>>>(part, pbase);
  k_sfin<<<SBLK, 256, 0, stream>>>(cnt, pbase, rowstart, cursor);
  k_place<<<eb, 256, 0, stream>>>(row, col, wts, dis, cursor, edges);
  for (int L = 0; L < 3; ++L) {
    k_wfrag<<<dim3(12, 8), 64, 0, stream>>>((const float*)d_in[3 + 6 * L],
                                            (const float*)d_in[4 + 6 * L],
                                            (const float*)d_in[5 + 6 * L],
                                            wfrag + (long)L * 12288);
  }
  k_tobf2<<<NF / 4 / 256, 256, 0, stream>>>(x, xhi, xlo);

  int gB = (NN + 3) / 4;            // 25000
  int nfBlocks = NF / 4 / 256;      // 6250

  for (int layer = 0; layer < 3; ++layer) {
    const float* bs = (const float*)d_in[6 + 6 * layer];  // [K,2,1,F]
    const float* gm = (const float*)d_in[7 + 6 * layer];  // [F]
    const float* bt = (const float*)d_in[8 + 6 * layer];  // [F]
    const uint4* wfL = wfrag + (long)layer * 12288;
    // hi tables: iw=+0, w=+1536, rw0=+3072, rw1=+4608; lo = +6144 each

    // t=0 fused: y0[n][k] = relu((A@x)@iw_k + x@rw0_k + b0_k)   [hi/lo compensated]
    k_l0<<<BLK64, 256, 0, stream>>>(rowstart, edges, xhi, xlo,
                                    wfL + 0, wfL + 6144, wfL + 3072, wfL + 3072 + 6144,
                                    bs, y0);
    // t=1: G = A@y0 (hi/lo); hm = mean_k relu(G@w_k + x@rw1_k + b1_k) + BN partials
    hipMemsetAsync(bns, 0, 2 * 64 * sizeof(float), stream);
    k_gath1<<<gB, 256, 0, stream>>>(rowstart, edges, y0, Ghi, Glo);
    k_gemmY1<<<SBLK, 256, 0, stream>>>(Ghi, Glo, xhi, xlo,
                                       wfL + 1536, wfL + 1536 + 6144,
                                       wfL + 4608, wfL + 4608 + 6144,
                                       bs, hm, bns);
    // BN finalize + relu
    if (layer == 2)
      k_bnfin<true><<<nfBlocks, 256, 0, stream>>>(hm, bns, bns + 64, gm, bt,
                                                  (float*)d_out, (ushort*)0, (ushort*)0);
    else
      k_bnfin<false><<<nfBlocks, 256, 0, stream>>>(hm, bns, bns + 64, gm, bt,
                                                   (float*)0, xhi, xlo);
  }
}